// Round 1
// baseline (7156.996 us; speedup 1.0000x reference)
//
#include <hip/hip_runtime.h>
#include <math.h>

static constexpr int NCOIL = 12;
static constexpr int HWSZ  = 65536;   // 256*256

// ---------------- complex helpers ----------------
__device__ __forceinline__ float2 cmulf(float2 a, float2 b) {
  return make_float2(a.x * b.x - a.y * b.y, a.x * b.y + a.y * b.x);
}
__device__ __forceinline__ float2 caddf(float2 a, float2 b) {
  return make_float2(a.x + b.x, a.y + b.y);
}
__device__ __forceinline__ float2 csubf(float2 a, float2 b) {
  return make_float2(a.x - b.x, a.y - b.y);
}

// ---------------- prep: twiddle table + weight transpose ----------------
// tw[l + j] = exp(-i*pi*j/l) for l in {1..128}, 0<=j<l  (index = (128+bf)>>s)
__global__ void k_twiddle(float2* __restrict__ tw) {
  int t = threadIdx.x;
  if (t == 0) { tw[0] = make_float2(1.f, 0.f); return; }
  int l = 1 << (31 - __clz(t));
  int j = t - l;
  float ang = -3.14159265358979323846f * (float)j / (float)l;
  float s, c;
  sincosf(ang, &s, &c);
  tw[t] = make_float2(c, s);
}

// w [OC][IC][3][3] -> wT [IC*9][OC]
__global__ void k_transpose_w(const float* __restrict__ w, float* __restrict__ wT,
                              int IC, int OC) {
  int i = blockIdx.x * 256 + threadIdx.x;
  int total = IC * 9 * OC;
  if (i >= total) return;
  int oc = i % OC;
  int rest = i / OC;            // ic*9 + k
  int ic = rest / 9, k = rest - ic * 9;
  wT[i] = w[(oc * IC + ic) * 9 + k];
}

// ---------------- conv layers ----------------
template<int IC, int RELU>
__global__ __launch_bounds__(256) void k_conv(
    const float* __restrict__ in,   // [IC][256][256]
    const float* __restrict__ wT,   // [IC*9][64]
    const float* __restrict__ bias, // [64]
    float* __restrict__ out)        // [64][256][256]
{
  __shared__ float patch[IC * 324];  // IC x 18 x 18
  const int t = threadIdx.x;
  const int tx0 = blockIdx.x << 4, ty0 = blockIdx.y << 4;
  for (int i = t; i < IC * 324; i += 256) {
    int ic = i / 324, rem = i - ic * 324;
    int py = rem / 18, px = rem - py * 18;
    int gy = ty0 + py - 1, gx = tx0 + px - 1;
    float v = 0.f;
    if (gy >= 0 && gy < 256 && gx >= 0 && gx < 256)
      v = in[(ic << 16) + (gy << 8) + gx];
    patch[i] = v;
  }
  __syncthreads();
  const int tx = t & 15, ty = t >> 4;
  float acc[64];
  #pragma unroll
  for (int o = 0; o < 64; ++o) acc[o] = 0.f;
  for (int ic = 0; ic < IC; ++ic) {
    const float* pb = &patch[ic * 324 + ty * 18 + tx];
    #pragma unroll
    for (int k = 0; k < 9; ++k) {
      const int ky = k / 3, kx = k - ky * 3;
      const float v = pb[ky * 18 + kx];
      const float* wr = &wT[(ic * 9 + k) << 6];  // uniform -> s_load
      #pragma unroll
      for (int o = 0; o < 64; ++o) acc[o] = fmaf(v, wr[o], acc[o]);
    }
  }
  const int ob = ((ty0 + ty) << 8) + tx0 + tx;
  #pragma unroll
  for (int o = 0; o < 64; ++o) {
    float rv = acc[o] + bias[o];
    if (RELU) rv = fmaxf(rv, 0.f);
    out[(o << 16) + ob] = rv;
  }
}

// conv5 (64->2) fused with residual + rhs = (1+lam)*atb + lam*conv5out, writes complex rhs
__global__ __launch_bounds__(256) void k_conv5_rhs(
    const float* __restrict__ in,    // h4 [64][256][256]
    const float* __restrict__ w5T,   // [576][2]
    const float* __restrict__ b5,    // [2]
    const float* __restrict__ atb_b, // [2][256][256]
    const float* __restrict__ lam,
    float2* __restrict__ rhs_b)      // [256][256]
{
  __shared__ float patch[64 * 324];
  const int t = threadIdx.x;
  const int tx0 = blockIdx.x << 4, ty0 = blockIdx.y << 4;
  for (int i = t; i < 64 * 324; i += 256) {
    int ic = i / 324, rem = i - ic * 324;
    int py = rem / 18, px = rem - py * 18;
    int gy = ty0 + py - 1, gx = tx0 + px - 1;
    float v = 0.f;
    if (gy >= 0 && gy < 256 && gx >= 0 && gx < 256)
      v = in[(ic << 16) + (gy << 8) + gx];
    patch[i] = v;
  }
  __syncthreads();
  const int tx = t & 15, ty = t >> 4;
  float a0 = 0.f, a1 = 0.f;
  for (int ic = 0; ic < 64; ++ic) {
    const float* pb = &patch[ic * 324 + ty * 18 + tx];
    #pragma unroll
    for (int k = 0; k < 9; ++k) {
      const int ky = k / 3, kx = k - ky * 3;
      const float v = pb[ky * 18 + kx];
      const int wi = (ic * 9 + k) << 1;
      a0 = fmaf(v, w5T[wi], a0);
      a1 = fmaf(v, w5T[wi + 1], a1);
    }
  }
  const int pix = ((ty0 + ty) << 8) + tx0 + tx;
  const float l = *lam;
  const float d0 = a0 + b5[0], d1 = a1 + b5[1];
  const float x0 = atb_b[pix], x1 = atb_b[HWSZ + pix];
  // rhs = atb + lam*(atb + conv5out)
  rhs_b[pix] = make_float2(fmaf(l, x0 + d0, x0), fmaf(l, x1 + d1, x1));
}

// ---------------- AtA pass 1: coil = csm * p, FFT along rows (W) ----------------
__global__ __launch_bounds__(256) void k_coil_fft_rows(
    const float2* __restrict__ p, const float* __restrict__ csm_r,
    const float* __restrict__ csm_i, const float2* __restrict__ tw,
    float2* __restrict__ coil)
{
  __shared__ float2 lds[1024];  // 2 buffers x 2 rows x 256
  const int t = threadIdx.x;
  const int bc = blockIdx.x;          // b*NCOIL + c
  const int b = bc / NCOIL;
  const int h0 = blockIdx.y << 1;
  #pragma unroll
  for (int e = 0; e < 2; ++e) {
    int idx = t + (e << 8);
    int lr = idx >> 8, w = idx & 255;
    int gi = (bc << 16) + ((h0 + lr) << 8) + w;
    int pi = (b << 16) + ((h0 + lr) << 8) + w;
    float cr = csm_r[gi], ci = csm_i[gi];
    float2 pv = p[pi];
    lds[(lr << 8) + w] = make_float2(cr * pv.x - ci * pv.y, cr * pv.y + ci * pv.x);
  }
  __syncthreads();
  const int lr = t >> 7, bf = t & 127;
  float2* src = lds; float2* dst = lds + 512;
  #pragma unroll
  for (int s = 0; s < 8; ++s) {
    const int m = 1 << s;
    float2 a = src[(lr << 8) + bf];
    float2 bb = src[(lr << 8) + bf + 128];
    float2 w = tw[(128 + bf) >> s];
    int o0 = bf + (bf & ~(m - 1));
    dst[(lr << 8) + o0] = caddf(a, bb);
    dst[(lr << 8) + o0 + m] = cmulf(csubf(a, bb), w);
    float2* tmp = src; src = dst; dst = tmp;
    __syncthreads();
  }
  #pragma unroll
  for (int e = 0; e < 2; ++e) {
    int idx = t + (e << 8);
    int lr2 = idx >> 8, w = idx & 255;
    coil[(bc << 16) + ((h0 + lr2) << 8) + w] = src[(lr2 << 8) + w];
  }
}

// ---------------- AtA pass 2: FFT cols (H), mask, IFFT cols ----------------
__global__ __launch_bounds__(256) void k_fft_cols_mask(
    float2* __restrict__ coil, const float* __restrict__ mask,
    const float2* __restrict__ tw)
{
  __shared__ float2 lds[2 * 256 * 17];  // 16 cols padded to 17, ping-pong
  const int t = threadIdx.x;
  const int bc = blockIdx.x;
  const int b = bc / NCOIL;
  const int w0 = blockIdx.y << 4;
  const int base = bc << 16;
  for (int i = 0; i < 16; ++i) {
    int idx = t + (i << 8);
    int h = idx >> 4, col = idx & 15;
    lds[h * 17 + col] = coil[base + (h << 8) + w0 + col];
  }
  __syncthreads();
  const int col = t & 15, bfb = t >> 4;
  float2* src = lds; float2* dst = lds + 256 * 17;
  // forward along H
  #pragma unroll
  for (int s = 0; s < 8; ++s) {
    const int m = 1 << s;
    #pragma unroll
    for (int rr = 0; rr < 8; ++rr) {
      int bf = bfb + (rr << 4);
      float2 a = src[bf * 17 + col];
      float2 bb = src[(bf + 128) * 17 + col];
      float2 w = tw[(128 + bf) >> s];
      int o0 = bf + (bf & ~(m - 1));
      dst[o0 * 17 + col] = caddf(a, bb);
      dst[(o0 + m) * 17 + col] = cmulf(csubf(a, bb), w);
    }
    float2* tmp = src; src = dst; dst = tmp;
    __syncthreads();
  }
  // k-space mask
  for (int i = 0; i < 16; ++i) {
    int idx = t + (i << 8);
    int h = idx >> 4, cl = idx & 15;
    float mv = mask[(b << 16) + (h << 8) + w0 + cl];
    float2 v = src[h * 17 + cl];
    src[h * 17 + cl] = make_float2(v.x * mv, v.y * mv);
  }
  __syncthreads();
  // inverse along H
  #pragma unroll
  for (int s = 0; s < 8; ++s) {
    const int m = 1 << s;
    #pragma unroll
    for (int rr = 0; rr < 8; ++rr) {
      int bf = bfb + (rr << 4);
      float2 a = src[bf * 17 + col];
      float2 bb = src[(bf + 128) * 17 + col];
      float2 w = tw[(128 + bf) >> s]; w.y = -w.y;
      int o0 = bf + (bf & ~(m - 1));
      dst[o0 * 17 + col] = caddf(a, bb);
      dst[(o0 + m) * 17 + col] = cmulf(csubf(a, bb), w);
    }
    float2* tmp = src; src = dst; dst = tmp;
    __syncthreads();
  }
  const float sc = 1.f / 256.f;
  for (int i = 0; i < 16; ++i) {
    int idx = t + (i << 8);
    int h = idx >> 4, cl = idx & 15;
    float2 v = src[h * 17 + cl];
    coil[base + (h << 8) + w0 + cl] = make_float2(v.x * sc, v.y * sc);
  }
}

// ------- AtA pass 3: IFFT rows, conj(csm) combine over coils, +lam*p, denom partials -------
__global__ __launch_bounds__(128) void k_ifft_rows_acc(
    const float2* __restrict__ coil, const float* __restrict__ csm_r,
    const float* __restrict__ csm_i, const float2* __restrict__ p,
    const float* __restrict__ lam, const float2* __restrict__ tw,
    float2* __restrict__ Ap, float* __restrict__ partials)
{
  __shared__ float2 lds[512];
  __shared__ float red[2];
  const int t = threadIdx.x;
  const int b = blockIdx.x, h = blockIdx.y;
  float2 acc0 = make_float2(0.f, 0.f), acc1 = make_float2(0.f, 0.f);
  for (int c = 0; c < NCOIL; ++c) {
    const int base = ((b * NCOIL + c) << 16) + (h << 8);
    lds[t] = coil[base + t];
    lds[t + 128] = coil[base + t + 128];
    __syncthreads();
    float2* src = lds; float2* dst = lds + 256;
    #pragma unroll
    for (int s = 0; s < 8; ++s) {
      const int m = 1 << s;
      float2 a = src[t], bb = src[t + 128];
      float2 w = tw[(128 + t) >> s]; w.y = -w.y;
      int o0 = t + (t & ~(m - 1));
      dst[o0] = caddf(a, bb);
      dst[o0 + m] = cmulf(csubf(a, bb), w);
      float2* tmp = src; src = dst; dst = tmp;
      __syncthreads();
    }
    {
      float2 z = src[t];
      float cr = csm_r[base + t], ci = csm_i[base + t];
      acc0.x += cr * z.x + ci * z.y;
      acc0.y += cr * z.y - ci * z.x;
      float2 z2 = src[t + 128];
      float cr2 = csm_r[base + t + 128], ci2 = csm_i[base + t + 128];
      acc1.x += cr2 * z2.x + ci2 * z2.y;
      acc1.y += cr2 * z2.y - ci2 * z2.x;
    }
    __syncthreads();
  }
  const float inv = 1.f / 256.f;
  const float l = *lam;
  float dp = 0.f;
  {
    int pi = (b << 16) + (h << 8) + t;
    float2 pv = p[pi];
    float2 apv = make_float2(fmaf(l, pv.x, acc0.x * inv), fmaf(l, pv.y, acc0.y * inv));
    Ap[pi] = apv;
    dp += pv.x * apv.x + pv.y * apv.y;
    pi += 128;
    float2 pv2 = p[pi];
    float2 apv2 = make_float2(fmaf(l, pv2.x, acc1.x * inv), fmaf(l, pv2.y, acc1.y * inv));
    Ap[pi] = apv2;
    dp += pv2.x * apv2.x + pv2.y * apv2.y;
  }
  #pragma unroll
  for (int off = 32; off; off >>= 1) dp += __shfl_down(dp, off);
  if ((t & 63) == 0) red[t >> 6] = dp;
  __syncthreads();
  if (t == 0) partials[(b << 8) + h] = red[0] + red[1];
}

// ---------------- CG vector + scalar kernels ----------------
__device__ __forceinline__ float blockRed256(float v, float* sm) {
  #pragma unroll
  for (int off = 32; off; off >>= 1) v += __shfl_down(v, off);
  int lane = threadIdx.x & 63, wv = threadIdx.x >> 6;
  if (lane == 0) sm[wv] = v;
  __syncthreads();
  return sm[0] + sm[1] + sm[2] + sm[3];
}

__global__ __launch_bounds__(256) void k_cg_init(
    const float2* __restrict__ rhs, float2* __restrict__ x,
    float2* __restrict__ r, float2* __restrict__ p, float* __restrict__ part)
{
  __shared__ float sm[4];
  const int t = threadIdx.x;
  const int base = blockIdx.x * 512;
  float s = 0.f;
  #pragma unroll
  for (int e = 0; e < 2; ++e) {
    int idx = base + t + (e << 8);
    float2 v = rhs[idx];
    x[idx] = make_float2(0.f, 0.f);
    r[idx] = v; p[idx] = v;
    s = fmaf(v.x, v.x, fmaf(v.y, v.y, s));
  }
  float tot = blockRed256(s, sm);
  if (t == 0) part[blockIdx.x] = tot;
}

// scalars: sc[0]=rTr, sc[1]=alpha, sc[2]=beta, sc[3]=cont
__global__ void k_reduce_alpha(const float* __restrict__ part, float* __restrict__ sc) {
  __shared__ double sm[4];
  double s = 0.0;
  for (int i = threadIdx.x; i < 2048; i += 256) s += (double)part[i];
  #pragma unroll
  for (int off = 32; off; off >>= 1) s += __shfl_down(s, off);
  int lane = threadIdx.x & 63, wv = threadIdx.x >> 6;
  if (lane == 0) sm[wv] = s;
  __syncthreads();
  if (threadIdx.x == 0) {
    float denom = (float)(sm[0] + sm[1] + sm[2] + sm[3]);
    float rTr = sc[0];
    bool cont = rTr > 1e-10f;
    sc[1] = cont ? rTr / denom : 0.f;  // alpha=0 => x,r unchanged, exactly
    sc[3] = cont ? 1.f : 0.f;
  }
}

__global__ void k_reduce_rtr(const float* __restrict__ part, float* __restrict__ sc, int init) {
  __shared__ double sm[4];
  double s = 0.0;
  for (int i = threadIdx.x; i < 1024; i += 256) s += (double)part[i];
  #pragma unroll
  for (int off = 32; off; off >>= 1) s += __shfl_down(s, off);
  int lane = threadIdx.x & 63, wv = threadIdx.x >> 6;
  if (lane == 0) sm[wv] = s;
  __syncthreads();
  if (threadIdx.x == 0) {
    float nv = (float)(sm[0] + sm[1] + sm[2] + sm[3]);
    if (init) { sc[0] = nv; sc[1] = 0.f; sc[2] = 0.f; sc[3] = 0.f; }
    else {
      bool cont = sc[3] != 0.f;
      sc[2] = cont ? nv / sc[0] : 0.f;
      sc[0] = nv;  // if !cont, nv == old rTr bitwise (alpha was 0)
    }
  }
}

__global__ __launch_bounds__(256) void k_update1(
    float2* __restrict__ x, float2* __restrict__ r,
    const float2* __restrict__ p, const float2* __restrict__ Ap,
    const float* __restrict__ sc, float* __restrict__ part)
{
  __shared__ float sm[4];
  const float alpha = sc[1];
  const int t = threadIdx.x;
  const int base = blockIdx.x * 512;
  float s = 0.f;
  #pragma unroll
  for (int e = 0; e < 2; ++e) {
    int idx = base + t + (e << 8);
    float2 pv = p[idx], av = Ap[idx], xv = x[idx], rv = r[idx];
    xv.x = fmaf(alpha, pv.x, xv.x); xv.y = fmaf(alpha, pv.y, xv.y);
    rv.x = fmaf(-alpha, av.x, rv.x); rv.y = fmaf(-alpha, av.y, rv.y);
    x[idx] = xv; r[idx] = rv;
    s = fmaf(rv.x, rv.x, fmaf(rv.y, rv.y, s));
  }
  float tot = blockRed256(s, sm);
  if (t == 0) part[blockIdx.x] = tot;
}

__global__ __launch_bounds__(256) void k_update2(
    float2* __restrict__ p, const float2* __restrict__ r, const float* __restrict__ sc)
{
  if (sc[3] == 0.f) return;  // uniform: p unchanged when !cont
  const float beta = sc[2];
  const int t = threadIdx.x;
  const int base = blockIdx.x * 512;
  #pragma unroll
  for (int e = 0; e < 2; ++e) {
    int idx = base + t + (e << 8);
    float2 pv = p[idx], rv = r[idx];
    p[idx] = make_float2(fmaf(beta, pv.x, rv.x), fmaf(beta, pv.y, rv.y));
  }
}

__global__ __launch_bounds__(256) void k_final(const float2* __restrict__ x,
                                               float* __restrict__ out) {
  const int t = threadIdx.x;
  const int base = blockIdx.x * 512;
  #pragma unroll
  for (int e = 0; e < 2; ++e) {
    int idx = base + t + (e << 8);
    int b = idx >> 16, pix = idx & 65535;
    float2 v = x[idx];
    out[(b << 17) + pix] = v.x;
    out[(b << 17) + 65536 + pix] = v.y;
  }
}

// ---------------- driver ----------------
extern "C" void kernel_launch(void* const* d_in, const int* in_sizes, int n_in,
                              void* d_out, int out_size, void* d_ws, size_t ws_size,
                              hipStream_t stream) {
  (void)in_sizes; (void)n_in; (void)out_size; (void)ws_size;
  const float* atb   = (const float*)d_in[0];
  const float* csm_r = (const float*)d_in[1];
  const float* csm_i = (const float*)d_in[2];
  const float* mask  = (const float*)d_in[3];
  const float* w1 = (const float*)d_in[4];  const float* b1 = (const float*)d_in[5];
  const float* w2 = (const float*)d_in[6];  const float* b2 = (const float*)d_in[7];
  const float* w3 = (const float*)d_in[8];  const float* b3 = (const float*)d_in[9];
  const float* w4 = (const float*)d_in[10]; const float* b4 = (const float*)d_in[11];
  const float* w5 = (const float*)d_in[12]; const float* b5 = (const float*)d_in[13];
  const float* lam = (const float*)d_in[14];

  char* ws = (char*)d_ws;
  // layout (bytes). conv ping-pong buffers alias the coil region (used later).
  float2* coil = (float2*)ws;                        // 8*12*65536*8 = 50331648
  float*  actA = (float*)ws;                         // 64*65536*4 = 16777216
  float*  actB = (float*)(ws + 16777216);            // 16777216
  float2* rhs  = (float2*)(ws + 50331648);           // 4194304
  float2* x    = (float2*)(ws + 54525952);
  float2* r    = (float2*)(ws + 58720256);
  float2* p    = (float2*)(ws + 62914560);
  float2* Ap   = (float2*)(ws + 67108864);
  float*  wT   = (float*)(ws + 71303168);            // 112896 floats
  float*  w1T = wT;            float* w2T = wT + 1152;
  float*  w3T = wT + 38016;    float* w4T = wT + 74880;
  float*  w5T = wT + 111744;
  float2* tw   = (float2*)(ws + 71754752);           // 256 float2
  float*  part = (float*)(ws + 71756800);            // 4096 floats: [0,2048)=denom, [2048,3072)=rtr
  float*  sc   = (float*)(ws + 71773184);            // scalars

  // prep
  k_twiddle<<<1, 256, 0, stream>>>(tw);
  k_transpose_w<<<(1152 + 255) / 256, 256, 0, stream>>>(w1, w1T, 2, 64);
  k_transpose_w<<<(36864 + 255) / 256, 256, 0, stream>>>(w2, w2T, 64, 64);
  k_transpose_w<<<(36864 + 255) / 256, 256, 0, stream>>>(w3, w3T, 64, 64);
  k_transpose_w<<<(36864 + 255) / 256, 256, 0, stream>>>(w4, w4T, 64, 64);
  k_transpose_w<<<(1152 + 255) / 256, 256, 0, stream>>>(w5, w5T, 64, 2);

  // CNN + rhs, per batch item (buffers alias coil region)
  const dim3 cgrid(16, 16);
  for (int b = 0; b < 8; ++b) {
    const float* atb_b = atb + (size_t)b * 2 * HWSZ;
    k_conv<2, 1><<<cgrid, 256, 0, stream>>>(atb_b, w1T, b1, actA);
    k_conv<64, 1><<<cgrid, 256, 0, stream>>>(actA, w2T, b2, actB);
    k_conv<64, 1><<<cgrid, 256, 0, stream>>>(actB, w3T, b3, actA);
    k_conv<64, 1><<<cgrid, 256, 0, stream>>>(actA, w4T, b4, actB);
    k_conv5_rhs<<<cgrid, 256, 0, stream>>>(actB, w5T, b5, atb_b, lam, rhs + (size_t)b * HWSZ);
  }

  // CG init
  k_cg_init<<<1024, 256, 0, stream>>>(rhs, x, r, p, part + 2048);
  k_reduce_rtr<<<1, 256, 0, stream>>>(part + 2048, sc, 1);

  for (int it = 0; it < 11; ++it) {
    k_coil_fft_rows<<<dim3(96, 128), 256, 0, stream>>>(p, csm_r, csm_i, tw, coil);
    k_fft_cols_mask<<<dim3(96, 16), 256, 0, stream>>>(coil, mask, tw);
    k_ifft_rows_acc<<<dim3(8, 256), 128, 0, stream>>>(coil, csm_r, csm_i, p, lam, tw, Ap, part);
    k_reduce_alpha<<<1, 256, 0, stream>>>(part, sc);
    k_update1<<<1024, 256, 0, stream>>>(x, r, p, Ap, sc, part + 2048);
    k_reduce_rtr<<<1, 256, 0, stream>>>(part + 2048, sc, 0);
    k_update2<<<1024, 256, 0, stream>>>(p, r, sc);
  }

  k_final<<<1024, 256, 0, stream>>>(x, (float*)d_out);
}

// Round 2
// 1789.468 us; speedup vs baseline: 3.9995x; 3.9995x over previous
//
#include <hip/hip_runtime.h>
#include <hip/hip_bf16.h>
#include <math.h>

static constexpr int NCOIL = 12;
static constexpr int HWSZ  = 65536;   // 256*256

typedef short v8s __attribute__((ext_vector_type(8)));
typedef float v4f __attribute__((ext_vector_type(4)));

__device__ __forceinline__ unsigned short f2bf(float v) {
  __hip_bfloat16 h = __float2bfloat16(v);
  union { __hip_bfloat16 h; unsigned short u; } cv; cv.h = h; return cv.u;
}
__device__ __forceinline__ float bf2f(unsigned short u) {
  return __uint_as_float(((unsigned)u) << 16);
}

// ---------------- complex helpers ----------------
__device__ __forceinline__ float2 cmulf(float2 a, float2 b) {
  return make_float2(a.x * b.x - a.y * b.y, a.x * b.y + a.y * b.x);
}
__device__ __forceinline__ float2 caddf(float2 a, float2 b) {
  return make_float2(a.x + b.x, a.y + b.y);
}
__device__ __forceinline__ float2 csubf(float2 a, float2 b) {
  return make_float2(a.x - b.x, a.y - b.y);
}

// ---------------- prep kernels ----------------
__global__ void k_twiddle(float2* __restrict__ tw) {
  int t = threadIdx.x;
  if (t == 0) { tw[0] = make_float2(1.f, 0.f); return; }
  int l = 1 << (31 - __clz(t));
  int j = t - l;
  float ang = -3.14159265358979323846f * (float)j / (float)l;
  float s, c;
  sincosf(ang, &s, &c);
  tw[t] = make_float2(c, s);
}

// w [OC][IC][3][3] -> wT [IC*9][OC]  (fp32, for layers 1 and 5)
__global__ void k_transpose_w(const float* __restrict__ w, float* __restrict__ wT,
                              int IC, int OC) {
  int i = blockIdx.x * 256 + threadIdx.x;
  int total = IC * 9 * OC;
  if (i >= total) return;
  int oc = i % OC;
  int rest = i / OC;            // ic*9 + k
  int ic = rest / 9, k = rest - ic * 9;
  wT[i] = w[(oc * IC + ic) * 9 + k];
}

// w [64][64][3][3] fp32 -> B-fragment order bf16: [ks=18][ocg=4][lane=64][j=8]
// K index = tap*64 + ic ; ks = tap*2 + (ic>=32) ; within chunk: ic = (ks&1)*32+(lane>>4)*8+j
__global__ void k_bfrag(const float* __restrict__ w, unsigned short* __restrict__ bf) {
  int i = blockIdx.x * 256 + threadIdx.x;   // 18*4*64*8 = 36864
  if (i >= 36864) return;
  int j = i & 7, lane = (i >> 3) & 63, ocg = (i >> 9) & 3, ks = i >> 11;
  int oc = (ocg << 4) + (lane & 15);
  int ic = ((ks & 1) << 5) + (((lane >> 4) & 3) << 3) + j;
  int tap = ks >> 1;
  bf[i] = f2bf(w[(oc * 64 + ic) * 9 + tap]);
}

// ---------------- layer 1: fp32 direct conv (IC=2), out pixel-major bf16 ----------------
__global__ __launch_bounds__(256) void k_conv1(
    const float* __restrict__ atb,   // [img][2][256][256] (base of this half-batch)
    const float* __restrict__ w1T,   // [18][64]
    const float* __restrict__ b1,
    unsigned short* __restrict__ out)// [img][256][256][64] bf16
{
  __shared__ float patch[2 * 324];
  const int t = threadIdx.x;
  const int img = blockIdx.z;
  const float* in = atb + (size_t)img * 131072;
  const int tx0 = blockIdx.x << 4, ty0 = blockIdx.y << 4;
  for (int i = t; i < 648; i += 256) {
    int ic = i / 324, rem = i - ic * 324;
    int py = rem / 18, px = rem - py * 18;
    int gy = ty0 + py - 1, gx = tx0 + px - 1;
    float v = 0.f;
    if ((unsigned)gy < 256u && (unsigned)gx < 256u)
      v = in[(ic << 16) + (gy << 8) + gx];
    patch[i] = v;
  }
  __syncthreads();
  const int tx = t & 15, ty = t >> 4;
  float acc[64];
  #pragma unroll
  for (int o = 0; o < 64; ++o) acc[o] = 0.f;
  #pragma unroll
  for (int ic = 0; ic < 2; ++ic) {
    const float* pb = &patch[ic * 324 + ty * 18 + tx];
    #pragma unroll
    for (int k = 0; k < 9; ++k) {
      const float v = pb[(k / 3) * 18 + (k % 3)];
      const float* wr = &w1T[(ic * 9 + k) << 6];
      #pragma unroll
      for (int o = 0; o < 64; ++o) acc[o] = fmaf(v, wr[o], acc[o]);
    }
  }
  size_t obase = ((size_t)img << 22) + ((size_t)(((ty0 + ty) << 8) + tx0 + tx) << 6);
  v8s* outv = (v8s*)(out + obase);
  #pragma unroll
  for (int g = 0; g < 8; ++g) {
    v8s ov;
    #pragma unroll
    for (int j = 0; j < 8; ++j) {
      float v = fmaxf(acc[(g << 3) + j] + b1[(g << 3) + j], 0.f);
      ov[j] = (short)f2bf(v);
    }
    outv[g] = ov;
  }
}

// ---------------- layers 2-4: bf16 MFMA implicit GEMM ----------------
// in/out pixel-major bf16 [img][256][256][64]; bfrag [18][4][64][8]
__global__ __launch_bounds__(256, 3) void k_conv_mfma(
    const unsigned short* __restrict__ in,
    const unsigned short* __restrict__ bfrag,
    const float* __restrict__ bias,
    unsigned short* __restrict__ out)
{
  __shared__ v8s halo[1440];   // [10 rows][18 cols][8 slots of 8ch] swizzled, 23040 B
  char* hb = (char*)halo;
  const int t = threadIdx.x;
  const int img = blockIdx.z;
  const int tx0 = blockIdx.x << 4, ty0 = blockIdx.y << 3;   // tile 16x8
  const size_t ibase = ((size_t)img << 22);
  // stage halo: 10x18 pixels x 64ch bf16, 16B chunks, XOR-swizzled slots
  for (int c = t; c < 1440; c += 256) {
    int hy = c / 144, rem = c - hy * 144;
    int hx = rem >> 3, slot = rem & 7;
    int gy = ty0 + hy - 1, gx = tx0 + hx - 1;
    v8s v = {0, 0, 0, 0, 0, 0, 0, 0};
    if ((unsigned)gy < 256u && (unsigned)gx < 256u)
      v = *(const v8s*)(in + ibase + ((size_t)((gy << 8) + gx) << 6) + (slot << 3));
    int xl = hy * 18 + hx;
    *(v8s*)(hb + xl * 128 + ((slot ^ (xl & 7)) << 4)) = v;
  }
  __syncthreads();
  const int lane = t & 63, w = t >> 6;
  const int wy = w >> 1, wx = w & 1;    // wy: pixel half (4 rows), wx: oc half (32)
  const int px = lane & 15, lg = lane >> 4;
  v4f acc[4][2];
  #pragma unroll
  for (int pf = 0; pf < 4; ++pf)
    #pragma unroll
    for (int og = 0; og < 2; ++og)
      #pragma unroll
      for (int rg = 0; rg < 4; ++rg) acc[pf][og][rg] = 0.f;

  #pragma unroll
  for (int ks = 0; ks < 18; ++ks) {
    const int tap = ks >> 1;
    const int dy = tap / 3, dx = tap - dy * 3;
    const int slot = ((ks & 1) << 2) | lg;
    v8s b0 = *(const v8s*)(bfrag + ((((ks << 2) | (wx << 1)) * 64 + lane) << 3));
    v8s b1 = *(const v8s*)(bfrag + ((((ks << 2) | (wx << 1) | 1) * 64 + lane) << 3));
    const int xbase = (wy * 4 + dy) * 18 + px + dx;
    #pragma unroll
    for (int pf = 0; pf < 4; ++pf) {
      int xl = xbase + pf * 18;
      v8s a = *(const v8s*)(hb + xl * 128 + ((slot ^ (xl & 7)) << 4));
      acc[pf][0] = __builtin_amdgcn_mfma_f32_16x16x32_bf16(a, b0, acc[pf][0], 0, 0, 0);
      acc[pf][1] = __builtin_amdgcn_mfma_f32_16x16x32_bf16(a, b1, acc[pf][1], 0, 0, 0);
    }
  }
  // epilogue: C layout col=lane&15 (oc), row=(lane>>4)*4+reg (px)
  const int ocl = lane & 15;
  const float bv0 = bias[(wx << 5) + ocl];
  const float bv1 = bias[(wx << 5) + 16 + ocl];
  #pragma unroll
  for (int pf = 0; pf < 4; ++pf) {
    const int gy = ty0 + wy * 4 + pf;
    #pragma unroll
    for (int og = 0; og < 2; ++og) {
      const int oc = (wx << 5) + (og << 4) + ocl;
      const float bv = og ? bv1 : bv0;
      #pragma unroll
      for (int rg = 0; rg < 4; ++rg) {
        float v = fmaxf(acc[pf][og][rg] + bv, 0.f);
        int gx = tx0 + (lg << 2) + rg;
        out[ibase + ((size_t)((gy << 8) + gx) << 6) + oc] = f2bf(v);
      }
    }
  }
}

// ---------------- layer 5 (64->2) + rhs = atb + lam*(atb + conv5) ----------------
__global__ __launch_bounds__(128) void k_conv5_rhs(
    const unsigned short* __restrict__ in,  // pixel-major bf16
    const float* __restrict__ w5T,          // [ic*9+tap][2]
    const float* __restrict__ b5,
    const float* __restrict__ atb,          // base of this half-batch
    const float* __restrict__ lam,
    float2* __restrict__ rhs)               // base of this half-batch
{
  __shared__ v8s halo[1440];
  char* hb = (char*)halo;
  const int t = threadIdx.x;
  const int img = blockIdx.z;
  const int tx0 = blockIdx.x << 4, ty0 = blockIdx.y << 3;
  const size_t ibase = ((size_t)img << 22);
  for (int c = t; c < 1440; c += 128) {
    int hy = c / 144, rem = c - hy * 144;
    int hx = rem >> 3, slot = rem & 7;
    int gy = ty0 + hy - 1, gx = tx0 + hx - 1;
    v8s v = {0, 0, 0, 0, 0, 0, 0, 0};
    if ((unsigned)gy < 256u && (unsigned)gx < 256u)
      v = *(const v8s*)(in + ibase + ((size_t)((gy << 8) + gx) << 6) + (slot << 3));
    int xl = hy * 18 + hx;
    *(v8s*)(hb + xl * 128 + ((slot ^ (xl & 7)) << 4)) = v;
  }
  __syncthreads();
  const int px = t & 15, py = t >> 4;
  float a0 = 0.f, a1 = 0.f;
  #pragma unroll
  for (int tap = 0; tap < 9; ++tap) {
    const int dy = tap / 3, dx = tap - dy * 3;
    const int xl = (py + dy) * 18 + px + dx;
    #pragma unroll
    for (int s8 = 0; s8 < 8; ++s8) {
      v8s a = *(const v8s*)(hb + xl * 128 + ((s8 ^ (xl & 7)) << 4));
      #pragma unroll
      for (int j = 0; j < 8; ++j) {
        float av = bf2f((unsigned short)a[j]);
        const float* wp = w5T + ((((s8 << 3) + j) * 9 + tap) << 1);
        a0 = fmaf(av, wp[0], a0);
        a1 = fmaf(av, wp[1], a1);
      }
    }
  }
  const int pix = ((ty0 + py) << 8) + tx0 + px;
  const float l = *lam;
  const float x0 = atb[(size_t)img * 131072 + pix];
  const float x1 = atb[(size_t)img * 131072 + 65536 + pix];
  const float d0 = a0 + b5[0], d1 = a1 + b5[1];
  rhs[(size_t)img * 65536 + pix] =
      make_float2(fmaf(l, x0 + d0, x0), fmaf(l, x1 + d1, x1));
}

// ---------------- AtA pass 1: coil = csm * p, FFT along rows (W) ----------------
__global__ __launch_bounds__(256) void k_coil_fft_rows(
    const float2* __restrict__ p, const float* __restrict__ csm_r,
    const float* __restrict__ csm_i, const float2* __restrict__ tw,
    float2* __restrict__ coil)
{
  __shared__ float2 lds[1024];
  const int t = threadIdx.x;
  const int bc = blockIdx.x;
  const int b = bc / NCOIL;
  const int h0 = blockIdx.y << 1;
  #pragma unroll
  for (int e = 0; e < 2; ++e) {
    int idx = t + (e << 8);
    int lr = idx >> 8, w = idx & 255;
    int gi = (bc << 16) + ((h0 + lr) << 8) + w;
    int pi = (b << 16) + ((h0 + lr) << 8) + w;
    float cr = csm_r[gi], ci = csm_i[gi];
    float2 pv = p[pi];
    lds[(lr << 8) + w] = make_float2(cr * pv.x - ci * pv.y, cr * pv.y + ci * pv.x);
  }
  __syncthreads();
  const int lr = t >> 7, bf = t & 127;
  float2* src = lds; float2* dst = lds + 512;
  #pragma unroll
  for (int s = 0; s < 8; ++s) {
    const int m = 1 << s;
    float2 a = src[(lr << 8) + bf];
    float2 bb = src[(lr << 8) + bf + 128];
    float2 w = tw[(128 + bf) >> s];
    int o0 = bf + (bf & ~(m - 1));
    dst[(lr << 8) + o0] = caddf(a, bb);
    dst[(lr << 8) + o0 + m] = cmulf(csubf(a, bb), w);
    float2* tmp = src; src = dst; dst = tmp;
    __syncthreads();
  }
  #pragma unroll
  for (int e = 0; e < 2; ++e) {
    int idx = t + (e << 8);
    int lr2 = idx >> 8, w = idx & 255;
    coil[(bc << 16) + ((h0 + lr2) << 8) + w] = src[(lr2 << 8) + w];
  }
}

// ---------------- AtA pass 2: FFT cols (H), mask, IFFT cols ----------------
__global__ __launch_bounds__(256) void k_fft_cols_mask(
    float2* __restrict__ coil, const float* __restrict__ mask,
    const float2* __restrict__ tw)
{
  __shared__ float2 lds[2 * 256 * 17];
  const int t = threadIdx.x;
  const int bc = blockIdx.x;
  const int b = bc / NCOIL;
  const int w0 = blockIdx.y << 4;
  const int base = bc << 16;
  for (int i = 0; i < 16; ++i) {
    int idx = t + (i << 8);
    int h = idx >> 4, col = idx & 15;
    lds[h * 17 + col] = coil[base + (h << 8) + w0 + col];
  }
  __syncthreads();
  const int col = t & 15, bfb = t >> 4;
  float2* src = lds; float2* dst = lds + 256 * 17;
  #pragma unroll
  for (int s = 0; s < 8; ++s) {
    const int m = 1 << s;
    #pragma unroll
    for (int rr = 0; rr < 8; ++rr) {
      int bf = bfb + (rr << 4);
      float2 a = src[bf * 17 + col];
      float2 bb = src[(bf + 128) * 17 + col];
      float2 w = tw[(128 + bf) >> s];
      int o0 = bf + (bf & ~(m - 1));
      dst[o0 * 17 + col] = caddf(a, bb);
      dst[(o0 + m) * 17 + col] = cmulf(csubf(a, bb), w);
    }
    float2* tmp = src; src = dst; dst = tmp;
    __syncthreads();
  }
  for (int i = 0; i < 16; ++i) {
    int idx = t + (i << 8);
    int h = idx >> 4, cl = idx & 15;
    float mv = mask[(b << 16) + (h << 8) + w0 + cl];
    float2 v = src[h * 17 + cl];
    src[h * 17 + cl] = make_float2(v.x * mv, v.y * mv);
  }
  __syncthreads();
  #pragma unroll
  for (int s = 0; s < 8; ++s) {
    const int m = 1 << s;
    #pragma unroll
    for (int rr = 0; rr < 8; ++rr) {
      int bf = bfb + (rr << 4);
      float2 a = src[bf * 17 + col];
      float2 bb = src[(bf + 128) * 17 + col];
      float2 w = tw[(128 + bf) >> s]; w.y = -w.y;
      int o0 = bf + (bf & ~(m - 1));
      dst[o0 * 17 + col] = caddf(a, bb);
      dst[(o0 + m) * 17 + col] = cmulf(csubf(a, bb), w);
    }
    float2* tmp = src; src = dst; dst = tmp;
    __syncthreads();
  }
  const float sc = 1.f / 256.f;
  for (int i = 0; i < 16; ++i) {
    int idx = t + (i << 8);
    int h = idx >> 4, cl = idx & 15;
    float2 v = src[h * 17 + cl];
    coil[base + (h << 8) + w0 + cl] = make_float2(v.x * sc, v.y * sc);
  }
}

// ------- AtA pass 3: IFFT rows, conj(csm) combine, +lam*p, denom partials -------
__global__ __launch_bounds__(128) void k_ifft_rows_acc(
    const float2* __restrict__ coil, const float* __restrict__ csm_r,
    const float* __restrict__ csm_i, const float2* __restrict__ p,
    const float* __restrict__ lam, const float2* __restrict__ tw,
    float2* __restrict__ Ap, float* __restrict__ partials)
{
  __shared__ float2 lds[512];
  __shared__ float red[2];
  const int t = threadIdx.x;
  const int b = blockIdx.x, h = blockIdx.y;
  float2 acc0 = make_float2(0.f, 0.f), acc1 = make_float2(0.f, 0.f);
  for (int c = 0; c < NCOIL; ++c) {
    const int base = ((b * NCOIL + c) << 16) + (h << 8);
    lds[t] = coil[base + t];
    lds[t + 128] = coil[base + t + 128];
    __syncthreads();
    float2* src = lds; float2* dst = lds + 256;
    #pragma unroll
    for (int s = 0; s < 8; ++s) {
      const int m = 1 << s;
      float2 a = src[t], bb = src[t + 128];
      float2 w = tw[(128 + t) >> s]; w.y = -w.y;
      int o0 = t + (t & ~(m - 1));
      dst[o0] = caddf(a, bb);
      dst[o0 + m] = cmulf(csubf(a, bb), w);
      float2* tmp = src; src = dst; dst = tmp;
      __syncthreads();
    }
    {
      float2 z = src[t];
      float cr = csm_r[base + t], ci = csm_i[base + t];
      acc0.x += cr * z.x + ci * z.y;
      acc0.y += cr * z.y - ci * z.x;
      float2 z2 = src[t + 128];
      float cr2 = csm_r[base + t + 128], ci2 = csm_i[base + t + 128];
      acc1.x += cr2 * z2.x + ci2 * z2.y;
      acc1.y += cr2 * z2.y - ci2 * z2.x;
    }
    __syncthreads();
  }
  const float inv = 1.f / 256.f;
  const float l = *lam;
  float dp = 0.f;
  {
    int pi = (b << 16) + (h << 8) + t;
    float2 pv = p[pi];
    float2 apv = make_float2(fmaf(l, pv.x, acc0.x * inv), fmaf(l, pv.y, acc0.y * inv));
    Ap[pi] = apv;
    dp += pv.x * apv.x + pv.y * apv.y;
    pi += 128;
    float2 pv2 = p[pi];
    float2 apv2 = make_float2(fmaf(l, pv2.x, acc1.x * inv), fmaf(l, pv2.y, acc1.y * inv));
    Ap[pi] = apv2;
    dp += pv2.x * apv2.x + pv2.y * apv2.y;
  }
  #pragma unroll
  for (int off = 32; off; off >>= 1) dp += __shfl_down(dp, off);
  if ((t & 63) == 0) red[t >> 6] = dp;
  __syncthreads();
  if (t == 0) partials[(b << 8) + h] = red[0] + red[1];
}

// ---------------- CG vector + scalar kernels ----------------
__device__ __forceinline__ float blockRed256(float v, float* sm) {
  #pragma unroll
  for (int off = 32; off; off >>= 1) v += __shfl_down(v, off);
  int lane = threadIdx.x & 63, wv = threadIdx.x >> 6;
  if (lane == 0) sm[wv] = v;
  __syncthreads();
  return sm[0] + sm[1] + sm[2] + sm[3];
}

__global__ __launch_bounds__(256) void k_cg_init(
    const float2* __restrict__ rhs, float2* __restrict__ x,
    float2* __restrict__ r, float2* __restrict__ p, float* __restrict__ part)
{
  __shared__ float sm[4];
  const int t = threadIdx.x;
  const int base = blockIdx.x * 512;
  float s = 0.f;
  #pragma unroll
  for (int e = 0; e < 2; ++e) {
    int idx = base + t + (e << 8);
    float2 v = rhs[idx];
    x[idx] = make_float2(0.f, 0.f);
    r[idx] = v; p[idx] = v;
    s = fmaf(v.x, v.x, fmaf(v.y, v.y, s));
  }
  float tot = blockRed256(s, sm);
  if (t == 0) part[blockIdx.x] = tot;
}

// sc[0]=rTr, sc[1]=alpha, sc[2]=beta, sc[3]=cont
__global__ void k_reduce_alpha(const float* __restrict__ part, float* __restrict__ sc) {
  __shared__ double sm[4];
  double s = 0.0;
  for (int i = threadIdx.x; i < 2048; i += 256) s += (double)part[i];
  #pragma unroll
  for (int off = 32; off; off >>= 1) s += __shfl_down(s, off);
  int lane = threadIdx.x & 63, wv = threadIdx.x >> 6;
  if (lane == 0) sm[wv] = s;
  __syncthreads();
  if (threadIdx.x == 0) {
    float denom = (float)(sm[0] + sm[1] + sm[2] + sm[3]);
    float rTr = sc[0];
    bool cont = rTr > 1e-10f;
    sc[1] = cont ? rTr / denom : 0.f;
    sc[3] = cont ? 1.f : 0.f;
  }
}

__global__ void k_reduce_rtr(const float* __restrict__ part, float* __restrict__ sc, int init) {
  __shared__ double sm[4];
  double s = 0.0;
  for (int i = threadIdx.x; i < 1024; i += 256) s += (double)part[i];
  #pragma unroll
  for (int off = 32; off; off >>= 1) s += __shfl_down(s, off);
  int lane = threadIdx.x & 63, wv = threadIdx.x >> 6;
  if (lane == 0) sm[wv] = s;
  __syncthreads();
  if (threadIdx.x == 0) {
    float nv = (float)(sm[0] + sm[1] + sm[2] + sm[3]);
    if (init) { sc[0] = nv; sc[1] = 0.f; sc[2] = 0.f; sc[3] = 0.f; }
    else {
      bool cont = sc[3] != 0.f;
      sc[2] = cont ? nv / sc[0] : 0.f;
      sc[0] = nv;
    }
  }
}

__global__ __launch_bounds__(256) void k_update1(
    float2* __restrict__ x, float2* __restrict__ r,
    const float2* __restrict__ p, const float2* __restrict__ Ap,
    const float* __restrict__ sc, float* __restrict__ part)
{
  __shared__ float sm[4];
  const float alpha = sc[1];
  const int t = threadIdx.x;
  const int base = blockIdx.x * 512;
  float s = 0.f;
  #pragma unroll
  for (int e = 0; e < 2; ++e) {
    int idx = base + t + (e << 8);
    float2 pv = p[idx], av = Ap[idx], xv = x[idx], rv = r[idx];
    xv.x = fmaf(alpha, pv.x, xv.x); xv.y = fmaf(alpha, pv.y, xv.y);
    rv.x = fmaf(-alpha, av.x, rv.x); rv.y = fmaf(-alpha, av.y, rv.y);
    x[idx] = xv; r[idx] = rv;
    s = fmaf(rv.x, rv.x, fmaf(rv.y, rv.y, s));
  }
  float tot = blockRed256(s, sm);
  if (t == 0) part[blockIdx.x] = tot;
}

__global__ __launch_bounds__(256) void k_update2(
    float2* __restrict__ p, const float2* __restrict__ r, const float* __restrict__ sc)
{
  if (sc[3] == 0.f) return;
  const float beta = sc[2];
  const int t = threadIdx.x;
  const int base = blockIdx.x * 512;
  #pragma unroll
  for (int e = 0; e < 2; ++e) {
    int idx = base + t + (e << 8);
    float2 pv = p[idx], rv = r[idx];
    p[idx] = make_float2(fmaf(beta, pv.x, rv.x), fmaf(beta, pv.y, rv.y));
  }
}

__global__ __launch_bounds__(256) void k_final(const float2* __restrict__ x,
                                               float* __restrict__ out) {
  const int t = threadIdx.x;
  const int base = blockIdx.x * 512;
  #pragma unroll
  for (int e = 0; e < 2; ++e) {
    int idx = base + t + (e << 8);
    int b = idx >> 16, pix = idx & 65535;
    float2 v = x[idx];
    out[(b << 17) + pix] = v.x;
    out[(b << 17) + 65536 + pix] = v.y;
  }
}

// ---------------- driver ----------------
extern "C" void kernel_launch(void* const* d_in, const int* in_sizes, int n_in,
                              void* d_out, int out_size, void* d_ws, size_t ws_size,
                              hipStream_t stream) {
  (void)in_sizes; (void)n_in; (void)out_size; (void)ws_size;
  const float* atb   = (const float*)d_in[0];
  const float* csm_r = (const float*)d_in[1];
  const float* csm_i = (const float*)d_in[2];
  const float* mask  = (const float*)d_in[3];
  const float* w1 = (const float*)d_in[4];  const float* b1 = (const float*)d_in[5];
  const float* w2 = (const float*)d_in[6];  const float* b2 = (const float*)d_in[7];
  const float* w3 = (const float*)d_in[8];  const float* b3 = (const float*)d_in[9];
  const float* w4 = (const float*)d_in[10]; const float* b4 = (const float*)d_in[11];
  const float* w5 = (const float*)d_in[12]; const float* b5 = (const float*)d_in[13];
  const float* lam = (const float*)d_in[14];

  char* ws = (char*)d_ws;
  // CNN phase (per 4-image half): actA@0 (33554432 B), actB@33554432
  unsigned short* actA = (unsigned short*)ws;
  unsigned short* actB = (unsigned short*)(ws + 33554432);
  // CG phase: coil@0 (50331648), then x,r,p,Ap (4x 4194304)
  float2* coil = (float2*)ws;
  float2* x    = (float2*)(ws + 50331648);
  float2* r    = (float2*)(ws + 54525952);
  float2* p    = (float2*)(ws + 58720256);
  float2* Ap   = (float2*)(ws + 62914560);
  float2* rhs  = (float2*)(ws + 67108864);           // 4194304 B (persists)
  float*  w1T  = (float*)(ws + 71303168);            // 4608 B
  float*  w5T  = (float*)(ws + 71307776);            // 4608 B
  unsigned short* bf2 = (unsigned short*)(ws + 71312384);  // 73728 B
  unsigned short* bf3 = (unsigned short*)(ws + 71386112);
  unsigned short* bf4 = (unsigned short*)(ws + 71459840);
  float2* tw   = (float2*)(ws + 71533568);           // 2048 B
  float*  part = (float*)(ws + 71535616);            // 16384 B
  float*  sc   = (float*)(ws + 71552000);

  // prep
  k_twiddle<<<1, 256, 0, stream>>>(tw);
  k_transpose_w<<<5, 256, 0, stream>>>(w1, w1T, 2, 64);
  k_transpose_w<<<5, 256, 0, stream>>>(w5, w5T, 64, 2);
  k_bfrag<<<144, 256, 0, stream>>>(w2, bf2);
  k_bfrag<<<144, 256, 0, stream>>>(w3, bf3);
  k_bfrag<<<144, 256, 0, stream>>>(w4, bf4);

  // CNN: two halves of 4 images each
  for (int half = 0; half < 2; ++half) {
    const float* atb_h = atb + (size_t)half * 4 * 131072;
    float2* rhs_h = rhs + (size_t)half * 4 * 65536;
    k_conv1<<<dim3(16, 16, 4), 256, 0, stream>>>(atb_h, w1T, b1, actA);
    k_conv_mfma<<<dim3(16, 32, 4), 256, 0, stream>>>(actA, bf2, b2, actB);
    k_conv_mfma<<<dim3(16, 32, 4), 256, 0, stream>>>(actB, bf3, b3, actA);
    k_conv_mfma<<<dim3(16, 32, 4), 256, 0, stream>>>(actA, bf4, b4, actB);
    k_conv5_rhs<<<dim3(16, 32, 4), 128, 0, stream>>>(actB, w5T, b5, atb_h, lam, rhs_h);
  }

  // CG init
  k_cg_init<<<1024, 256, 0, stream>>>(rhs, x, r, p, part + 2048);
  k_reduce_rtr<<<1, 256, 0, stream>>>(part + 2048, sc, 1);

  for (int it = 0; it < 11; ++it) {
    k_coil_fft_rows<<<dim3(96, 128), 256, 0, stream>>>(p, csm_r, csm_i, tw, coil);
    k_fft_cols_mask<<<dim3(96, 16), 256, 0, stream>>>(coil, mask, tw);
    k_ifft_rows_acc<<<dim3(8, 256), 128, 0, stream>>>(coil, csm_r, csm_i, p, lam, tw, Ap, part);
    k_reduce_alpha<<<1, 256, 0, stream>>>(part, sc);
    k_update1<<<1024, 256, 0, stream>>>(x, r, p, Ap, sc, part + 2048);
    k_reduce_rtr<<<1, 256, 0, stream>>>(part + 2048, sc, 0);
    k_update2<<<1024, 256, 0, stream>>>(p, r, sc);
  }

  k_final<<<1024, 256, 0, stream>>>(x, (float*)d_out);
}

// Round 3
// 1612.786 us; speedup vs baseline: 4.4377x; 1.1096x over previous
//
#include <hip/hip_runtime.h>
#include <hip/hip_bf16.h>
#include <math.h>

static constexpr int NCOIL = 12;
static constexpr int HWSZ  = 65536;   // 256*256

typedef short v8s __attribute__((ext_vector_type(8)));
typedef float v4f __attribute__((ext_vector_type(4)));

__device__ __forceinline__ unsigned short f2bf(float v) {
  __hip_bfloat16 h = __float2bfloat16(v);
  union { __hip_bfloat16 h; unsigned short u; } cv; cv.h = h; return cv.u;
}
__device__ __forceinline__ float bf2f(unsigned short u) {
  return __uint_as_float(((unsigned)u) << 16);
}

// ---------------- complex helpers ----------------
__device__ __forceinline__ float2 cmulf(float2 a, float2 b) {
  return make_float2(a.x * b.x - a.y * b.y, a.x * b.y + a.y * b.x);
}
__device__ __forceinline__ float2 caddf(float2 a, float2 b) {
  return make_float2(a.x + b.x, a.y + b.y);
}
__device__ __forceinline__ float2 csubf(float2 a, float2 b) {
  return make_float2(a.x - b.x, a.y - b.y);
}

// ---------------- prep kernels ----------------
__global__ void k_twiddle(float2* __restrict__ tw) {
  int t = threadIdx.x;
  if (t == 0) { tw[0] = make_float2(1.f, 0.f); return; }
  int l = 1 << (31 - __clz(t));
  int j = t - l;
  float ang = -3.14159265358979323846f * (float)j / (float)l;
  float s, c;
  sincosf(ang, &s, &c);
  tw[t] = make_float2(c, s);
}

// w [OC][IC][3][3] -> wT [IC*9][OC]  (fp32, for layer 1)
__global__ void k_transpose_w(const float* __restrict__ w, float* __restrict__ wT,
                              int IC, int OC) {
  int i = blockIdx.x * 256 + threadIdx.x;
  int total = IC * 9 * OC;
  if (i >= total) return;
  int oc = i % OC;
  int rest = i / OC;            // ic*9 + k
  int ic = rest / 9, k = rest - ic * 9;
  wT[i] = w[(oc * IC + ic) * 9 + k];
}

// w [64][64][3][3] fp32 -> B-fragment order bf16: [ks=18][ocg=4][lane=64][j=8]
__global__ void k_bfrag(const float* __restrict__ w, unsigned short* __restrict__ bf) {
  int i = blockIdx.x * 256 + threadIdx.x;   // 18*4*64*8 = 36864
  if (i >= 36864) return;
  int j = i & 7, lane = (i >> 3) & 63, ocg = (i >> 9) & 3, ks = i >> 11;
  int oc = (ocg << 4) + (lane & 15);
  int ic = ((ks & 1) << 5) + (((lane >> 4) & 3) << 3) + j;
  int tap = ks >> 1;
  bf[i] = f2bf(w[(oc * 64 + ic) * 9 + tap]);
}

// w5 [2][64][3][3] -> B-fragment bf16 [ks=18][lane=64][j=8], oc padded 2->16
__global__ void k_bfrag5(const float* __restrict__ w, unsigned short* __restrict__ bf) {
  int i = blockIdx.x * 256 + threadIdx.x;   // 18*64*8 = 9216
  if (i >= 9216) return;
  int j = i & 7, lane = (i >> 3) & 63, ks = i >> 9;
  int oc = lane & 15;
  int ic = ((ks & 1) << 5) + (((lane >> 4) & 3) << 3) + j;
  int tap = ks >> 1;
  bf[i] = (oc < 2) ? f2bf(w[(oc * 64 + ic) * 9 + tap]) : (unsigned short)0;
}

// ---------------- layer 1: fp32 direct conv (IC=2), out pixel-major bf16 ----------------
__global__ __launch_bounds__(256) void k_conv1(
    const float* __restrict__ atb,   // [img][2][256][256] (half-batch base)
    const float* __restrict__ w1T,   // [18][64]
    const float* __restrict__ b1,
    unsigned short* __restrict__ out)// [img][256][256][64] bf16
{
  __shared__ float patch[2 * 324];
  const int t = threadIdx.x;
  const int img = blockIdx.z;
  const float* in = atb + (size_t)img * 131072;
  const int tx0 = blockIdx.x << 4, ty0 = blockIdx.y << 4;
  for (int i = t; i < 648; i += 256) {
    int ic = i / 324, rem = i - ic * 324;
    int py = rem / 18, px = rem - py * 18;
    int gy = ty0 + py - 1, gx = tx0 + px - 1;
    float v = 0.f;
    if ((unsigned)gy < 256u && (unsigned)gx < 256u)
      v = in[(ic << 16) + (gy << 8) + gx];
    patch[i] = v;
  }
  __syncthreads();
  const int tx = t & 15, ty = t >> 4;
  float acc[64];
  #pragma unroll
  for (int o = 0; o < 64; ++o) acc[o] = 0.f;
  #pragma unroll
  for (int ic = 0; ic < 2; ++ic) {
    const float* pb = &patch[ic * 324 + ty * 18 + tx];
    #pragma unroll
    for (int k = 0; k < 9; ++k) {
      const float v = pb[(k / 3) * 18 + (k % 3)];
      const float* wr = &w1T[(ic * 9 + k) << 6];
      #pragma unroll
      for (int o = 0; o < 64; ++o) acc[o] = fmaf(v, wr[o], acc[o]);
    }
  }
  size_t obase = ((size_t)img << 22) + ((size_t)(((ty0 + ty) << 8) + tx0 + tx) << 6);
  v8s* outv = (v8s*)(out + obase);
  #pragma unroll
  for (int g = 0; g < 8; ++g) {
    v8s ov;
    #pragma unroll
    for (int j = 0; j < 8; ++j) {
      float v = fmaxf(acc[(g << 3) + j] + b1[(g << 3) + j], 0.f);
      ov[j] = (short)f2bf(v);
    }
    outv[g] = ov;
  }
}

// ---------------- layers 2-4: bf16 MFMA implicit GEMM (16x16 tile, 8 waves) ----------------
// wave w owns rows {w*2, w*2+1} x 16 px x 64 oc: per ks 2 A-reads, 4 B, 8 MFMA
__global__ __launch_bounds__(512, 4) void k_conv_mfma(
    const unsigned short* __restrict__ in,
    const unsigned short* __restrict__ bfrag,
    const float* __restrict__ bias,
    unsigned short* __restrict__ out)
{
  __shared__ v8s halo[2592];   // 18x18 px x 8 slots of 8ch, swizzled: 41472 B
  char* hb = (char*)halo;
  const int t = threadIdx.x;
  const int img = blockIdx.z;
  const int tx0 = blockIdx.x << 4, ty0 = blockIdx.y << 4;
  const size_t ibase = ((size_t)img << 22);
  for (int c = t; c < 2592; c += 512) {
    int hy = c / 144, rem = c - hy * 144;
    int hx = rem >> 3, slot = rem & 7;
    int gy = ty0 + hy - 1, gx = tx0 + hx - 1;
    v8s v = {0, 0, 0, 0, 0, 0, 0, 0};
    if ((unsigned)gy < 256u && (unsigned)gx < 256u)
      v = *(const v8s*)(in + ibase + ((size_t)((gy << 8) + gx) << 6) + (slot << 3));
    int xl = hy * 18 + hx;
    *(v8s*)(hb + xl * 128 + ((slot ^ (xl & 7)) << 4)) = v;
  }
  __syncthreads();
  const int lane = t & 63, w = t >> 6;
  const int px = lane & 15, lg = lane >> 4;
  v4f acc[2][4];
  #pragma unroll
  for (int pf = 0; pf < 2; ++pf)
    #pragma unroll
    for (int og = 0; og < 4; ++og)
      #pragma unroll
      for (int rg = 0; rg < 4; ++rg) acc[pf][og][rg] = 0.f;

  #pragma unroll
  for (int ks = 0; ks < 18; ++ks) {
    const int tap = ks >> 1;
    const int dy = tap / 3, dx = tap - dy * 3;
    const int slot = ((ks & 1) << 2) | lg;
    v8s b0 = *(const v8s*)(bfrag + ((((ks << 2) | 0) * 64 + lane) << 3));
    v8s b1 = *(const v8s*)(bfrag + ((((ks << 2) | 1) * 64 + lane) << 3));
    v8s b2 = *(const v8s*)(bfrag + ((((ks << 2) | 2) * 64 + lane) << 3));
    v8s b3 = *(const v8s*)(bfrag + ((((ks << 2) | 3) * 64 + lane) << 3));
    #pragma unroll
    for (int pf = 0; pf < 2; ++pf) {
      int xl = (w * 2 + pf + dy) * 18 + px + dx;
      v8s a = *(const v8s*)(hb + xl * 128 + ((slot ^ (xl & 7)) << 4));
      acc[pf][0] = __builtin_amdgcn_mfma_f32_16x16x32_bf16(a, b0, acc[pf][0], 0, 0, 0);
      acc[pf][1] = __builtin_amdgcn_mfma_f32_16x16x32_bf16(a, b1, acc[pf][1], 0, 0, 0);
      acc[pf][2] = __builtin_amdgcn_mfma_f32_16x16x32_bf16(a, b2, acc[pf][2], 0, 0, 0);
      acc[pf][3] = __builtin_amdgcn_mfma_f32_16x16x32_bf16(a, b3, acc[pf][3], 0, 0, 0);
    }
  }
  // C layout: col(lane&15)=oc, row=(lane>>4)*4+reg = pixel-x
  const int ocl = lane & 15;
  float bv[4];
  #pragma unroll
  for (int og = 0; og < 4; ++og) bv[og] = bias[(og << 4) + ocl];
  #pragma unroll
  for (int pf = 0; pf < 2; ++pf) {
    const int gy = ty0 + w * 2 + pf;
    #pragma unroll
    for (int og = 0; og < 4; ++og) {
      const int oc = (og << 4) + ocl;
      #pragma unroll
      for (int rg = 0; rg < 4; ++rg) {
        float v = fmaxf(acc[pf][og][rg] + bv[og], 0.f);
        int gx = tx0 + (lg << 2) + rg;
        out[ibase + ((size_t)((gy << 8) + gx) << 6) + oc] = f2bf(v);
      }
    }
  }
}

// ---------------- layer 5 (64->2, MFMA) + rhs = atb + lam*(atb + conv5) ----------------
__global__ __launch_bounds__(512, 4) void k_conv5_rhs(
    const unsigned short* __restrict__ in,  // pixel-major bf16
    const unsigned short* __restrict__ bf5, // [18][64][8], oc padded to 16
    const float* __restrict__ b5,
    const float* __restrict__ atb,          // half-batch base
    const float* __restrict__ lam,
    float2* __restrict__ rhs)               // half-batch base
{
  __shared__ v8s halo[2592];
  char* hb = (char*)halo;
  const int t = threadIdx.x;
  const int img = blockIdx.z;
  const int tx0 = blockIdx.x << 4, ty0 = blockIdx.y << 4;
  const size_t ibase = ((size_t)img << 22);
  for (int c = t; c < 2592; c += 512) {
    int hy = c / 144, rem = c - hy * 144;
    int hx = rem >> 3, slot = rem & 7;
    int gy = ty0 + hy - 1, gx = tx0 + hx - 1;
    v8s v = {0, 0, 0, 0, 0, 0, 0, 0};
    if ((unsigned)gy < 256u && (unsigned)gx < 256u)
      v = *(const v8s*)(in + ibase + ((size_t)((gy << 8) + gx) << 6) + (slot << 3));
    int xl = hy * 18 + hx;
    *(v8s*)(hb + xl * 128 + ((slot ^ (xl & 7)) << 4)) = v;
  }
  __syncthreads();
  const int lane = t & 63, w = t >> 6;
  const int px = lane & 15, lg = lane >> 4;
  v4f acc[2];
  #pragma unroll
  for (int pf = 0; pf < 2; ++pf)
    #pragma unroll
    for (int rg = 0; rg < 4; ++rg) acc[pf][rg] = 0.f;
  #pragma unroll
  for (int ks = 0; ks < 18; ++ks) {
    const int tap = ks >> 1;
    const int dy = tap / 3, dx = tap - dy * 3;
    const int slot = ((ks & 1) << 2) | lg;
    v8s b = *(const v8s*)(bf5 + (((ks * 64) + lane) << 3));
    #pragma unroll
    for (int pf = 0; pf < 2; ++pf) {
      int xl = (w * 2 + pf + dy) * 18 + px + dx;
      v8s a = *(const v8s*)(hb + xl * 128 + ((slot ^ (xl & 7)) << 4));
      acc[pf] = __builtin_amdgcn_mfma_f32_16x16x32_bf16(a, b, acc[pf], 0, 0, 0);
    }
  }
  const int ocl = lane & 15;
  const float l = *lam;
  const float bsel = b5[ocl & 1];
  #pragma unroll
  for (int pf = 0; pf < 2; ++pf) {
    const int gy = ty0 + w * 2 + pf;
    #pragma unroll
    for (int rg = 0; rg < 4; ++rg) {
      float v = acc[pf][rg] + bsel;        // lane ocl=0: real, ocl=1: imag
      float d1 = __shfl_down(v, 1);
      if (ocl == 0) {
        int gx = tx0 + (lg << 2) + rg;
        int pix = (gy << 8) + gx;
        float x0 = atb[(size_t)img * 131072 + pix];
        float x1 = atb[(size_t)img * 131072 + 65536 + pix];
        rhs[(size_t)img * 65536 + pix] =
            make_float2(fmaf(l, x0 + v, x0), fmaf(l, x1 + d1, x1));
      }
    }
  }
}

// ---------------- AtA pass 1: coil = csm * p, FFT along rows (W) ----------------
__global__ __launch_bounds__(256) void k_coil_fft_rows(
    const float2* __restrict__ p, const float* __restrict__ csm_r,
    const float* __restrict__ csm_i, const float2* __restrict__ tw,
    float2* __restrict__ coil)
{
  __shared__ float2 lds[1024];
  const int t = threadIdx.x;
  const int bc = blockIdx.x;
  const int b = bc / NCOIL;
  const int h0 = blockIdx.y << 1;
  #pragma unroll
  for (int e = 0; e < 2; ++e) {
    int idx = t + (e << 8);
    int lr = idx >> 8, w = idx & 255;
    int gi = (bc << 16) + ((h0 + lr) << 8) + w;
    int pi = (b << 16) + ((h0 + lr) << 8) + w;
    float cr = csm_r[gi], ci = csm_i[gi];
    float2 pv = p[pi];
    lds[(lr << 8) + w] = make_float2(cr * pv.x - ci * pv.y, cr * pv.y + ci * pv.x);
  }
  __syncthreads();
  const int lr = t >> 7, bf = t & 127;
  float2* src = lds; float2* dst = lds + 512;
  #pragma unroll
  for (int s = 0; s < 8; ++s) {
    const int m = 1 << s;
    float2 a = src[(lr << 8) + bf];
    float2 bb = src[(lr << 8) + bf + 128];
    float2 w = tw[(128 + bf) >> s];
    int o0 = bf + (bf & ~(m - 1));
    dst[(lr << 8) + o0] = caddf(a, bb);
    dst[(lr << 8) + o0 + m] = cmulf(csubf(a, bb), w);
    float2* tmp = src; src = dst; dst = tmp;
    __syncthreads();
  }
  #pragma unroll
  for (int e = 0; e < 2; ++e) {
    int idx = t + (e << 8);
    int lr2 = idx >> 8, w = idx & 255;
    coil[(bc << 16) + ((h0 + lr2) << 8) + w] = src[(lr2 << 8) + w];
  }
}

// ---------------- AtA pass 2: FFT cols (H), mask, IFFT cols ----------------
__global__ __launch_bounds__(256) void k_fft_cols_mask(
    float2* __restrict__ coil, const float* __restrict__ mask,
    const float2* __restrict__ tw)
{
  __shared__ float2 lds[2 * 256 * 17];
  const int t = threadIdx.x;
  const int bc = blockIdx.x;
  const int b = bc / NCOIL;
  const int w0 = blockIdx.y << 4;
  const int base = bc << 16;
  for (int i = 0; i < 16; ++i) {
    int idx = t + (i << 8);
    int h = idx >> 4, col = idx & 15;
    lds[h * 17 + col] = coil[base + (h << 8) + w0 + col];
  }
  __syncthreads();
  const int col = t & 15, bfb = t >> 4;
  float2* src = lds; float2* dst = lds + 256 * 17;
  #pragma unroll
  for (int s = 0; s < 8; ++s) {
    const int m = 1 << s;
    #pragma unroll
    for (int rr = 0; rr < 8; ++rr) {
      int bf = bfb + (rr << 4);
      float2 a = src[bf * 17 + col];
      float2 bb = src[(bf + 128) * 17 + col];
      float2 w = tw[(128 + bf) >> s];
      int o0 = bf + (bf & ~(m - 1));
      dst[o0 * 17 + col] = caddf(a, bb);
      dst[(o0 + m) * 17 + col] = cmulf(csubf(a, bb), w);
    }
    float2* tmp = src; src = dst; dst = tmp;
    __syncthreads();
  }
  for (int i = 0; i < 16; ++i) {
    int idx = t + (i << 8);
    int h = idx >> 4, cl = idx & 15;
    float mv = mask[(b << 16) + (h << 8) + w0 + cl];
    float2 v = src[h * 17 + cl];
    src[h * 17 + cl] = make_float2(v.x * mv, v.y * mv);
  }
  __syncthreads();
  #pragma unroll
  for (int s = 0; s < 8; ++s) {
    const int m = 1 << s;
    #pragma unroll
    for (int rr = 0; rr < 8; ++rr) {
      int bf = bfb + (rr << 4);
      float2 a = src[bf * 17 + col];
      float2 bb = src[(bf + 128) * 17 + col];
      float2 w = tw[(128 + bf) >> s]; w.y = -w.y;
      int o0 = bf + (bf & ~(m - 1));
      dst[o0 * 17 + col] = caddf(a, bb);
      dst[(o0 + m) * 17 + col] = cmulf(csubf(a, bb), w);
    }
    float2* tmp = src; src = dst; dst = tmp;
    __syncthreads();
  }
  const float sc = 1.f / 256.f;
  for (int i = 0; i < 16; ++i) {
    int idx = t + (i << 8);
    int h = idx >> 4, cl = idx & 15;
    float2 v = src[h * 17 + cl];
    coil[base + (h << 8) + w0 + cl] = make_float2(v.x * sc, v.y * sc);
  }
}

// ------- AtA pass 3: IFFT rows (2 rows/block), conj(csm) combine, +lam*p, denom partials -------
__global__ __launch_bounds__(256) void k_ifft_rows_acc(
    const float2* __restrict__ coil, const float* __restrict__ csm_r,
    const float* __restrict__ csm_i, const float2* __restrict__ p,
    const float* __restrict__ lam, const float2* __restrict__ tw,
    float2* __restrict__ Ap, float* __restrict__ partials)
{
  __shared__ float2 lds[1024];
  __shared__ float red[4];
  const int t = threadIdx.x;
  const int b = blockIdx.x, h0 = blockIdx.y << 1;
  const int row = t >> 7, bf = t & 127;
  float2 acc0 = make_float2(0.f, 0.f), acc1 = make_float2(0.f, 0.f);
  for (int c = 0; c < NCOIL; ++c) {
    const int gb = ((b * NCOIL + c) << 16) + (h0 << 8);
    lds[t] = coil[gb + t];
    lds[t + 256] = coil[gb + t + 256];
    __syncthreads();
    float2* src = lds; float2* dst = lds + 512;
    #pragma unroll
    for (int s = 0; s < 8; ++s) {
      const int m = 1 << s;
      float2 a = src[(row << 8) + bf], bb = src[(row << 8) + bf + 128];
      float2 w = tw[(128 + bf) >> s]; w.y = -w.y;
      int o0 = bf + (bf & ~(m - 1));
      dst[(row << 8) + o0] = caddf(a, bb);
      dst[(row << 8) + o0 + m] = cmulf(csubf(a, bb), w);
      float2* tmp = src; src = dst; dst = tmp;
      __syncthreads();
    }
    {
      int gi = gb + (row << 8) + bf;
      float2 z = src[(row << 8) + bf];
      float cr = csm_r[gi], ci = csm_i[gi];
      acc0.x += cr * z.x + ci * z.y;
      acc0.y += cr * z.y - ci * z.x;
      float2 z2 = src[(row << 8) + bf + 128];
      float cr2 = csm_r[gi + 128], ci2 = csm_i[gi + 128];
      acc1.x += cr2 * z2.x + ci2 * z2.y;
      acc1.y += cr2 * z2.y - ci2 * z2.x;
    }
    __syncthreads();
  }
  const float inv = 1.f / 256.f;
  const float l = *lam;
  float dp = 0.f;
  {
    int pi = (b << 16) + ((h0 + row) << 8) + bf;
    float2 pv = p[pi];
    float2 apv = make_float2(fmaf(l, pv.x, acc0.x * inv), fmaf(l, pv.y, acc0.y * inv));
    Ap[pi] = apv;
    dp += pv.x * apv.x + pv.y * apv.y;
    pi += 128;
    float2 pv2 = p[pi];
    float2 apv2 = make_float2(fmaf(l, pv2.x, acc1.x * inv), fmaf(l, pv2.y, acc1.y * inv));
    Ap[pi] = apv2;
    dp += pv2.x * apv2.x + pv2.y * apv2.y;
  }
  #pragma unroll
  for (int off = 32; off; off >>= 1) dp += __shfl_down(dp, off);
  if ((t & 63) == 0) red[t >> 6] = dp;
  __syncthreads();
  if (t == 0) partials[(b << 7) + blockIdx.y] = red[0] + red[1] + red[2] + red[3];
}

// ---------------- CG vector kernels (scalar logic folded in) ----------------
__device__ __forceinline__ float blockRed256(float v, float* sm) {
  #pragma unroll
  for (int off = 32; off; off >>= 1) v += __shfl_down(v, off);
  int lane = threadIdx.x & 63, wv = threadIdx.x >> 6;
  if (lane == 0) sm[wv] = v;
  __syncthreads();
  return sm[0] + sm[1] + sm[2] + sm[3];
}

__device__ __forceinline__ void blockRed2(float& a, float& b, float2* sm) {
  #pragma unroll
  for (int off = 32; off; off >>= 1) {
    a += __shfl_down(a, off);
    b += __shfl_down(b, off);
  }
  int lane = threadIdx.x & 63, wv = threadIdx.x >> 6;
  if (lane == 0) sm[wv] = make_float2(a, b);
  __syncthreads();
  float2 s0 = sm[0], s1 = sm[1], s2 = sm[2], s3 = sm[3];
  a = s0.x + s1.x + s2.x + s3.x;
  b = s0.y + s1.y + s2.y + s3.y;
}

__global__ __launch_bounds__(256) void k_cg_init(
    const float2* __restrict__ rhs, float2* __restrict__ x,
    float2* __restrict__ r, float2* __restrict__ p, float* __restrict__ part)
{
  __shared__ float sm[4];
  const int t = threadIdx.x;
  const int base = blockIdx.x * 512;
  float s = 0.f;
  #pragma unroll
  for (int e = 0; e < 2; ++e) {
    int idx = base + t + (e << 8);
    float2 v = rhs[idx];
    x[idx] = make_float2(0.f, 0.f);
    r[idx] = v; p[idx] = v;
    s = fmaf(v.x, v.x, fmaf(v.y, v.y, s));
  }
  float tot = blockRed256(s, sm);
  if (t == 0) part[blockIdx.x] = tot;
}

// x += alpha p; r -= alpha Ap; alpha computed per-block from partials (identical everywhere)
__global__ __launch_bounds__(256) void k_update1(
    float2* __restrict__ x, float2* __restrict__ r,
    const float2* __restrict__ p, const float2* __restrict__ Ap,
    const float* __restrict__ part_d, const float* __restrict__ part_r_old,
    float* __restrict__ part_r_new)
{
  __shared__ float2 sm2[4];
  __shared__ float sm[4];
  const int t = threadIdx.x;
  float sd = 0.f, sr = 0.f;
  for (int i = t; i < 1024; i += 256) { sd += part_d[i]; sr += part_r_old[i]; }
  blockRed2(sd, sr, sm2);
  const bool cont = sr > 1e-10f;
  const float alpha = cont ? sr / sd : 0.f;   // alpha=0 => x,r (and rTr) frozen exactly
  const int base = blockIdx.x * 512;
  float s = 0.f;
  #pragma unroll
  for (int e = 0; e < 2; ++e) {
    int idx = base + t + (e << 8);
    float2 pv = p[idx], av = Ap[idx], xv = x[idx], rv = r[idx];
    xv.x = fmaf(alpha, pv.x, xv.x); xv.y = fmaf(alpha, pv.y, xv.y);
    rv.x = fmaf(-alpha, av.x, rv.x); rv.y = fmaf(-alpha, av.y, rv.y);
    x[idx] = xv; r[idx] = rv;
    s = fmaf(rv.x, rv.x, fmaf(rv.y, rv.y, s));
  }
  float tot = blockRed256(s, sm);
  if (t == 0) part_r_new[blockIdx.x] = tot;
}

// p = r + beta p; beta computed per-block; skipped entirely when !cont
__global__ __launch_bounds__(256) void k_update2(
    float2* __restrict__ p, const float2* __restrict__ r,
    const float* __restrict__ part_r_old, const float* __restrict__ part_r_new)
{
  __shared__ float2 sm2[4];
  const int t = threadIdx.x;
  float so = 0.f, sn = 0.f;
  for (int i = t; i < 1024; i += 256) { so += part_r_old[i]; sn += part_r_new[i]; }
  blockRed2(so, sn, sm2);
  if (!(so > 1e-10f)) return;               // p frozen when !cont
  const float beta = sn / so;
  const int base = blockIdx.x * 512;
  #pragma unroll
  for (int e = 0; e < 2; ++e) {
    int idx = base + t + (e << 8);
    float2 pv = p[idx], rv = r[idx];
    p[idx] = make_float2(fmaf(beta, pv.x, rv.x), fmaf(beta, pv.y, rv.y));
  }
}

__global__ __launch_bounds__(256) void k_final(const float2* __restrict__ x,
                                               float* __restrict__ out) {
  const int t = threadIdx.x;
  const int base = blockIdx.x * 512;
  #pragma unroll
  for (int e = 0; e < 2; ++e) {
    int idx = base + t + (e << 8);
    int b = idx >> 16, pix = idx & 65535;
    float2 v = x[idx];
    out[(b << 17) + pix] = v.x;
    out[(b << 17) + 65536 + pix] = v.y;
  }
}

// ---------------- driver ----------------
extern "C" void kernel_launch(void* const* d_in, const int* in_sizes, int n_in,
                              void* d_out, int out_size, void* d_ws, size_t ws_size,
                              hipStream_t stream) {
  (void)in_sizes; (void)n_in; (void)out_size; (void)ws_size;
  const float* atb   = (const float*)d_in[0];
  const float* csm_r = (const float*)d_in[1];
  const float* csm_i = (const float*)d_in[2];
  const float* mask  = (const float*)d_in[3];
  const float* w1 = (const float*)d_in[4];  const float* b1 = (const float*)d_in[5];
  const float* w2 = (const float*)d_in[6];  const float* b2 = (const float*)d_in[7];
  const float* w3 = (const float*)d_in[8];  const float* b3 = (const float*)d_in[9];
  const float* w4 = (const float*)d_in[10]; const float* b4 = (const float*)d_in[11];
  const float* w5 = (const float*)d_in[12]; const float* b5 = (const float*)d_in[13];
  const float* lam = (const float*)d_in[14];

  char* ws = (char*)d_ws;
  // CNN phase: actA@0 (32 MB), actB@33554432 (32 MB) — alias CG coil/x/r region
  unsigned short* actA = (unsigned short*)ws;
  unsigned short* actB = (unsigned short*)(ws + 33554432);
  // CG phase
  float2* coil = (float2*)ws;                        // 50331648 B
  float2* x    = (float2*)(ws + 50331648);
  float2* r    = (float2*)(ws + 54525952);
  float2* p    = (float2*)(ws + 58720256);
  float2* Ap   = (float2*)(ws + 62914560);
  float2* rhs  = (float2*)(ws + 67108864);           // 4 MB (persists)
  float*  w1T  = (float*)(ws + 71303168);            // 4608 B
  unsigned short* bf2 = (unsigned short*)(ws + 71307776);  // 73728 B each
  unsigned short* bf3 = (unsigned short*)(ws + 71381504);
  unsigned short* bf4 = (unsigned short*)(ws + 71455232);
  unsigned short* bf5 = (unsigned short*)(ws + 71528960);  // 18432 B
  float2* tw   = (float2*)(ws + 71547392);           // 2048 B
  float*  part = (float*)(ws + 71549440);            // part_d 1024 + 12x1024 part_r
  float*  part_d = part;
  float*  part_r = part + 1024;

  // prep
  k_twiddle<<<1, 256, 0, stream>>>(tw);
  k_transpose_w<<<5, 256, 0, stream>>>(w1, w1T, 2, 64);
  k_bfrag<<<144, 256, 0, stream>>>(w2, bf2);
  k_bfrag<<<144, 256, 0, stream>>>(w3, bf3);
  k_bfrag<<<144, 256, 0, stream>>>(w4, bf4);
  k_bfrag5<<<36, 256, 0, stream>>>(w5, bf5);

  // CNN: two halves of 4 images each
  for (int half = 0; half < 2; ++half) {
    const float* atb_h = atb + (size_t)half * 4 * 131072;
    float2* rhs_h = rhs + (size_t)half * 4 * 65536;
    k_conv1<<<dim3(16, 16, 4), 256, 0, stream>>>(atb_h, w1T, b1, actA);
    k_conv_mfma<<<dim3(16, 16, 4), 512, 0, stream>>>(actA, bf2, b2, actB);
    k_conv_mfma<<<dim3(16, 16, 4), 512, 0, stream>>>(actB, bf3, b3, actA);
    k_conv_mfma<<<dim3(16, 16, 4), 512, 0, stream>>>(actA, bf4, b4, actB);
    k_conv5_rhs<<<dim3(16, 16, 4), 512, 0, stream>>>(actB, bf5, b5, atb_h, lam, rhs_h);
  }

  // CG
  k_cg_init<<<1024, 256, 0, stream>>>(rhs, x, r, p, part_r);
  for (int it = 0; it < 11; ++it) {
    k_coil_fft_rows<<<dim3(96, 128), 256, 0, stream>>>(p, csm_r, csm_i, tw, coil);
    k_fft_cols_mask<<<dim3(96, 16), 256, 0, stream>>>(coil, mask, tw);
    k_ifft_rows_acc<<<dim3(8, 128), 256, 0, stream>>>(coil, csm_r, csm_i, p, lam, tw, Ap, part_d);
    k_update1<<<1024, 256, 0, stream>>>(x, r, p, Ap, part_d,
                                        part_r + it * 1024, part_r + (it + 1) * 1024);
    k_update2<<<1024, 256, 0, stream>>>(p, r, part_r + it * 1024, part_r + (it + 1) * 1024);
  }

  k_final<<<1024, 256, 0, stream>>>(x, (float*)d_out);
}

// Round 4
// 1261.383 us; speedup vs baseline: 5.6739x; 1.2786x over previous
//
#include <hip/hip_runtime.h>
#include <hip/hip_bf16.h>
#include <math.h>

static constexpr int NCOIL = 12;
static constexpr int HWSZ  = 65536;   // 256*256

typedef short v8s __attribute__((ext_vector_type(8)));
typedef float v4f __attribute__((ext_vector_type(4)));

__device__ __forceinline__ unsigned short f2bf(float v) {
  __hip_bfloat16 h = __float2bfloat16(v);
  union { __hip_bfloat16 h; unsigned short u; } cv; cv.h = h; return cv.u;
}
__device__ __forceinline__ float bf2f(unsigned short u) {
  return __uint_as_float(((unsigned)u) << 16);
}

// ---------------- complex helpers ----------------
__device__ __forceinline__ float2 cmulf(float2 a, float2 b) {
  return make_float2(a.x * b.x - a.y * b.y, a.x * b.y + a.y * b.x);
}
__device__ __forceinline__ float2 caddf(float2 a, float2 b) {
  return make_float2(a.x + b.x, a.y + b.y);
}
__device__ __forceinline__ float2 csubf(float2 a, float2 b) {
  return make_float2(a.x - b.x, a.y - b.y);
}

// ---------------- in-register 16-pt DFT (four-step building block) ----------------
// TC[j]=cos(pi j/8), TS[j]=-sin(pi j/8)  => W16^j = (TC[j], TS[j])
__device__ __constant__ const float TC16[8] = {
  1.f, 0.92387953f, 0.70710678f, 0.38268343f, 0.f, -0.38268343f, -0.70710678f, -0.92387953f};
__device__ __constant__ const float TS16[8] = {
  0.f, -0.38268343f, -0.70710678f, -0.92387953f, -1.f, -0.92387953f, -0.70710678f, -0.38268343f};
__device__ __constant__ const int REV4[16] = {0,8,4,12,2,10,6,14,1,9,5,13,3,11,7,15};

// DIF: natural input -> output reg r holds X[rev4(r)]
template<int INV>
__device__ __forceinline__ void dif16(float2 v[16]) {
  #pragma unroll
  for (int ls = 0; ls < 4; ++ls) {
    const int len = 16 >> ls, half = len >> 1, step = 1 << ls;
    #pragma unroll
    for (int i = 0; i < 16; i += len) {
      #pragma unroll
      for (int j = 0; j < half; ++j) {
        float2 a = v[i + j], b = v[i + j + half];
        v[i + j] = caddf(a, b);
        float2 d = csubf(a, b);
        float cr = TC16[j * step];
        float ci = INV ? -TS16[j * step] : TS16[j * step];
        v[i + j + half] = make_float2(d.x * cr - d.y * ci, d.x * ci + d.y * cr);
      }
    }
  }
}

// DIT: input reg r holds in[rev4(r)] -> natural-order output
template<int INV>
__device__ __forceinline__ void dit16(float2 v[16]) {
  #pragma unroll
  for (int ls = 0; ls < 4; ++ls) {
    const int len = 2 << ls, half = len >> 1, step = 16 / len;
    #pragma unroll
    for (int i = 0; i < 16; i += len) {
      #pragma unroll
      for (int j = 0; j < half; ++j) {
        float cr = TC16[j * step];
        float ci = INV ? -TS16[j * step] : TS16[j * step];
        float2 b = v[i + j + half];
        float2 tt = make_float2(b.x * cr - b.y * ci, b.x * ci + b.y * cr);
        float2 a = v[i + j];
        v[i + j] = caddf(a, tt);
        v[i + j + half] = csubf(a, tt);
      }
    }
  }
}

// ---------------- prep kernels ----------------
// tw[0:256): Stockham table (rows kernels); tw[256:512): twf[j]=exp(-2pi i j/256)
__global__ void k_twiddle(float2* __restrict__ tw) {
  int t = threadIdx.x;
  {
    float ang = -6.28318530717958647692f * (float)t / 256.f;
    float s, c; sincosf(ang, &s, &c);
    tw[256 + t] = make_float2(c, s);
  }
  if (t == 0) { tw[0] = make_float2(1.f, 0.f); return; }
  int l = 1 << (31 - __clz(t));
  int j = t - l;
  float ang = -3.14159265358979323846f * (float)j / (float)l;
  float s, c; sincosf(ang, &s, &c);
  tw[t] = make_float2(c, s);
}

// w [OC][IC][3][3] -> wT [IC*9][OC]  (fp32, for layer 1)
__global__ void k_transpose_w(const float* __restrict__ w, float* __restrict__ wT,
                              int IC, int OC) {
  int i = blockIdx.x * 256 + threadIdx.x;
  int total = IC * 9 * OC;
  if (i >= total) return;
  int oc = i % OC;
  int rest = i / OC;            // ic*9 + k
  int ic = rest / 9, k = rest - ic * 9;
  wT[i] = w[(oc * IC + ic) * 9 + k];
}

// w [64][64][3][3] fp32 -> B-fragment order bf16: [ks=18][ocg=4][lane=64][j=8]
__global__ void k_bfrag(const float* __restrict__ w, unsigned short* __restrict__ bf) {
  int i = blockIdx.x * 256 + threadIdx.x;   // 18*4*64*8 = 36864
  if (i >= 36864) return;
  int j = i & 7, lane = (i >> 3) & 63, ocg = (i >> 9) & 3, ks = i >> 11;
  int oc = (ocg << 4) + (lane & 15);
  int ic = ((ks & 1) << 5) + (((lane >> 4) & 3) << 3) + j;
  int tap = ks >> 1;
  bf[i] = f2bf(w[(oc * 64 + ic) * 9 + tap]);
}

// w5 [2][64][3][3] -> B-fragment bf16 [ks=18][lane=64][j=8], oc padded 2->16
__global__ void k_bfrag5(const float* __restrict__ w, unsigned short* __restrict__ bf) {
  int i = blockIdx.x * 256 + threadIdx.x;   // 18*64*8 = 9216
  if (i >= 9216) return;
  int j = i & 7, lane = (i >> 3) & 63, ks = i >> 9;
  int oc = lane & 15;
  int ic = ((ks & 1) << 5) + (((lane >> 4) & 3) << 3) + j;
  int tap = ks >> 1;
  bf[i] = (oc < 2) ? f2bf(w[(oc * 64 + ic) * 9 + tap]) : (unsigned short)0;
}

// ---------------- layer 1: fp32 direct conv (IC=2), out pixel-major bf16 ----------------
__global__ __launch_bounds__(256) void k_conv1(
    const float* __restrict__ atb,   // [img][2][256][256] (half-batch base)
    const float* __restrict__ w1T,   // [18][64]
    const float* __restrict__ b1,
    unsigned short* __restrict__ out)// [img][256][256][64] bf16
{
  __shared__ float patch[2 * 324];
  const int t = threadIdx.x;
  const int img = blockIdx.z;
  const float* in = atb + (size_t)img * 131072;
  const int tx0 = blockIdx.x << 4, ty0 = blockIdx.y << 4;
  for (int i = t; i < 648; i += 256) {
    int ic = i / 324, rem = i - ic * 324;
    int py = rem / 18, px = rem - py * 18;
    int gy = ty0 + py - 1, gx = tx0 + px - 1;
    float v = 0.f;
    if ((unsigned)gy < 256u && (unsigned)gx < 256u)
      v = in[(ic << 16) + (gy << 8) + gx];
    patch[i] = v;
  }
  __syncthreads();
  const int tx = t & 15, ty = t >> 4;
  float acc[64];
  #pragma unroll
  for (int o = 0; o < 64; ++o) acc[o] = 0.f;
  #pragma unroll
  for (int ic = 0; ic < 2; ++ic) {
    const float* pb = &patch[ic * 324 + ty * 18 + tx];
    #pragma unroll
    for (int k = 0; k < 9; ++k) {
      const float v = pb[(k / 3) * 18 + (k % 3)];
      const float* wr = &w1T[(ic * 9 + k) << 6];
      #pragma unroll
      for (int o = 0; o < 64; ++o) acc[o] = fmaf(v, wr[o], acc[o]);
    }
  }
  size_t obase = ((size_t)img << 22) + ((size_t)(((ty0 + ty) << 8) + tx0 + tx) << 6);
  v8s* outv = (v8s*)(out + obase);
  #pragma unroll
  for (int g = 0; g < 8; ++g) {
    v8s ov;
    #pragma unroll
    for (int j = 0; j < 8; ++j) {
      float v = fmaxf(acc[(g << 3) + j] + b1[(g << 3) + j], 0.f);
      ov[j] = (short)f2bf(v);
    }
    outv[g] = ov;
  }
}

// ---------------- layers 2-4: bf16 MFMA implicit GEMM (16x16 tile, 8 waves) ----------------
__global__ __launch_bounds__(512, 4) void k_conv_mfma(
    const unsigned short* __restrict__ in,
    const unsigned short* __restrict__ bfrag,
    const float* __restrict__ bias,
    unsigned short* __restrict__ out)
{
  __shared__ v8s halo[2592];   // 18x18 px x 8 slots of 8ch, swizzled: 41472 B
  char* hb = (char*)halo;
  const int t = threadIdx.x;
  const int img = blockIdx.z;
  const int tx0 = blockIdx.x << 4, ty0 = blockIdx.y << 4;
  const size_t ibase = ((size_t)img << 22);
  for (int c = t; c < 2592; c += 512) {
    int hy = c / 144, rem = c - hy * 144;
    int hx = rem >> 3, slot = rem & 7;
    int gy = ty0 + hy - 1, gx = tx0 + hx - 1;
    v8s v = {0, 0, 0, 0, 0, 0, 0, 0};
    if ((unsigned)gy < 256u && (unsigned)gx < 256u)
      v = *(const v8s*)(in + ibase + ((size_t)((gy << 8) + gx) << 6) + (slot << 3));
    int xl = hy * 18 + hx;
    *(v8s*)(hb + xl * 128 + ((slot ^ (xl & 7)) << 4)) = v;
  }
  __syncthreads();
  const int lane = t & 63, w = t >> 6;
  const int px = lane & 15, lg = lane >> 4;
  v4f acc[2][4];
  #pragma unroll
  for (int pf = 0; pf < 2; ++pf)
    #pragma unroll
    for (int og = 0; og < 4; ++og)
      #pragma unroll
      for (int rg = 0; rg < 4; ++rg) acc[pf][og][rg] = 0.f;

  #pragma unroll
  for (int ks = 0; ks < 18; ++ks) {
    const int tap = ks >> 1;
    const int dy = tap / 3, dx = tap - dy * 3;
    const int slot = ((ks & 1) << 2) | lg;
    v8s b0 = *(const v8s*)(bfrag + ((((ks << 2) | 0) * 64 + lane) << 3));
    v8s b1 = *(const v8s*)(bfrag + ((((ks << 2) | 1) * 64 + lane) << 3));
    v8s b2 = *(const v8s*)(bfrag + ((((ks << 2) | 2) * 64 + lane) << 3));
    v8s b3 = *(const v8s*)(bfrag + ((((ks << 2) | 3) * 64 + lane) << 3));
    #pragma unroll
    for (int pf = 0; pf < 2; ++pf) {
      int xl = (w * 2 + pf + dy) * 18 + px + dx;
      v8s a = *(const v8s*)(hb + xl * 128 + ((slot ^ (xl & 7)) << 4));
      acc[pf][0] = __builtin_amdgcn_mfma_f32_16x16x32_bf16(a, b0, acc[pf][0], 0, 0, 0);
      acc[pf][1] = __builtin_amdgcn_mfma_f32_16x16x32_bf16(a, b1, acc[pf][1], 0, 0, 0);
      acc[pf][2] = __builtin_amdgcn_mfma_f32_16x16x32_bf16(a, b2, acc[pf][2], 0, 0, 0);
      acc[pf][3] = __builtin_amdgcn_mfma_f32_16x16x32_bf16(a, b3, acc[pf][3], 0, 0, 0);
    }
  }
  const int ocl = lane & 15;
  float bv[4];
  #pragma unroll
  for (int og = 0; og < 4; ++og) bv[og] = bias[(og << 4) + ocl];
  #pragma unroll
  for (int pf = 0; pf < 2; ++pf) {
    const int gy = ty0 + w * 2 + pf;
    #pragma unroll
    for (int og = 0; og < 4; ++og) {
      const int oc = (og << 4) + ocl;
      #pragma unroll
      for (int rg = 0; rg < 4; ++rg) {
        float v = fmaxf(acc[pf][og][rg] + bv[og], 0.f);
        int gx = tx0 + (lg << 2) + rg;
        out[ibase + ((size_t)((gy << 8) + gx) << 6) + oc] = f2bf(v);
      }
    }
  }
}

// ---------------- layer 5 (64->2, MFMA) + rhs = atb + lam*(atb + conv5) ----------------
__global__ __launch_bounds__(512, 4) void k_conv5_rhs(
    const unsigned short* __restrict__ in,  // pixel-major bf16
    const unsigned short* __restrict__ bf5, // [18][64][8], oc padded to 16
    const float* __restrict__ b5,
    const float* __restrict__ atb,          // half-batch base
    const float* __restrict__ lam,
    float2* __restrict__ rhs)               // half-batch base
{
  __shared__ v8s halo[2592];
  char* hb = (char*)halo;
  const int t = threadIdx.x;
  const int img = blockIdx.z;
  const int tx0 = blockIdx.x << 4, ty0 = blockIdx.y << 4;
  const size_t ibase = ((size_t)img << 22);
  for (int c = t; c < 2592; c += 512) {
    int hy = c / 144, rem = c - hy * 144;
    int hx = rem >> 3, slot = rem & 7;
    int gy = ty0 + hy - 1, gx = tx0 + hx - 1;
    v8s v = {0, 0, 0, 0, 0, 0, 0, 0};
    if ((unsigned)gy < 256u && (unsigned)gx < 256u)
      v = *(const v8s*)(in + ibase + ((size_t)((gy << 8) + gx) << 6) + (slot << 3));
    int xl = hy * 18 + hx;
    *(v8s*)(hb + xl * 128 + ((slot ^ (xl & 7)) << 4)) = v;
  }
  __syncthreads();
  const int lane = t & 63, w = t >> 6;
  const int px = lane & 15, lg = lane >> 4;
  v4f acc[2];
  #pragma unroll
  for (int pf = 0; pf < 2; ++pf)
    #pragma unroll
    for (int rg = 0; rg < 4; ++rg) acc[pf][rg] = 0.f;
  #pragma unroll
  for (int ks = 0; ks < 18; ++ks) {
    const int tap = ks >> 1;
    const int dy = tap / 3, dx = tap - dy * 3;
    const int slot = ((ks & 1) << 2) | lg;
    v8s b = *(const v8s*)(bf5 + (((ks * 64) + lane) << 3));
    #pragma unroll
    for (int pf = 0; pf < 2; ++pf) {
      int xl = (w * 2 + pf + dy) * 18 + px + dx;
      v8s a = *(const v8s*)(hb + xl * 128 + ((slot ^ (xl & 7)) << 4));
      acc[pf] = __builtin_amdgcn_mfma_f32_16x16x32_bf16(a, b, acc[pf], 0, 0, 0);
    }
  }
  const int ocl = lane & 15;
  const float l = *lam;
  const float bsel = b5[ocl & 1];
  #pragma unroll
  for (int pf = 0; pf < 2; ++pf) {
    const int gy = ty0 + w * 2 + pf;
    #pragma unroll
    for (int rg = 0; rg < 4; ++rg) {
      float v = acc[pf][rg] + bsel;        // lane ocl=0: real, ocl=1: imag
      float d1 = __shfl_down(v, 1);
      if (ocl == 0) {
        int gx = tx0 + (lg << 2) + rg;
        int pix = (gy << 8) + gx;
        float x0 = atb[(size_t)img * 131072 + pix];
        float x1 = atb[(size_t)img * 131072 + 65536 + pix];
        rhs[(size_t)img * 65536 + pix] =
            make_float2(fmaf(l, x0 + v, x0), fmaf(l, x1 + d1, x1));
      }
    }
  }
}

// ---------------- AtA pass 1: coil = csm * p, FFT along rows (W) ----------------
__global__ __launch_bounds__(256) void k_coil_fft_rows(
    const float2* __restrict__ p, const float* __restrict__ csm_r,
    const float* __restrict__ csm_i, const float2* __restrict__ tw,
    float2* __restrict__ coil)
{
  __shared__ float2 lds[1024];
  const int t = threadIdx.x;
  const int bc = blockIdx.x;
  const int b = bc / NCOIL;
  const int h0 = blockIdx.y << 1;
  #pragma unroll
  for (int e = 0; e < 2; ++e) {
    int idx = t + (e << 8);
    int lr = idx >> 8, w = idx & 255;
    int gi = (bc << 16) + ((h0 + lr) << 8) + w;
    int pi = (b << 16) + ((h0 + lr) << 8) + w;
    float cr = csm_r[gi], ci = csm_i[gi];
    float2 pv = p[pi];
    lds[(lr << 8) + w] = make_float2(cr * pv.x - ci * pv.y, cr * pv.y + ci * pv.x);
  }
  __syncthreads();
  const int lr = t >> 7, bf = t & 127;
  float2* src = lds; float2* dst = lds + 512;
  #pragma unroll
  for (int s = 0; s < 8; ++s) {
    const int m = 1 << s;
    float2 a = src[(lr << 8) + bf];
    float2 bb = src[(lr << 8) + bf + 128];
    float2 w = tw[(128 + bf) >> s];
    int o0 = bf + (bf & ~(m - 1));
    dst[(lr << 8) + o0] = caddf(a, bb);
    dst[(lr << 8) + o0 + m] = cmulf(csubf(a, bb), w);
    float2* tmp = src; src = dst; dst = tmp;
    __syncthreads();
  }
  #pragma unroll
  for (int e = 0; e < 2; ++e) {
    int idx = t + (e << 8);
    int lr2 = idx >> 8, w = idx & 255;
    coil[(bc << 16) + ((h0 + lr2) << 8) + w] = src[(lr2 << 8) + w];
  }
}

// ---------------- AtA pass 2: four-step col FFT + mask + col IFFT ----------------
// 16 cols x 256 rows per block; thread=(col,idx); 3 barriers total.
__global__ __launch_bounds__(256) void k_fft_cols_mask(
    float2* __restrict__ coil, const float* __restrict__ mask,
    const float2* __restrict__ twf)   // twf[j] = exp(-2pi i j/256)
{
  __shared__ float2 trans[4096];      // [16][16][16] = 32 KB
  const int t = threadIdx.x;
  const int bc = blockIdx.x, b = bc / NCOIL;
  const int w0 = blockIdx.y << 4;
  const int col = t & 15, idx = t >> 4;
  const int base = (bc << 16) + w0 + col;
  float2 v[16];
  // load rows idx + 16*h2
  #pragma unroll
  for (int h2 = 0; h2 < 16; ++h2)
    v[h2] = coil[base + ((idx + (h2 << 4)) << 8)];
  // ---- forward ----
  dif16<0>(v);                        // reg r = A[k1=rev(r)]
  #pragma unroll
  for (int r = 0; r < 16; ++r) {      // twiddle W256^{h1*k1}, h1=idx
    int k1 = REV4[r];
    v[r] = cmulf(v[r], twf[idx * k1]);
    trans[(idx << 8) + (k1 << 4) + col] = v[r];
  }
  __syncthreads();
  #pragma unroll
  for (int h1 = 0; h1 < 16; ++h1)
    v[h1] = trans[(h1 << 8) + (idx << 4) + col];
  __syncthreads();                    // protect later overwrite
  dif16<0>(v);                        // reg r = X[k1=idx + 16*rev(r)]
  // ---- mask in registers ----
  #pragma unroll
  for (int r = 0; r < 16; ++r) {
    float mv = mask[(b << 16) + ((idx + (REV4[r] << 4)) << 8) + w0 + col];
    v[r].x *= mv; v[r].y *= mv;
  }
  // ---- inverse ----
  dit16<1>(v);                        // natural h1' in reg r
  #pragma unroll
  for (int r = 0; r < 16; ++r) {      // conj twiddle W256^{-k1*h1'}, k1=idx
    float2 w = twf[idx * r];
    v[r] = make_float2(v[r].x * w.x + v[r].y * w.y, v[r].y * w.x - v[r].x * w.y);
    trans[(idx << 8) + (r << 4) + col] = v[r];
  }
  __syncthreads();
  #pragma unroll
  for (int k1 = 0; k1 < 16; ++k1)
    v[k1] = trans[(k1 << 8) + (idx << 4) + col];
  dif16<1>(v);                        // reg r = x[h1=idx + 16*rev(r)] (unscaled)
  const float sc = 1.f / 256.f;
  #pragma unroll
  for (int r = 0; r < 16; ++r)
    coil[base + ((idx + (REV4[r] << 4)) << 8)] =
        make_float2(v[r].x * sc, v[r].y * sc);
}

// ------- AtA pass 3: IFFT rows (2 rows/block), conj(csm) combine, +lam*p, denom partials -------
__global__ __launch_bounds__(256) void k_ifft_rows_acc(
    const float2* __restrict__ coil, const float* __restrict__ csm_r,
    const float* __restrict__ csm_i, const float2* __restrict__ p,
    const float* __restrict__ lam, const float2* __restrict__ tw,
    float2* __restrict__ Ap, float* __restrict__ partials)
{
  __shared__ float2 lds[1024];
  __shared__ float red[4];
  const int t = threadIdx.x;
  const int b = blockIdx.x, h0 = blockIdx.y << 1;
  const int row = t >> 7, bf = t & 127;
  float2 acc0 = make_float2(0.f, 0.f), acc1 = make_float2(0.f, 0.f);
  for (int c = 0; c < NCOIL; ++c) {
    const int gb = ((b * NCOIL + c) << 16) + (h0 << 8);
    lds[t] = coil[gb + t];
    lds[t + 256] = coil[gb + t + 256];
    __syncthreads();
    float2* src = lds; float2* dst = lds + 512;
    #pragma unroll
    for (int s = 0; s < 8; ++s) {
      const int m = 1 << s;
      float2 a = src[(row << 8) + bf], bb = src[(row << 8) + bf + 128];
      float2 w = tw[(128 + bf) >> s]; w.y = -w.y;
      int o0 = bf + (bf & ~(m - 1));
      dst[(row << 8) + o0] = caddf(a, bb);
      dst[(row << 8) + o0 + m] = cmulf(csubf(a, bb), w);
      float2* tmp = src; src = dst; dst = tmp;
      __syncthreads();
    }
    {
      int gi = gb + (row << 8) + bf;
      float2 z = src[(row << 8) + bf];
      float cr = csm_r[gi], ci = csm_i[gi];
      acc0.x += cr * z.x + ci * z.y;
      acc0.y += cr * z.y - ci * z.x;
      float2 z2 = src[(row << 8) + bf + 128];
      float cr2 = csm_r[gi + 128], ci2 = csm_i[gi + 128];
      acc1.x += cr2 * z2.x + ci2 * z2.y;
      acc1.y += cr2 * z2.y - ci2 * z2.x;
    }
    __syncthreads();
  }
  const float inv = 1.f / 256.f;
  const float l = *lam;
  float dp = 0.f;
  {
    int pi = (b << 16) + ((h0 + row) << 8) + bf;
    float2 pv = p[pi];
    float2 apv = make_float2(fmaf(l, pv.x, acc0.x * inv), fmaf(l, pv.y, acc0.y * inv));
    Ap[pi] = apv;
    dp += pv.x * apv.x + pv.y * apv.y;
    pi += 128;
    float2 pv2 = p[pi];
    float2 apv2 = make_float2(fmaf(l, pv2.x, acc1.x * inv), fmaf(l, pv2.y, acc1.y * inv));
    Ap[pi] = apv2;
    dp += pv2.x * apv2.x + pv2.y * apv2.y;
  }
  #pragma unroll
  for (int off = 32; off; off >>= 1) dp += __shfl_down(dp, off);
  if ((t & 63) == 0) red[t >> 6] = dp;
  __syncthreads();
  if (t == 0) partials[(b << 7) + blockIdx.y] = red[0] + red[1] + red[2] + red[3];
}

// ---------------- CG vector kernels (scalar logic folded in) ----------------
__device__ __forceinline__ float blockRed256(float v, float* sm) {
  #pragma unroll
  for (int off = 32; off; off >>= 1) v += __shfl_down(v, off);
  int lane = threadIdx.x & 63, wv = threadIdx.x >> 6;
  if (lane == 0) sm[wv] = v;
  __syncthreads();
  return sm[0] + sm[1] + sm[2] + sm[3];
}

__device__ __forceinline__ void blockRed2(float& a, float& b, float2* sm) {
  #pragma unroll
  for (int off = 32; off; off >>= 1) {
    a += __shfl_down(a, off);
    b += __shfl_down(b, off);
  }
  int lane = threadIdx.x & 63, wv = threadIdx.x >> 6;
  if (lane == 0) sm[wv] = make_float2(a, b);
  __syncthreads();
  float2 s0 = sm[0], s1 = sm[1], s2 = sm[2], s3 = sm[3];
  a = s0.x + s1.x + s2.x + s3.x;
  b = s0.y + s1.y + s2.y + s3.y;
}

__global__ __launch_bounds__(256) void k_cg_init(
    const float2* __restrict__ rhs, float2* __restrict__ x,
    float2* __restrict__ r, float2* __restrict__ p, float* __restrict__ part)
{
  __shared__ float sm[4];
  const int t = threadIdx.x;
  const int base = blockIdx.x * 512;
  float s = 0.f;
  #pragma unroll
  for (int e = 0; e < 2; ++e) {
    int idx = base + t + (e << 8);
    float2 v = rhs[idx];
    x[idx] = make_float2(0.f, 0.f);
    r[idx] = v; p[idx] = v;
    s = fmaf(v.x, v.x, fmaf(v.y, v.y, s));
  }
  float tot = blockRed256(s, sm);
  if (t == 0) part[blockIdx.x] = tot;
}

// x += alpha p; r -= alpha Ap; alpha computed per-block from partials (identical everywhere)
__global__ __launch_bounds__(256) void k_update1(
    float2* __restrict__ x, float2* __restrict__ r,
    const float2* __restrict__ p, const float2* __restrict__ Ap,
    const float* __restrict__ part_d, const float* __restrict__ part_r_old,
    float* __restrict__ part_r_new)
{
  __shared__ float2 sm2[4];
  __shared__ float sm[4];
  const int t = threadIdx.x;
  float sd = 0.f, sr = 0.f;
  for (int i = t; i < 1024; i += 256) { sd += part_d[i]; sr += part_r_old[i]; }
  blockRed2(sd, sr, sm2);
  const bool cont = sr > 1e-10f;
  const float alpha = cont ? sr / sd : 0.f;   // alpha=0 => x,r (and rTr) frozen exactly
  const int base = blockIdx.x * 512;
  float s = 0.f;
  #pragma unroll
  for (int e = 0; e < 2; ++e) {
    int idx = base + t + (e << 8);
    float2 pv = p[idx], av = Ap[idx], xv = x[idx], rv = r[idx];
    xv.x = fmaf(alpha, pv.x, xv.x); xv.y = fmaf(alpha, pv.y, xv.y);
    rv.x = fmaf(-alpha, av.x, rv.x); rv.y = fmaf(-alpha, av.y, rv.y);
    x[idx] = xv; r[idx] = rv;
    s = fmaf(rv.x, rv.x, fmaf(rv.y, rv.y, s));
  }
  float tot = blockRed256(s, sm);
  if (t == 0) part_r_new[blockIdx.x] = tot;
}

// p = r + beta p; beta computed per-block; skipped entirely when !cont
__global__ __launch_bounds__(256) void k_update2(
    float2* __restrict__ p, const float2* __restrict__ r,
    const float* __restrict__ part_r_old, const float* __restrict__ part_r_new)
{
  __shared__ float2 sm2[4];
  const int t = threadIdx.x;
  float so = 0.f, sn = 0.f;
  for (int i = t; i < 1024; i += 256) { so += part_r_old[i]; sn += part_r_new[i]; }
  blockRed2(so, sn, sm2);
  if (!(so > 1e-10f)) return;               // p frozen when !cont
  const float beta = sn / so;
  const int base = blockIdx.x * 512;
  #pragma unroll
  for (int e = 0; e < 2; ++e) {
    int idx = base + t + (e << 8);
    float2 pv = p[idx], rv = r[idx];
    p[idx] = make_float2(fmaf(beta, pv.x, rv.x), fmaf(beta, pv.y, rv.y));
  }
}

__global__ __launch_bounds__(256) void k_final(const float2* __restrict__ x,
                                               float* __restrict__ out) {
  const int t = threadIdx.x;
  const int base = blockIdx.x * 512;
  #pragma unroll
  for (int e = 0; e < 2; ++e) {
    int idx = base + t + (e << 8);
    int b = idx >> 16, pix = idx & 65535;
    float2 v = x[idx];
    out[(b << 17) + pix] = v.x;
    out[(b << 17) + 65536 + pix] = v.y;
  }
}

// ---------------- driver ----------------
extern "C" void kernel_launch(void* const* d_in, const int* in_sizes, int n_in,
                              void* d_out, int out_size, void* d_ws, size_t ws_size,
                              hipStream_t stream) {
  (void)in_sizes; (void)n_in; (void)out_size; (void)ws_size;
  const float* atb   = (const float*)d_in[0];
  const float* csm_r = (const float*)d_in[1];
  const float* csm_i = (const float*)d_in[2];
  const float* mask  = (const float*)d_in[3];
  const float* w1 = (const float*)d_in[4];  const float* b1 = (const float*)d_in[5];
  const float* w2 = (const float*)d_in[6];  const float* b2 = (const float*)d_in[7];
  const float* w3 = (const float*)d_in[8];  const float* b3 = (const float*)d_in[9];
  const float* w4 = (const float*)d_in[10]; const float* b4 = (const float*)d_in[11];
  const float* w5 = (const float*)d_in[12]; const float* b5 = (const float*)d_in[13];
  const float* lam = (const float*)d_in[14];

  char* ws = (char*)d_ws;
  // CNN phase: actA@0 (32 MB), actB@33554432 (32 MB) — alias CG coil/x/r region
  unsigned short* actA = (unsigned short*)ws;
  unsigned short* actB = (unsigned short*)(ws + 33554432);
  // CG phase
  float2* coil = (float2*)ws;                        // 50331648 B
  float2* x    = (float2*)(ws + 50331648);
  float2* r    = (float2*)(ws + 54525952);
  float2* p    = (float2*)(ws + 58720256);
  float2* Ap   = (float2*)(ws + 62914560);
  float2* rhs  = (float2*)(ws + 67108864);           // 4 MB (persists)
  float*  w1T  = (float*)(ws + 71303168);            // 4608 B
  unsigned short* bf2 = (unsigned short*)(ws + 71307776);  // 73728 B each
  unsigned short* bf3 = (unsigned short*)(ws + 71381504);
  unsigned short* bf4 = (unsigned short*)(ws + 71455232);
  unsigned short* bf5 = (unsigned short*)(ws + 71528960);  // 18432 B
  float2* tw   = (float2*)(ws + 71547392);           // 512 float2 = 4096 B
  float2* twf  = tw + 256;
  float*  part = (float*)(ws + 71551488);            // part_d 1024 + 12x1024 part_r
  float*  part_d = part;
  float*  part_r = part + 1024;

  // prep
  k_twiddle<<<1, 256, 0, stream>>>(tw);
  k_transpose_w<<<5, 256, 0, stream>>>(w1, w1T, 2, 64);
  k_bfrag<<<144, 256, 0, stream>>>(w2, bf2);
  k_bfrag<<<144, 256, 0, stream>>>(w3, bf3);
  k_bfrag<<<144, 256, 0, stream>>>(w4, bf4);
  k_bfrag5<<<36, 256, 0, stream>>>(w5, bf5);

  // CNN: two halves of 4 images each
  for (int half = 0; half < 2; ++half) {
    const float* atb_h = atb + (size_t)half * 4 * 131072;
    float2* rhs_h = rhs + (size_t)half * 4 * 65536;
    k_conv1<<<dim3(16, 16, 4), 256, 0, stream>>>(atb_h, w1T, b1, actA);
    k_conv_mfma<<<dim3(16, 16, 4), 512, 0, stream>>>(actA, bf2, b2, actB);
    k_conv_mfma<<<dim3(16, 16, 4), 512, 0, stream>>>(actB, bf3, b3, actA);
    k_conv_mfma<<<dim3(16, 16, 4), 512, 0, stream>>>(actA, bf4, b4, actB);
    k_conv5_rhs<<<dim3(16, 16, 4), 512, 0, stream>>>(actB, bf5, b5, atb_h, lam, rhs_h);
  }

  // CG
  k_cg_init<<<1024, 256, 0, stream>>>(rhs, x, r, p, part_r);
  for (int it = 0; it < 11; ++it) {
    k_coil_fft_rows<<<dim3(96, 128), 256, 0, stream>>>(p, csm_r, csm_i, tw, coil);
    k_fft_cols_mask<<<dim3(96, 16), 256, 0, stream>>>(coil, mask, twf);
    k_ifft_rows_acc<<<dim3(8, 128), 256, 0, stream>>>(coil, csm_r, csm_i, p, lam, tw, Ap, part_d);
    k_update1<<<1024, 256, 0, stream>>>(x, r, p, Ap, part_d,
                                        part_r + it * 1024, part_r + (it + 1) * 1024);
    k_update2<<<1024, 256, 0, stream>>>(p, r, part_r + it * 1024, part_r + (it + 1) * 1024);
  }

  k_final<<<1024, 256, 0, stream>>>(x, (float*)d_out);
}

// Round 5
// 1230.858 us; speedup vs baseline: 5.8146x; 1.0248x over previous
//
#include <hip/hip_runtime.h>
#include <hip/hip_bf16.h>
#include <math.h>

static constexpr int NCOIL = 12;
static constexpr int HWSZ  = 65536;   // 256*256

typedef short v8s __attribute__((ext_vector_type(8)));
typedef float v4f __attribute__((ext_vector_type(4)));

__device__ __forceinline__ unsigned short f2bf(float v) {
  __hip_bfloat16 h = __float2bfloat16(v);
  union { __hip_bfloat16 h; unsigned short u; } cv; cv.h = h; return cv.u;
}
__device__ __forceinline__ float bf2f(unsigned short u) {
  return __uint_as_float(((unsigned)u) << 16);
}

// ---------------- complex helpers ----------------
__device__ __forceinline__ float2 cmulf(float2 a, float2 b) {
  return make_float2(a.x * b.x - a.y * b.y, a.x * b.y + a.y * b.x);
}
__device__ __forceinline__ float2 caddf(float2 a, float2 b) {
  return make_float2(a.x + b.x, a.y + b.y);
}
__device__ __forceinline__ float2 csubf(float2 a, float2 b) {
  return make_float2(a.x - b.x, a.y - b.y);
}

// ---------------- block reductions ----------------
__device__ __forceinline__ float blockRed256(float v, float* sm) {
  #pragma unroll
  for (int off = 32; off; off >>= 1) v += __shfl_down(v, off);
  int lane = threadIdx.x & 63, wv = threadIdx.x >> 6;
  if (lane == 0) sm[wv] = v;
  __syncthreads();
  return sm[0] + sm[1] + sm[2] + sm[3];
}

__device__ __forceinline__ void blockRed2(float& a, float& b, float2* sm) {
  #pragma unroll
  for (int off = 32; off; off >>= 1) {
    a += __shfl_down(a, off);
    b += __shfl_down(b, off);
  }
  int lane = threadIdx.x & 63, wv = threadIdx.x >> 6;
  if (lane == 0) sm[wv] = make_float2(a, b);
  __syncthreads();
  float2 s0 = sm[0], s1 = sm[1], s2 = sm[2], s3 = sm[3];
  a = s0.x + s1.x + s2.x + s3.x;
  b = s0.y + s1.y + s2.y + s3.y;
}

// ---------------- in-register 16-pt DFT (four-step building block) ----------------
__device__ __constant__ const float TC16[8] = {
  1.f, 0.92387953f, 0.70710678f, 0.38268343f, 0.f, -0.38268343f, -0.70710678f, -0.92387953f};
__device__ __constant__ const float TS16[8] = {
  0.f, -0.38268343f, -0.70710678f, -0.92387953f, -1.f, -0.92387953f, -0.70710678f, -0.38268343f};
__device__ __constant__ const int REV4[16] = {0,8,4,12,2,10,6,14,1,9,5,13,3,11,7,15};

// DIF: natural input -> output reg r holds X[rev4(r)]
template<int INV>
__device__ __forceinline__ void dif16(float2 v[16]) {
  #pragma unroll
  for (int ls = 0; ls < 4; ++ls) {
    const int len = 16 >> ls, half = len >> 1, step = 1 << ls;
    #pragma unroll
    for (int i = 0; i < 16; i += len) {
      #pragma unroll
      for (int j = 0; j < half; ++j) {
        float2 a = v[i + j], b = v[i + j + half];
        v[i + j] = caddf(a, b);
        float2 d = csubf(a, b);
        float cr = TC16[j * step];
        float ci = INV ? -TS16[j * step] : TS16[j * step];
        v[i + j + half] = make_float2(d.x * cr - d.y * ci, d.x * ci + d.y * cr);
      }
    }
  }
}

// DIT: input reg r holds in[rev4(r)] -> natural-order output
template<int INV>
__device__ __forceinline__ void dit16(float2 v[16]) {
  #pragma unroll
  for (int ls = 0; ls < 4; ++ls) {
    const int len = 2 << ls, half = len >> 1, step = 16 / len;
    #pragma unroll
    for (int i = 0; i < 16; i += len) {
      #pragma unroll
      for (int j = 0; j < half; ++j) {
        float cr = TC16[j * step];
        float ci = INV ? -TS16[j * step] : TS16[j * step];
        float2 b = v[i + j + half];
        float2 tt = make_float2(b.x * cr - b.y * ci, b.x * ci + b.y * cr);
        float2 a = v[i + j];
        v[i + j] = caddf(a, tt);
        v[i + j + half] = csubf(a, tt);
      }
    }
  }
}

// ---------------- prep kernels ----------------
// tw[0:256): legacy Stockham table; tw[256:512): twf[j]=exp(-2pi i j/256)
__global__ void k_twiddle(float2* __restrict__ tw) {
  int t = threadIdx.x;
  {
    float ang = -6.28318530717958647692f * (float)t / 256.f;
    float s, c; sincosf(ang, &s, &c);
    tw[256 + t] = make_float2(c, s);
  }
  if (t == 0) { tw[0] = make_float2(1.f, 0.f); return; }
  int l = 1 << (31 - __clz(t));
  int j = t - l;
  float ang = -3.14159265358979323846f * (float)j / (float)l;
  float s, c; sincosf(ang, &s, &c);
  tw[t] = make_float2(c, s);
}

// w [OC][IC][3][3] -> wT [IC*9][OC]  (fp32, for layer 1)
__global__ void k_transpose_w(const float* __restrict__ w, float* __restrict__ wT,
                              int IC, int OC) {
  int i = blockIdx.x * 256 + threadIdx.x;
  int total = IC * 9 * OC;
  if (i >= total) return;
  int oc = i % OC;
  int rest = i / OC;            // ic*9 + k
  int ic = rest / 9, k = rest - ic * 9;
  wT[i] = w[(oc * IC + ic) * 9 + k];
}

// w [64][64][3][3] fp32 -> B-fragment order bf16: [ks=18][ocg=4][lane=64][j=8]
__global__ void k_bfrag(const float* __restrict__ w, unsigned short* __restrict__ bf) {
  int i = blockIdx.x * 256 + threadIdx.x;   // 18*4*64*8 = 36864
  if (i >= 36864) return;
  int j = i & 7, lane = (i >> 3) & 63, ocg = (i >> 9) & 3, ks = i >> 11;
  int oc = (ocg << 4) + (lane & 15);
  int ic = ((ks & 1) << 5) + (((lane >> 4) & 3) << 3) + j;
  int tap = ks >> 1;
  bf[i] = f2bf(w[(oc * 64 + ic) * 9 + tap]);
}

// w5 [2][64][3][3] -> B-fragment bf16 [ks=18][lane=64][j=8], oc padded 2->16
__global__ void k_bfrag5(const float* __restrict__ w, unsigned short* __restrict__ bf) {
  int i = blockIdx.x * 256 + threadIdx.x;   // 18*64*8 = 9216
  if (i >= 9216) return;
  int j = i & 7, lane = (i >> 3) & 63, ks = i >> 9;
  int oc = lane & 15;
  int ic = ((ks & 1) << 5) + (((lane >> 4) & 3) << 3) + j;
  int tap = ks >> 1;
  bf[i] = (oc < 2) ? f2bf(w[(oc * 64 + ic) * 9 + tap]) : (unsigned short)0;
}

// ---------------- layer 1: fp32 direct conv (IC=2), out pixel-major bf16 ----------------
__global__ __launch_bounds__(256) void k_conv1(
    const float* __restrict__ atb,   // [img][2][256][256] (half-batch base)
    const float* __restrict__ w1T,   // [18][64]
    const float* __restrict__ b1,
    unsigned short* __restrict__ out)// [img][256][256][64] bf16
{
  __shared__ float patch[2 * 324];
  const int t = threadIdx.x;
  const int img = blockIdx.z;
  const float* in = atb + (size_t)img * 131072;
  const int tx0 = blockIdx.x << 4, ty0 = blockIdx.y << 4;
  for (int i = t; i < 648; i += 256) {
    int ic = i / 324, rem = i - ic * 324;
    int py = rem / 18, px = rem - py * 18;
    int gy = ty0 + py - 1, gx = tx0 + px - 1;
    float v = 0.f;
    if ((unsigned)gy < 256u && (unsigned)gx < 256u)
      v = in[(ic << 16) + (gy << 8) + gx];
    patch[i] = v;
  }
  __syncthreads();
  const int tx = t & 15, ty = t >> 4;
  float acc[64];
  #pragma unroll
  for (int o = 0; o < 64; ++o) acc[o] = 0.f;
  #pragma unroll
  for (int ic = 0; ic < 2; ++ic) {
    const float* pb = &patch[ic * 324 + ty * 18 + tx];
    #pragma unroll
    for (int k = 0; k < 9; ++k) {
      const float v = pb[(k / 3) * 18 + (k % 3)];
      const float* wr = &w1T[(ic * 9 + k) << 6];
      #pragma unroll
      for (int o = 0; o < 64; ++o) acc[o] = fmaf(v, wr[o], acc[o]);
    }
  }
  size_t obase = ((size_t)img << 22) + ((size_t)(((ty0 + ty) << 8) + tx0 + tx) << 6);
  v8s* outv = (v8s*)(out + obase);
  #pragma unroll
  for (int g = 0; g < 8; ++g) {
    v8s ov;
    #pragma unroll
    for (int j = 0; j < 8; ++j) {
      float v = fmaxf(acc[(g << 3) + j] + b1[(g << 3) + j], 0.f);
      ov[j] = (short)f2bf(v);
    }
    outv[g] = ov;
  }
}

// ---------------- layers 2-4: bf16 MFMA implicit GEMM (16x16 tile, 8 waves) ----------------
__global__ __launch_bounds__(512, 4) void k_conv_mfma(
    const unsigned short* __restrict__ in,
    const unsigned short* __restrict__ bfrag,
    const float* __restrict__ bias,
    unsigned short* __restrict__ out)
{
  __shared__ v8s halo[2592];   // 18x18 px x 8 slots of 8ch, swizzled: 41472 B
  char* hb = (char*)halo;
  const int t = threadIdx.x;
  const int img = blockIdx.z;
  const int tx0 = blockIdx.x << 4, ty0 = blockIdx.y << 4;
  const size_t ibase = ((size_t)img << 22);
  for (int c = t; c < 2592; c += 512) {
    int hy = c / 144, rem = c - hy * 144;
    int hx = rem >> 3, slot = rem & 7;
    int gy = ty0 + hy - 1, gx = tx0 + hx - 1;
    v8s v = {0, 0, 0, 0, 0, 0, 0, 0};
    if ((unsigned)gy < 256u && (unsigned)gx < 256u)
      v = *(const v8s*)(in + ibase + ((size_t)((gy << 8) + gx) << 6) + (slot << 3));
    int xl = hy * 18 + hx;
    *(v8s*)(hb + xl * 128 + ((slot ^ (xl & 7)) << 4)) = v;
  }
  __syncthreads();
  const int lane = t & 63, w = t >> 6;
  const int px = lane & 15, lg = lane >> 4;
  v4f acc[2][4];
  #pragma unroll
  for (int pf = 0; pf < 2; ++pf)
    #pragma unroll
    for (int og = 0; og < 4; ++og)
      #pragma unroll
      for (int rg = 0; rg < 4; ++rg) acc[pf][og][rg] = 0.f;

  #pragma unroll
  for (int ks = 0; ks < 18; ++ks) {
    const int tap = ks >> 1;
    const int dy = tap / 3, dx = tap - dy * 3;
    const int slot = ((ks & 1) << 2) | lg;
    v8s b0 = *(const v8s*)(bfrag + ((((ks << 2) | 0) * 64 + lane) << 3));
    v8s b1 = *(const v8s*)(bfrag + ((((ks << 2) | 1) * 64 + lane) << 3));
    v8s b2 = *(const v8s*)(bfrag + ((((ks << 2) | 2) * 64 + lane) << 3));
    v8s b3 = *(const v8s*)(bfrag + ((((ks << 2) | 3) * 64 + lane) << 3));
    #pragma unroll
    for (int pf = 0; pf < 2; ++pf) {
      int xl = (w * 2 + pf + dy) * 18 + px + dx;
      v8s a = *(const v8s*)(hb + xl * 128 + ((slot ^ (xl & 7)) << 4));
      acc[pf][0] = __builtin_amdgcn_mfma_f32_16x16x32_bf16(a, b0, acc[pf][0], 0, 0, 0);
      acc[pf][1] = __builtin_amdgcn_mfma_f32_16x16x32_bf16(a, b1, acc[pf][1], 0, 0, 0);
      acc[pf][2] = __builtin_amdgcn_mfma_f32_16x16x32_bf16(a, b2, acc[pf][2], 0, 0, 0);
      acc[pf][3] = __builtin_amdgcn_mfma_f32_16x16x32_bf16(a, b3, acc[pf][3], 0, 0, 0);
    }
  }
  const int ocl = lane & 15;
  float bv[4];
  #pragma unroll
  for (int og = 0; og < 4; ++og) bv[og] = bias[(og << 4) + ocl];
  #pragma unroll
  for (int pf = 0; pf < 2; ++pf) {
    const int gy = ty0 + w * 2 + pf;
    #pragma unroll
    for (int og = 0; og < 4; ++og) {
      const int oc = (og << 4) + ocl;
      #pragma unroll
      for (int rg = 0; rg < 4; ++rg) {
        float v = fmaxf(acc[pf][og][rg] + bv[og], 0.f);
        int gx = tx0 + (lg << 2) + rg;
        out[ibase + ((size_t)((gy << 8) + gx) << 6) + oc] = f2bf(v);
      }
    }
  }
}

// ---------------- layer 5 (64->2, MFMA) + rhs = atb + lam*(atb + conv5) ----------------
__global__ __launch_bounds__(512, 4) void k_conv5_rhs(
    const unsigned short* __restrict__ in,  // pixel-major bf16
    const unsigned short* __restrict__ bf5, // [18][64][8], oc padded to 16
    const float* __restrict__ b5,
    const float* __restrict__ atb,          // half-batch base
    const float* __restrict__ lam,
    float2* __restrict__ rhs)               // half-batch base
{
  __shared__ v8s halo[2592];
  char* hb = (char*)halo;
  const int t = threadIdx.x;
  const int img = blockIdx.z;
  const int tx0 = blockIdx.x << 4, ty0 = blockIdx.y << 4;
  const size_t ibase = ((size_t)img << 22);
  for (int c = t; c < 2592; c += 512) {
    int hy = c / 144, rem = c - hy * 144;
    int hx = rem >> 3, slot = rem & 7;
    int gy = ty0 + hy - 1, gx = tx0 + hx - 1;
    v8s v = {0, 0, 0, 0, 0, 0, 0, 0};
    if ((unsigned)gy < 256u && (unsigned)gx < 256u)
      v = *(const v8s*)(in + ibase + ((size_t)((gy << 8) + gx) << 6) + (slot << 3));
    int xl = hy * 18 + hx;
    *(v8s*)(hb + xl * 128 + ((slot ^ (xl & 7)) << 4)) = v;
  }
  __syncthreads();
  const int lane = t & 63, w = t >> 6;
  const int px = lane & 15, lg = lane >> 4;
  v4f acc[2];
  #pragma unroll
  for (int pf = 0; pf < 2; ++pf)
    #pragma unroll
    for (int rg = 0; rg < 4; ++rg) acc[pf][rg] = 0.f;
  #pragma unroll
  for (int ks = 0; ks < 18; ++ks) {
    const int tap = ks >> 1;
    const int dy = tap / 3, dx = tap - dy * 3;
    const int slot = ((ks & 1) << 2) | lg;
    v8s b = *(const v8s*)(bf5 + (((ks * 64) + lane) << 3));
    #pragma unroll
    for (int pf = 0; pf < 2; ++pf) {
      int xl = (w * 2 + pf + dy) * 18 + px + dx;
      v8s a = *(const v8s*)(hb + xl * 128 + ((slot ^ (xl & 7)) << 4));
      acc[pf] = __builtin_amdgcn_mfma_f32_16x16x32_bf16(a, b, acc[pf], 0, 0, 0);
    }
  }
  const int ocl = lane & 15;
  const float l = *lam;
  const float bsel = b5[ocl & 1];
  #pragma unroll
  for (int pf = 0; pf < 2; ++pf) {
    const int gy = ty0 + w * 2 + pf;
    #pragma unroll
    for (int rg = 0; rg < 4; ++rg) {
      float v = acc[pf][rg] + bsel;        // lane ocl=0: real, ocl=1: imag
      float d1 = __shfl_down(v, 1);
      if (ocl == 0) {
        int gx = tx0 + (lg << 2) + rg;
        int pix = (gy << 8) + gx;
        float x0 = atb[(size_t)img * 131072 + pix];
        float x1 = atb[(size_t)img * 131072 + 65536 + pix];
        rhs[(size_t)img * 65536 + pix] =
            make_float2(fmaf(l, x0 + v, x0), fmaf(l, x1 + d1, x1));
      }
    }
  }
}

// ---- AtA pass 1: (fused p-update) coil = csm * p, four-step row FFT ----
// grid (96 bc, 16 rowgroups), block 256: idx = t&15 (lane-fast), row16 = t>>4.
// LDS layout: logical (A,B) -> trans[(A<<8) + (row16<<4) + (B^A)]  (XOR bank swizzle)
__global__ __launch_bounds__(256) void k_coil_fft_rows(
    const float2* __restrict__ p_prev, const float2* __restrict__ r,
    float2* __restrict__ p_out,
    const float* __restrict__ part_r_old, const float* __restrict__ part_r_new,
    const int first,
    const float* __restrict__ csm_r, const float* __restrict__ csm_i,
    const float2* __restrict__ twf, float2* __restrict__ coil)
{
  __shared__ float2 trans[4096];      // 32 KB
  __shared__ float2 sm2[4];
  const int t = threadIdx.x;
  const int bc = blockIdx.x, b = bc / NCOIL, c = bc - b * NCOIL;
  const int idx = t & 15, row16 = t >> 4;
  const int row = (blockIdx.y << 4) + row16;

  // beta for the deferred p-update (identical in every block -> deterministic)
  float beta = 0.f; bool do_upd = false;
  if (!first) {
    float so = 0.f, sn = 0.f;
    for (int i = t; i < 1024; i += 256) { so += part_r_old[i]; sn += part_r_new[i]; }
    blockRed2(so, sn, sm2);
    do_upd = so > 1e-10f;
    beta = do_upd ? sn / so : 0.f;
  }

  const int pb = (b << 16) + (row << 8);
  const int gb = (bc << 16) + (row << 8);
  float2 v[16];
  #pragma unroll
  for (int h2 = 0; h2 < 16; ++h2) {
    int n = idx + (h2 << 4);
    float2 pv = p_prev[pb + n];
    if (!first) {
      if (do_upd) {
        float2 rv = r[pb + n];
        pv = make_float2(fmaf(beta, pv.x, rv.x), fmaf(beta, pv.y, rv.y));
      }
      if (c == 0) p_out[pb + n] = pv;   // one coil-block per b writes p_new
    }
    float cr = csm_r[gb + n], ci = csm_i[gb + n];
    v[h2] = make_float2(cr * pv.x - ci * pv.y, cr * pv.y + ci * pv.x);
  }
  // forward four-step along W
  dif16<0>(v);
  #pragma unroll
  for (int rr = 0; rr < 16; ++rr) {
    int k1 = REV4[rr];
    v[rr] = cmulf(v[rr], twf[idx * k1]);
    trans[(k1 << 8) + (row16 << 4) + (idx ^ k1)] = v[rr];
  }
  __syncthreads();
  #pragma unroll
  for (int h1 = 0; h1 < 16; ++h1)
    v[h1] = trans[(idx << 8) + (row16 << 4) + (h1 ^ idx)];
  dif16<0>(v);                         // reg rr <-> k_w = idx + 16*REV4[rr]
  #pragma unroll
  for (int rr = 0; rr < 16; ++rr)
    coil[gb + idx + (REV4[rr] << 4)] = v[rr];
}

// ---------------- AtA pass 2: four-step col FFT + mask + col IFFT ----------------
__global__ __launch_bounds__(256) void k_fft_cols_mask(
    float2* __restrict__ coil, const float* __restrict__ mask,
    const float2* __restrict__ twf)   // twf[j] = exp(-2pi i j/256)
{
  __shared__ float2 trans[4096];      // [16][16][16] = 32 KB
  const int t = threadIdx.x;
  const int bc = blockIdx.x, b = bc / NCOIL;
  const int w0 = blockIdx.y << 4;
  const int col = t & 15, idx = t >> 4;
  const int base = (bc << 16) + w0 + col;
  float2 v[16];
  #pragma unroll
  for (int h2 = 0; h2 < 16; ++h2)
    v[h2] = coil[base + ((idx + (h2 << 4)) << 8)];
  // ---- forward ----
  dif16<0>(v);
  #pragma unroll
  for (int r = 0; r < 16; ++r) {
    int k1 = REV4[r];
    v[r] = cmulf(v[r], twf[idx * k1]);
    trans[(idx << 8) + (k1 << 4) + col] = v[r];
  }
  __syncthreads();
  #pragma unroll
  for (int h1 = 0; h1 < 16; ++h1)
    v[h1] = trans[(h1 << 8) + (idx << 4) + col];
  __syncthreads();
  dif16<0>(v);                        // reg r = X[k = idx + 16*rev(r)]
  // ---- mask in registers ----
  #pragma unroll
  for (int r = 0; r < 16; ++r) {
    float mv = mask[(b << 16) + ((idx + (REV4[r] << 4)) << 8) + w0 + col];
    v[r].x *= mv; v[r].y *= mv;
  }
  // ---- inverse ----
  dit16<1>(v);
  #pragma unroll
  for (int r = 0; r < 16; ++r) {
    float2 w = twf[idx * r];
    v[r] = make_float2(v[r].x * w.x + v[r].y * w.y, v[r].y * w.x - v[r].x * w.y);
    trans[(idx << 8) + (r << 4) + col] = v[r];
  }
  __syncthreads();
  #pragma unroll
  for (int k1 = 0; k1 < 16; ++k1)
    v[k1] = trans[(k1 << 8) + (idx << 4) + col];
  dif16<1>(v);                        // reg r = x[h = idx + 16*rev(r)] (unscaled)
  const float sc = 1.f / 256.f;
  #pragma unroll
  for (int r = 0; r < 16; ++r)
    coil[base + ((idx + (REV4[r] << 4)) << 8)] =
        make_float2(v[r].x * sc, v[r].y * sc);
}

// ---- AtA pass 3a: four-step row IFFT + conj(csm) partial sum over 3 coils ----
// grid (8 b, 16 rowgroups, 4 csplit); partial written IN-PLACE into coil plane cs*3.
__global__ __launch_bounds__(256) void k_ifft_rows_acc(
    float2* __restrict__ coil, const float* __restrict__ csm_r,
    const float* __restrict__ csm_i, const float2* __restrict__ twf)
{
  __shared__ float2 trans[4096];
  const int t = threadIdx.x;
  const int b = blockIdx.x, cs = blockIdx.z;
  const int idx = t & 15, row16 = t >> 4;
  const int row = (blockIdx.y << 4) + row16;
  float2 acc[16];
  #pragma unroll
  for (int rr = 0; rr < 16; ++rr) acc[rr] = make_float2(0.f, 0.f);
  for (int j = 0; j < 3; ++j) {
    const int c = cs * 3 + j;
    const int gb = ((b * NCOIL + c) << 16) + (row << 8);
    float2 v[16];
    #pragma unroll
    for (int rr = 0; rr < 16; ++rr)
      v[rr] = coil[gb + idx + (REV4[rr] << 4)];
    dit16<1>(v);                      // natural order
    if (j) __syncthreads();           // protect trans reuse
    #pragma unroll
    for (int rr = 0; rr < 16; ++rr) {
      float2 w = twf[idx * rr];
      float2 z = v[rr];
      trans[(rr << 8) + (row16 << 4) + (idx ^ rr)] =
          make_float2(z.x * w.x + z.y * w.y, z.y * w.x - z.x * w.y);
    }
    __syncthreads();
    #pragma unroll
    for (int k1 = 0; k1 < 16; ++k1)
      v[k1] = trans[(idx << 8) + (row16 << 4) + (k1 ^ idx)];
    dif16<1>(v);                      // reg rr <-> w = idx + 16*REV4[rr]
    #pragma unroll
    for (int rr = 0; rr < 16; ++rr) {
      int gi = gb + idx + (REV4[rr] << 4);
      float cr = csm_r[gi], ci = csm_i[gi];
      float2 z = v[rr];
      acc[rr].x += cr * z.x + ci * z.y;
      acc[rr].y += cr * z.y - ci * z.x;
    }
  }
  const int ob = ((b * NCOIL + cs * 3) << 16) + (row << 8);
  #pragma unroll
  for (int rr = 0; rr < 16; ++rr)
    coil[ob + idx + (REV4[rr] << 4)] = acc[rr];
}

// ---- AtA pass 3b: combine 4 partials + lam*p -> Ap, denominator partials ----
__global__ __launch_bounds__(256) void k_combine(
    const float2* __restrict__ coil, const float2* __restrict__ p,
    const float* __restrict__ lam, float2* __restrict__ Ap,
    float* __restrict__ part_d)
{
  __shared__ float sm[4];
  const int t = threadIdx.x;
  const float l = *lam;
  const float inv = 1.f / 256.f;
  float dp = 0.f;
  #pragma unroll
  for (int e = 0; e < 2; ++e) {
    int pix = blockIdx.x * 512 + t + (e << 8);
    int b = pix >> 16, off = pix & 65535;
    int cb = ((b * NCOIL) << 16) + off;
    float2 s0 = coil[cb];
    float2 s1 = coil[cb + (3 << 16)];
    float2 s2 = coil[cb + (6 << 16)];
    float2 s3 = coil[cb + (9 << 16)];
    float sx = (s0.x + s1.x) + (s2.x + s3.x);
    float sy = (s0.y + s1.y) + (s2.y + s3.y);
    float2 pv = p[pix];
    float2 apv = make_float2(fmaf(l, pv.x, sx * inv), fmaf(l, pv.y, sy * inv));
    Ap[pix] = apv;
    dp += pv.x * apv.x + pv.y * apv.y;
  }
  float tot = blockRed256(dp, sm);
  if (t == 0) part_d[blockIdx.x] = tot;
}

// ---------------- CG vector kernels ----------------
__global__ __launch_bounds__(256) void k_cg_init(
    const float2* __restrict__ rhs, float2* __restrict__ x,
    float2* __restrict__ r, float2* __restrict__ p, float* __restrict__ part)
{
  __shared__ float sm[4];
  const int t = threadIdx.x;
  const int base = blockIdx.x * 512;
  float s = 0.f;
  #pragma unroll
  for (int e = 0; e < 2; ++e) {
    int idx = base + t + (e << 8);
    float2 v = rhs[idx];
    x[idx] = make_float2(0.f, 0.f);
    r[idx] = v; p[idx] = v;
    s = fmaf(v.x, v.x, fmaf(v.y, v.y, s));
  }
  float tot = blockRed256(s, sm);
  if (t == 0) part[blockIdx.x] = tot;
}

// x += alpha p; r -= alpha Ap; alpha computed per-block from partials (identical everywhere)
__global__ __launch_bounds__(256) void k_update1(
    float2* __restrict__ x, float2* __restrict__ r,
    const float2* __restrict__ p, const float2* __restrict__ Ap,
    const float* __restrict__ part_d, const float* __restrict__ part_r_old,
    float* __restrict__ part_r_new)
{
  __shared__ float2 sm2[4];
  __shared__ float sm[4];
  const int t = threadIdx.x;
  float sd = 0.f, sr = 0.f;
  for (int i = t; i < 1024; i += 256) { sd += part_d[i]; sr += part_r_old[i]; }
  blockRed2(sd, sr, sm2);
  const bool cont = sr > 1e-10f;
  const float alpha = cont ? sr / sd : 0.f;   // alpha=0 => x,r (and rTr) frozen exactly
  const int base = blockIdx.x * 512;
  float s = 0.f;
  #pragma unroll
  for (int e = 0; e < 2; ++e) {
    int idx = base + t + (e << 8);
    float2 pv = p[idx], av = Ap[idx], xv = x[idx], rv = r[idx];
    xv.x = fmaf(alpha, pv.x, xv.x); xv.y = fmaf(alpha, pv.y, xv.y);
    rv.x = fmaf(-alpha, av.x, rv.x); rv.y = fmaf(-alpha, av.y, rv.y);
    x[idx] = xv; r[idx] = rv;
    s = fmaf(rv.x, rv.x, fmaf(rv.y, rv.y, s));
  }
  float tot = blockRed256(s, sm);
  if (t == 0) part_r_new[blockIdx.x] = tot;
}

__global__ __launch_bounds__(256) void k_final(const float2* __restrict__ x,
                                               float* __restrict__ out) {
  const int t = threadIdx.x;
  const int base = blockIdx.x * 512;
  #pragma unroll
  for (int e = 0; e < 2; ++e) {
    int idx = base + t + (e << 8);
    int b = idx >> 16, pix = idx & 65535;
    float2 v = x[idx];
    out[(b << 17) + pix] = v.x;
    out[(b << 17) + 65536 + pix] = v.y;
  }
}

// ---------------- driver ----------------
extern "C" void kernel_launch(void* const* d_in, const int* in_sizes, int n_in,
                              void* d_out, int out_size, void* d_ws, size_t ws_size,
                              hipStream_t stream) {
  (void)in_sizes; (void)n_in; (void)out_size; (void)ws_size;
  const float* atb   = (const float*)d_in[0];
  const float* csm_r = (const float*)d_in[1];
  const float* csm_i = (const float*)d_in[2];
  const float* mask  = (const float*)d_in[3];
  const float* w1 = (const float*)d_in[4];  const float* b1 = (const float*)d_in[5];
  const float* w2 = (const float*)d_in[6];  const float* b2 = (const float*)d_in[7];
  const float* w3 = (const float*)d_in[8];  const float* b3 = (const float*)d_in[9];
  const float* w4 = (const float*)d_in[10]; const float* b4 = (const float*)d_in[11];
  const float* w5 = (const float*)d_in[12]; const float* b5 = (const float*)d_in[13];
  const float* lam = (const float*)d_in[14];

  char* ws = (char*)d_ws;
  // CNN phase: actA@0 (32 MB), actB@33554432 (32 MB) — alias CG coil/x/r region
  unsigned short* actA = (unsigned short*)ws;
  unsigned short* actB = (unsigned short*)(ws + 33554432);
  // CG phase
  float2* coil = (float2*)ws;                        // 50331648 B
  float2* x    = (float2*)(ws + 50331648);
  float2* r    = (float2*)(ws + 54525952);
  float2* pbuf0= (float2*)(ws + 58720256);
  float2* Ap   = (float2*)(ws + 62914560);
  float2* rhs  = (float2*)(ws + 67108864);           // 4 MB; doubles as pbuf1 after cg_init
  float2* pbuf1= rhs;
  float*  w1T  = (float*)(ws + 71303168);            // 4608 B
  unsigned short* bf2 = (unsigned short*)(ws + 71307776);  // 73728 B each
  unsigned short* bf3 = (unsigned short*)(ws + 71381504);
  unsigned short* bf4 = (unsigned short*)(ws + 71455232);
  unsigned short* bf5 = (unsigned short*)(ws + 71528960);  // 18432 B
  float2* tw   = (float2*)(ws + 71547392);           // 512 float2 = 4096 B
  float2* twf  = tw + 256;
  float*  part = (float*)(ws + 71551488);            // part_d 1024 + 12x1024 part_r
  float*  part_d = part;
  float*  part_r = part + 1024;

  // prep
  k_twiddle<<<1, 256, 0, stream>>>(tw);
  k_transpose_w<<<5, 256, 0, stream>>>(w1, w1T, 2, 64);
  k_bfrag<<<144, 256, 0, stream>>>(w2, bf2);
  k_bfrag<<<144, 256, 0, stream>>>(w3, bf3);
  k_bfrag<<<144, 256, 0, stream>>>(w4, bf4);
  k_bfrag5<<<36, 256, 0, stream>>>(w5, bf5);

  // CNN: two halves of 4 images each
  for (int half = 0; half < 2; ++half) {
    const float* atb_h = atb + (size_t)half * 4 * 131072;
    float2* rhs_h = rhs + (size_t)half * 4 * 65536;
    k_conv1<<<dim3(16, 16, 4), 256, 0, stream>>>(atb_h, w1T, b1, actA);
    k_conv_mfma<<<dim3(16, 16, 4), 512, 0, stream>>>(actA, bf2, b2, actB);
    k_conv_mfma<<<dim3(16, 16, 4), 512, 0, stream>>>(actB, bf3, b3, actA);
    k_conv_mfma<<<dim3(16, 16, 4), 512, 0, stream>>>(actA, bf4, b4, actB);
    k_conv5_rhs<<<dim3(16, 16, 4), 512, 0, stream>>>(actB, bf5, b5, atb_h, lam, rhs_h);
  }

  // CG
  k_cg_init<<<1024, 256, 0, stream>>>(rhs, x, r, pbuf0, part_r);
  for (int it = 0; it < 11; ++it) {
    float2* p_cur = (it % 2 == 0) ? pbuf0 : pbuf1;
    float2* p_prv = (it == 0) ? pbuf0 : ((it % 2 == 0) ? pbuf1 : pbuf0);
    const float* pro = part_r + (it > 0 ? (it - 1) : 0) * 1024;
    const float* prn = part_r + it * 1024;
    k_coil_fft_rows<<<dim3(96, 16), 256, 0, stream>>>(
        p_prv, r, p_cur, pro, prn, it == 0 ? 1 : 0, csm_r, csm_i, twf, coil);
    k_fft_cols_mask<<<dim3(96, 16), 256, 0, stream>>>(coil, mask, twf);
    k_ifft_rows_acc<<<dim3(8, 16, 4), 256, 0, stream>>>(coil, csm_r, csm_i, twf);
    k_combine<<<1024, 256, 0, stream>>>(coil, p_cur, lam, Ap, part_d);
    k_update1<<<1024, 256, 0, stream>>>(x, r, p_cur, Ap, part_d,
                                        part_r + it * 1024, part_r + (it + 1) * 1024);
  }

  k_final<<<1024, 256, 0, stream>>>(x, (float*)d_out);
}

// Round 6
// 1110.350 us; speedup vs baseline: 6.4457x; 1.1085x over previous
//
#include <hip/hip_runtime.h>
#include <hip/hip_bf16.h>
#include <math.h>

static constexpr int NCOIL = 12;
static constexpr int HWSZ  = 65536;   // 256*256

typedef short v8s __attribute__((ext_vector_type(8)));
typedef float v4f __attribute__((ext_vector_type(4)));

__device__ __forceinline__ unsigned short f2bf(float v) {
  __hip_bfloat16 h = __float2bfloat16(v);
  union { __hip_bfloat16 h; unsigned short u; } cv; cv.h = h; return cv.u;
}
__device__ __forceinline__ float bf2f(unsigned short u) {
  return __uint_as_float(((unsigned)u) << 16);
}
__device__ __forceinline__ unsigned pack_bf(float2 v) {
  return ((unsigned)f2bf(v.y) << 16) | (unsigned)f2bf(v.x);
}
__device__ __forceinline__ float2 unpack_bf(unsigned u) {
  return make_float2(bf2f((unsigned short)(u & 0xffffu)),
                     bf2f((unsigned short)(u >> 16)));
}

// ---------------- complex helpers ----------------
__device__ __forceinline__ float2 cmulf(float2 a, float2 b) {
  return make_float2(a.x * b.x - a.y * b.y, a.x * b.y + a.y * b.x);
}
__device__ __forceinline__ float2 caddf(float2 a, float2 b) {
  return make_float2(a.x + b.x, a.y + b.y);
}
__device__ __forceinline__ float2 csubf(float2 a, float2 b) {
  return make_float2(a.x - b.x, a.y - b.y);
}

// ---------------- block reductions ----------------
__device__ __forceinline__ float blockRed256(float v, float* sm) {
  #pragma unroll
  for (int off = 32; off; off >>= 1) v += __shfl_down(v, off);
  int lane = threadIdx.x & 63, wv = threadIdx.x >> 6;
  if (lane == 0) sm[wv] = v;
  __syncthreads();
  return sm[0] + sm[1] + sm[2] + sm[3];
}

__device__ __forceinline__ void blockRed2(float& a, float& b, float2* sm) {
  #pragma unroll
  for (int off = 32; off; off >>= 1) {
    a += __shfl_down(a, off);
    b += __shfl_down(b, off);
  }
  int lane = threadIdx.x & 63, wv = threadIdx.x >> 6;
  if (lane == 0) sm[wv] = make_float2(a, b);
  __syncthreads();
  float2 s0 = sm[0], s1 = sm[1], s2 = sm[2], s3 = sm[3];
  a = s0.x + s1.x + s2.x + s3.x;
  b = s0.y + s1.y + s2.y + s3.y;
}

// ---------------- in-register 16-pt DFT (four-step building block) ----------------
__device__ __constant__ const float TC16[8] = {
  1.f, 0.92387953f, 0.70710678f, 0.38268343f, 0.f, -0.38268343f, -0.70710678f, -0.92387953f};
__device__ __constant__ const float TS16[8] = {
  0.f, -0.38268343f, -0.70710678f, -0.92387953f, -1.f, -0.92387953f, -0.70710678f, -0.38268343f};
__device__ __constant__ const int REV4[16] = {0,8,4,12,2,10,6,14,1,9,5,13,3,11,7,15};

// DIF: natural input -> output reg r holds X[rev4(r)]
template<int INV>
__device__ __forceinline__ void dif16(float2 v[16]) {
  #pragma unroll
  for (int ls = 0; ls < 4; ++ls) {
    const int len = 16 >> ls, half = len >> 1, step = 1 << ls;
    #pragma unroll
    for (int i = 0; i < 16; i += len) {
      #pragma unroll
      for (int j = 0; j < half; ++j) {
        float2 a = v[i + j], b = v[i + j + half];
        v[i + j] = caddf(a, b);
        float2 d = csubf(a, b);
        float cr = TC16[j * step];
        float ci = INV ? -TS16[j * step] : TS16[j * step];
        v[i + j + half] = make_float2(d.x * cr - d.y * ci, d.x * ci + d.y * cr);
      }
    }
  }
}

// DIT: input reg r holds in[rev4(r)] -> natural-order output
template<int INV>
__device__ __forceinline__ void dit16(float2 v[16]) {
  #pragma unroll
  for (int ls = 0; ls < 4; ++ls) {
    const int len = 2 << ls, half = len >> 1, step = 16 / len;
    #pragma unroll
    for (int i = 0; i < 16; i += len) {
      #pragma unroll
      for (int j = 0; j < half; ++j) {
        float cr = TC16[j * step];
        float ci = INV ? -TS16[j * step] : TS16[j * step];
        float2 b = v[i + j + half];
        float2 tt = make_float2(b.x * cr - b.y * ci, b.x * ci + b.y * cr);
        float2 a = v[i + j];
        v[i + j] = caddf(a, tt);
        v[i + j + half] = csubf(a, tt);
      }
    }
  }
}

// ---------------- prep kernels ----------------
__global__ void k_twiddle(float2* __restrict__ twf) {
  int t = threadIdx.x;
  float ang = -6.28318530717958647692f * (float)t / 256.f;
  float s, c; sincosf(ang, &s, &c);
  twf[t] = make_float2(c, s);
}

// csm fp32 r/i planes -> packed bf16x2
__global__ void k_csm_pack(const float* __restrict__ cr, const float* __restrict__ ci,
                           unsigned* __restrict__ o, int n) {
  int t = blockIdx.x * 256 + threadIdx.x;
  if (t < n) o[t] = ((unsigned)f2bf(ci[t]) << 16) | (unsigned)f2bf(cr[t]);
}

// w [OC][IC][3][3] -> wT [IC*9][OC]  (fp32, for layer 1)
__global__ void k_transpose_w(const float* __restrict__ w, float* __restrict__ wT,
                              int IC, int OC) {
  int i = blockIdx.x * 256 + threadIdx.x;
  int total = IC * 9 * OC;
  if (i >= total) return;
  int oc = i % OC;
  int rest = i / OC;
  int ic = rest / 9, k = rest - ic * 9;
  wT[i] = w[(oc * IC + ic) * 9 + k];
}

// w [64][64][3][3] fp32 -> B-fragment order bf16: [ks=18][ocg=4][lane=64][j=8]
__global__ void k_bfrag(const float* __restrict__ w, unsigned short* __restrict__ bf) {
  int i = blockIdx.x * 256 + threadIdx.x;
  if (i >= 36864) return;
  int j = i & 7, lane = (i >> 3) & 63, ocg = (i >> 9) & 3, ks = i >> 11;
  int oc = (ocg << 4) + (lane & 15);
  int ic = ((ks & 1) << 5) + (((lane >> 4) & 3) << 3) + j;
  int tap = ks >> 1;
  bf[i] = f2bf(w[(oc * 64 + ic) * 9 + tap]);
}

// w5 [2][64][3][3] -> B-fragment bf16 [ks=18][lane=64][j=8], oc padded 2->16
__global__ void k_bfrag5(const float* __restrict__ w, unsigned short* __restrict__ bf) {
  int i = blockIdx.x * 256 + threadIdx.x;
  if (i >= 9216) return;
  int j = i & 7, lane = (i >> 3) & 63, ks = i >> 9;
  int oc = lane & 15;
  int ic = ((ks & 1) << 5) + (((lane >> 4) & 3) << 3) + j;
  int tap = ks >> 1;
  bf[i] = (oc < 2) ? f2bf(w[(oc * 64 + ic) * 9 + tap]) : (unsigned short)0;
}

// ---------------- layer 1: fp32 direct conv (IC=2), out pixel-major bf16 ----------------
__global__ __launch_bounds__(256) void k_conv1(
    const float* __restrict__ atb,   // [8][2][256][256]
    const float* __restrict__ w1T,   // [18][64]
    const float* __restrict__ b1,
    unsigned short* __restrict__ out)// [8][256][256][64] bf16
{
  __shared__ float patch[2 * 324];
  const int t = threadIdx.x;
  const int img = blockIdx.z;
  const float* in = atb + (size_t)img * 131072;
  const int tx0 = blockIdx.x << 4, ty0 = blockIdx.y << 4;
  for (int i = t; i < 648; i += 256) {
    int ic = i / 324, rem = i - ic * 324;
    int py = rem / 18, px = rem - py * 18;
    int gy = ty0 + py - 1, gx = tx0 + px - 1;
    float v = 0.f;
    if ((unsigned)gy < 256u && (unsigned)gx < 256u)
      v = in[(ic << 16) + (gy << 8) + gx];
    patch[i] = v;
  }
  __syncthreads();
  const int tx = t & 15, ty = t >> 4;
  float acc[64];
  #pragma unroll
  for (int o = 0; o < 64; ++o) acc[o] = 0.f;
  #pragma unroll
  for (int ic = 0; ic < 2; ++ic) {
    const float* pb = &patch[ic * 324 + ty * 18 + tx];
    #pragma unroll
    for (int k = 0; k < 9; ++k) {
      const float v = pb[(k / 3) * 18 + (k % 3)];
      const float* wr = &w1T[(ic * 9 + k) << 6];
      #pragma unroll
      for (int o = 0; o < 64; ++o) acc[o] = fmaf(v, wr[o], acc[o]);
    }
  }
  size_t obase = ((size_t)img << 22) + ((size_t)(((ty0 + ty) << 8) + tx0 + tx) << 6);
  v8s* outv = (v8s*)(out + obase);
  #pragma unroll
  for (int g = 0; g < 8; ++g) {
    v8s ov;
    #pragma unroll
    for (int j = 0; j < 8; ++j) {
      float v = fmaxf(acc[(g << 3) + j] + b1[(g << 3) + j], 0.f);
      ov[j] = (short)f2bf(v);
    }
    outv[g] = ov;
  }
}

// ---------------- layers 2-4: bf16 MFMA implicit GEMM (16x16 tile, 8 waves) ----------------
__global__ __launch_bounds__(512, 4) void k_conv_mfma(
    const unsigned short* __restrict__ in,
    const unsigned short* __restrict__ bfrag,
    const float* __restrict__ bias,
    unsigned short* __restrict__ out)
{
  __shared__ v8s halo[2592];   // 18x18 px x 8 slots of 8ch, swizzled: 41472 B
  char* hb = (char*)halo;
  const int t = threadIdx.x;
  const int img = blockIdx.z;
  const int tx0 = blockIdx.x << 4, ty0 = blockIdx.y << 4;
  const size_t ibase = ((size_t)img << 22);
  for (int c = t; c < 2592; c += 512) {
    int hy = c / 144, rem = c - hy * 144;
    int hx = rem >> 3, slot = rem & 7;
    int gy = ty0 + hy - 1, gx = tx0 + hx - 1;
    v8s v = {0, 0, 0, 0, 0, 0, 0, 0};
    if ((unsigned)gy < 256u && (unsigned)gx < 256u)
      v = *(const v8s*)(in + ibase + ((size_t)((gy << 8) + gx) << 6) + (slot << 3));
    int xl = hy * 18 + hx;
    *(v8s*)(hb + xl * 128 + ((slot ^ (xl & 7)) << 4)) = v;
  }
  __syncthreads();
  const int lane = t & 63, w = t >> 6;
  const int px = lane & 15, lg = lane >> 4;
  v4f acc[2][4];
  #pragma unroll
  for (int pf = 0; pf < 2; ++pf)
    #pragma unroll
    for (int og = 0; og < 4; ++og)
      #pragma unroll
      for (int rg = 0; rg < 4; ++rg) acc[pf][og][rg] = 0.f;

  #pragma unroll
  for (int ks = 0; ks < 18; ++ks) {
    const int tap = ks >> 1;
    const int dy = tap / 3, dx = tap - dy * 3;
    const int slot = ((ks & 1) << 2) | lg;
    v8s b0 = *(const v8s*)(bfrag + ((((ks << 2) | 0) * 64 + lane) << 3));
    v8s b1 = *(const v8s*)(bfrag + ((((ks << 2) | 1) * 64 + lane) << 3));
    v8s b2 = *(const v8s*)(bfrag + ((((ks << 2) | 2) * 64 + lane) << 3));
    v8s b3 = *(const v8s*)(bfrag + ((((ks << 2) | 3) * 64 + lane) << 3));
    #pragma unroll
    for (int pf = 0; pf < 2; ++pf) {
      int xl = (w * 2 + pf + dy) * 18 + px + dx;
      v8s a = *(const v8s*)(hb + xl * 128 + ((slot ^ (xl & 7)) << 4));
      acc[pf][0] = __builtin_amdgcn_mfma_f32_16x16x32_bf16(a, b0, acc[pf][0], 0, 0, 0);
      acc[pf][1] = __builtin_amdgcn_mfma_f32_16x16x32_bf16(a, b1, acc[pf][1], 0, 0, 0);
      acc[pf][2] = __builtin_amdgcn_mfma_f32_16x16x32_bf16(a, b2, acc[pf][2], 0, 0, 0);
      acc[pf][3] = __builtin_amdgcn_mfma_f32_16x16x32_bf16(a, b3, acc[pf][3], 0, 0, 0);
    }
  }
  const int ocl = lane & 15;
  float bv[4];
  #pragma unroll
  for (int og = 0; og < 4; ++og) bv[og] = bias[(og << 4) + ocl];
  #pragma unroll
  for (int pf = 0; pf < 2; ++pf) {
    const int gy = ty0 + w * 2 + pf;
    #pragma unroll
    for (int og = 0; og < 4; ++og) {
      const int oc = (og << 4) + ocl;
      #pragma unroll
      for (int rg = 0; rg < 4; ++rg) {
        float v = fmaxf(acc[pf][og][rg] + bv[og], 0.f);
        int gx = tx0 + (lg << 2) + rg;
        out[ibase + ((size_t)((gy << 8) + gx) << 6) + oc] = f2bf(v);
      }
    }
  }
}

// ---------------- layer 5 (64->2, MFMA) + rhs = atb + lam*(atb + conv5) ----------------
__global__ __launch_bounds__(512, 4) void k_conv5_rhs(
    const unsigned short* __restrict__ in,
    const unsigned short* __restrict__ bf5,
    const float* __restrict__ b5,
    const float* __restrict__ atb,
    const float* __restrict__ lam,
    float2* __restrict__ rhs)
{
  __shared__ v8s halo[2592];
  char* hb = (char*)halo;
  const int t = threadIdx.x;
  const int img = blockIdx.z;
  const int tx0 = blockIdx.x << 4, ty0 = blockIdx.y << 4;
  const size_t ibase = ((size_t)img << 22);
  for (int c = t; c < 2592; c += 512) {
    int hy = c / 144, rem = c - hy * 144;
    int hx = rem >> 3, slot = rem & 7;
    int gy = ty0 + hy - 1, gx = tx0 + hx - 1;
    v8s v = {0, 0, 0, 0, 0, 0, 0, 0};
    if ((unsigned)gy < 256u && (unsigned)gx < 256u)
      v = *(const v8s*)(in + ibase + ((size_t)((gy << 8) + gx) << 6) + (slot << 3));
    int xl = hy * 18 + hx;
    *(v8s*)(hb + xl * 128 + ((slot ^ (xl & 7)) << 4)) = v;
  }
  __syncthreads();
  const int lane = t & 63, w = t >> 6;
  const int px = lane & 15, lg = lane >> 4;
  v4f acc[2];
  #pragma unroll
  for (int pf = 0; pf < 2; ++pf)
    #pragma unroll
    for (int rg = 0; rg < 4; ++rg) acc[pf][rg] = 0.f;
  #pragma unroll
  for (int ks = 0; ks < 18; ++ks) {
    const int tap = ks >> 1;
    const int dy = tap / 3, dx = tap - dy * 3;
    const int slot = ((ks & 1) << 2) | lg;
    v8s b = *(const v8s*)(bf5 + (((ks * 64) + lane) << 3));
    #pragma unroll
    for (int pf = 0; pf < 2; ++pf) {
      int xl = (w * 2 + pf + dy) * 18 + px + dx;
      v8s a = *(const v8s*)(hb + xl * 128 + ((slot ^ (xl & 7)) << 4));
      acc[pf] = __builtin_amdgcn_mfma_f32_16x16x32_bf16(a, b, acc[pf], 0, 0, 0);
    }
  }
  const int ocl = lane & 15;
  const float l = *lam;
  const float bsel = b5[ocl & 1];
  #pragma unroll
  for (int pf = 0; pf < 2; ++pf) {
    const int gy = ty0 + w * 2 + pf;
    #pragma unroll
    for (int rg = 0; rg < 4; ++rg) {
      float v = acc[pf][rg] + bsel;
      float d1 = __shfl_down(v, 1);
      if (ocl == 0) {
        int gx = tx0 + (lg << 2) + rg;
        int pix = (gy << 8) + gx;
        float x0 = atb[(size_t)img * 131072 + pix];
        float x1 = atb[(size_t)img * 131072 + 65536 + pix];
        rhs[(size_t)img * 65536 + pix] =
            make_float2(fmaf(l, x0 + v, x0), fmaf(l, x1 + d1, x1));
      }
    }
  }
}

// ---- AtA pass 1: (fused p-update) coil = csm*p (bf16 out), row FFT, part_p ----
__global__ __launch_bounds__(256) void k_coil_fft_rows(
    const float2* __restrict__ p_prev, const float2* __restrict__ r,
    float2* __restrict__ p_out,
    const float* __restrict__ part_r_old, const float* __restrict__ part_r_new,
    const int first,
    const unsigned* __restrict__ csmh, const float2* __restrict__ twf,
    unsigned* __restrict__ coil, float* __restrict__ part_p)
{
  __shared__ float2 trans[4096];
  __shared__ float2 sm2[4];
  __shared__ float sm1[4];
  const int t = threadIdx.x;
  const int bc = blockIdx.x, b = bc / NCOIL, c = bc - b * NCOIL;
  const int idx = t & 15, row16 = t >> 4;
  const int row = (blockIdx.y << 4) + row16;

  float beta = 0.f; bool do_upd = false;
  if (!first) {
    float so = 0.f, sn = 0.f;
    for (int i = t; i < 1024; i += 256) { so += part_r_old[i]; sn += part_r_new[i]; }
    blockRed2(so, sn, sm2);
    do_upd = so > 1e-10f;
    beta = do_upd ? sn / so : 0.f;
  }

  const int pb = (b << 16) + (row << 8);
  const int gb = (bc << 16) + (row << 8);
  float2 v[16];
  float pe = 0.f;
  #pragma unroll
  for (int h2 = 0; h2 < 16; ++h2) {
    int n = idx + (h2 << 4);
    float2 pv = p_prev[pb + n];
    if (!first && do_upd) {
      float2 rv = r[pb + n];
      pv = make_float2(fmaf(beta, pv.x, rv.x), fmaf(beta, pv.y, rv.y));
    }
    if (c == 0) {
      if (!first) p_out[pb + n] = pv;
      pe = fmaf(pv.x, pv.x, fmaf(pv.y, pv.y, pe));
    }
    float2 cs = unpack_bf(csmh[gb + n]);
    v[h2] = make_float2(cs.x * pv.x - cs.y * pv.y, cs.x * pv.y + cs.y * pv.x);
  }
  if (c == 0) {
    float tot = blockRed256(pe, sm1);
    if (t == 0) part_p[(b << 4) + blockIdx.y] = tot;
  }
  // forward four-step along W
  dif16<0>(v);
  #pragma unroll
  for (int rr = 0; rr < 16; ++rr) {
    int k1 = REV4[rr];
    v[rr] = cmulf(v[rr], twf[idx * k1]);
    trans[(k1 << 8) + (row16 << 4) + (idx ^ k1)] = v[rr];
  }
  __syncthreads();
  #pragma unroll
  for (int h1 = 0; h1 < 16; ++h1)
    v[h1] = trans[(idx << 8) + (row16 << 4) + (h1 ^ idx)];
  dif16<0>(v);
  #pragma unroll
  for (int rr = 0; rr < 16; ++rr)
    coil[gb + idx + (REV4[rr] << 4)] = pack_bf(v[rr]);
}

// ---- AtA pass 2: col FFT + mask (+part_m) + col IFFT, bf16 coil in/out ----
__global__ __launch_bounds__(256) void k_fft_cols_mask(
    unsigned* __restrict__ coil, const float* __restrict__ mask,
    const float2* __restrict__ twf, float* __restrict__ part_m)
{
  __shared__ float2 trans[4096];
  __shared__ float smR[4];
  const int t = threadIdx.x;
  const int bc = blockIdx.x, b = bc / NCOIL;
  const int w0 = blockIdx.y << 4;
  const int col = t & 15, idx = t >> 4;
  const int base = (bc << 16) + w0 + col;
  float2 v[16];
  #pragma unroll
  for (int h2 = 0; h2 < 16; ++h2)
    v[h2] = unpack_bf(coil[base + ((idx + (h2 << 4)) << 8)]);
  // ---- forward ----
  dif16<0>(v);
  #pragma unroll
  for (int r = 0; r < 16; ++r) {
    int k1 = REV4[r];
    v[r] = cmulf(v[r], twf[idx * k1]);
    trans[(idx << 8) + (k1 << 4) + col] = v[r];
  }
  __syncthreads();
  #pragma unroll
  for (int h1 = 0; h1 < 16; ++h1)
    v[h1] = trans[(h1 << 8) + (idx << 4) + col];
  __syncthreads();
  dif16<0>(v);
  // ---- mask in registers + k-space energy partial (denominator) ----
  float pm = 0.f;
  #pragma unroll
  for (int r = 0; r < 16; ++r) {
    float mv = mask[(b << 16) + ((idx + (REV4[r] << 4)) << 8) + w0 + col];
    v[r].x *= mv; v[r].y *= mv;
    pm = fmaf(v[r].x, v[r].x, fmaf(v[r].y, v[r].y, pm));
  }
  float tot = blockRed256(pm, smR);   // internal barrier also guards trans reuse
  if (t == 0) part_m[(bc << 4) + blockIdx.y] = tot;
  // ---- inverse ----
  dit16<1>(v);
  #pragma unroll
  for (int r = 0; r < 16; ++r) {
    float2 w = twf[idx * r];
    v[r] = make_float2(v[r].x * w.x + v[r].y * w.y, v[r].y * w.x - v[r].x * w.y);
    trans[(idx << 8) + (r << 4) + col] = v[r];
  }
  __syncthreads();
  #pragma unroll
  for (int k1 = 0; k1 < 16; ++k1)
    v[k1] = trans[(k1 << 8) + (idx << 4) + col];
  dif16<1>(v);
  const float sc = 1.f / 256.f;
  #pragma unroll
  for (int r = 0; r < 16; ++r)
    coil[base + ((idx + (REV4[r] << 4)) << 8)] =
        pack_bf(make_float2(v[r].x * sc, v[r].y * sc));
}

// ---- AtA pass 3: row IFFT + conj(csm) partial sum over 3 coils -> fp32 partials ----
__global__ __launch_bounds__(256) void k_ifft_rows_acc(
    const unsigned* __restrict__ coil, const unsigned* __restrict__ csmh,
    const float2* __restrict__ twf, float2* __restrict__ partbuf)
{
  __shared__ float2 trans[4096];
  const int t = threadIdx.x;
  const int b = blockIdx.x, cs = blockIdx.z;
  const int idx = t & 15, row16 = t >> 4;
  const int row = (blockIdx.y << 4) + row16;
  float2 acc[16];
  #pragma unroll
  for (int rr = 0; rr < 16; ++rr) acc[rr] = make_float2(0.f, 0.f);
  for (int j = 0; j < 3; ++j) {
    const int c = cs * 3 + j;
    const int gb = ((b * NCOIL + c) << 16) + (row << 8);
    float2 v[16];
    #pragma unroll
    for (int rr = 0; rr < 16; ++rr)
      v[rr] = unpack_bf(coil[gb + idx + (REV4[rr] << 4)]);
    dit16<1>(v);
    if (j) __syncthreads();
    #pragma unroll
    for (int rr = 0; rr < 16; ++rr) {
      float2 w = twf[idx * rr];
      float2 z = v[rr];
      trans[(rr << 8) + (row16 << 4) + (idx ^ rr)] =
          make_float2(z.x * w.x + z.y * w.y, z.y * w.x - z.x * w.y);
    }
    __syncthreads();
    #pragma unroll
    for (int k1 = 0; k1 < 16; ++k1)
      v[k1] = trans[(idx << 8) + (row16 << 4) + (k1 ^ idx)];
    dif16<1>(v);
    #pragma unroll
    for (int rr = 0; rr < 16; ++rr) {
      int gi = gb + idx + (REV4[rr] << 4);
      float2 cw = unpack_bf(csmh[gi]);
      float2 z = v[rr];
      acc[rr].x += cw.x * z.x + cw.y * z.y;
      acc[rr].y += cw.x * z.y - cw.y * z.x;
    }
  }
  const int ob = (((cs << 3) + b) << 16) + (row << 8);
  #pragma unroll
  for (int rr = 0; rr < 16; ++rr)
    partbuf[ob + idx + (REV4[rr] << 4)] = acc[rr];
}

// ---- update1: alpha from energy-denominator, Ap inline, x,r update, part_r ----
__global__ __launch_bounds__(256) void k_update1(
    float2* __restrict__ x, float2* __restrict__ r, const float2* __restrict__ p,
    const float2* __restrict__ partbuf,
    const float* __restrict__ part_m, const float* __restrict__ part_p,
    const float* __restrict__ part_r_old, float* __restrict__ part_r_new,
    const float* __restrict__ lam)
{
  __shared__ float2 sm2[4];
  __shared__ float smA[4];
  __shared__ float smB[4];
  const int t = threadIdx.x;
  float se = 0.f, sp = 0.f, sr = 0.f;
  for (int i = t; i < 1536; i += 256) se += part_m[i];
  if (t < 128) sp = part_p[t];
  for (int i = t; i < 1024; i += 256) sr += part_r_old[i];
  blockRed2(se, sp, sm2);
  sr = blockRed256(sr, smA);
  const float l = *lam;
  const float denom = se * (1.f / 65536.f) + l * sp;
  const bool cont = sr > 1e-10f;
  const float alpha = cont ? sr / denom : 0.f;  // alpha=0 => x,r,rTr frozen exactly
  const float inv2 = 1.f / 256.f;
  float s = 0.f;
  #pragma unroll
  for (int e = 0; e < 2; ++e) {
    int pix = blockIdx.x * 512 + t + (e << 8);
    int b = pix >> 16, off = pix & 65535;
    float2 s0 = partbuf[(b << 16) + off];
    float2 s1 = partbuf[((8 + b) << 16) + off];
    float2 s2 = partbuf[((16 + b) << 16) + off];
    float2 s3 = partbuf[((24 + b) << 16) + off];
    float sx = (s0.x + s1.x) + (s2.x + s3.x);
    float sy = (s0.y + s1.y) + (s2.y + s3.y);
    float2 pv = p[pix], xv = x[pix], rv = r[pix];
    float2 apv = make_float2(fmaf(l, pv.x, sx * inv2), fmaf(l, pv.y, sy * inv2));
    xv.x = fmaf(alpha, pv.x, xv.x); xv.y = fmaf(alpha, pv.y, xv.y);
    rv.x = fmaf(-alpha, apv.x, rv.x); rv.y = fmaf(-alpha, apv.y, rv.y);
    x[pix] = xv; r[pix] = rv;
    s = fmaf(rv.x, rv.x, fmaf(rv.y, rv.y, s));
  }
  float tot = blockRed256(s, smB);
  if (t == 0) part_r_new[blockIdx.x] = tot;
}

// ---------------- CG init / final ----------------
__global__ __launch_bounds__(256) void k_cg_init(
    const float2* __restrict__ rhs, float2* __restrict__ x,
    float2* __restrict__ r, float2* __restrict__ p, float* __restrict__ part)
{
  __shared__ float sm[4];
  const int t = threadIdx.x;
  const int base = blockIdx.x * 512;
  float s = 0.f;
  #pragma unroll
  for (int e = 0; e < 2; ++e) {
    int idx = base + t + (e << 8);
    float2 v = rhs[idx];
    x[idx] = make_float2(0.f, 0.f);
    r[idx] = v; p[idx] = v;
    s = fmaf(v.x, v.x, fmaf(v.y, v.y, s));
  }
  float tot = blockRed256(s, sm);
  if (t == 0) part[blockIdx.x] = tot;
}

__global__ __launch_bounds__(256) void k_final(const float2* __restrict__ x,
                                               float* __restrict__ out) {
  const int t = threadIdx.x;
  const int base = blockIdx.x * 512;
  #pragma unroll
  for (int e = 0; e < 2; ++e) {
    int idx = base + t + (e << 8);
    int b = idx >> 16, pix = idx & 65535;
    float2 v = x[idx];
    out[(b << 17) + pix] = v.x;
    out[(b << 17) + 65536 + pix] = v.y;
  }
}

// ---------------- driver ----------------
extern "C" void kernel_launch(void* const* d_in, const int* in_sizes, int n_in,
                              void* d_out, int out_size, void* d_ws, size_t ws_size,
                              hipStream_t stream) {
  (void)in_sizes; (void)n_in; (void)out_size; (void)ws_size;
  const float* atb   = (const float*)d_in[0];
  const float* csm_r = (const float*)d_in[1];
  const float* csm_i = (const float*)d_in[2];
  const float* mask  = (const float*)d_in[3];
  const float* w1 = (const float*)d_in[4];  const float* b1 = (const float*)d_in[5];
  const float* w2 = (const float*)d_in[6];  const float* b2 = (const float*)d_in[7];
  const float* w3 = (const float*)d_in[8];  const float* b3 = (const float*)d_in[9];
  const float* w4 = (const float*)d_in[10]; const float* b4 = (const float*)d_in[11];
  const float* w5 = (const float*)d_in[12]; const float* b5 = (const float*)d_in[13];
  const float* lam = (const float*)d_in[14];

  char* ws = (char*)d_ws;   // ws_size observed = 256 MiB; we use ~218.4 MB
  unsigned short* actA = (unsigned short*)ws;                  // 64 MiB
  unsigned short* actB = (unsigned short*)(ws + 67108864);     // 64 MiB
  unsigned* coil   = (unsigned*)(ws + 134217728);              // 25165824 B (bf16x2)
  float2* partbuf  = (float2*)(ws + 159383552);                // 16777216 B
  float2* x        = (float2*)(ws + 176160768);                // 4 MiB
  float2* r        = (float2*)(ws + 180355072);
  float2* pbuf0    = (float2*)(ws + 184549376);
  float2* rhs      = (float2*)(ws + 188743680);                // doubles as pbuf1
  float2* pbuf1    = rhs;
  unsigned* csmh   = (unsigned*)(ws + 192937984);              // 25165824 B
  float*  w1T      = (float*)(ws + 218103808);                 // 4608 B
  unsigned short* bf2 = (unsigned short*)(ws + 218108416);     // 73728 B each
  unsigned short* bf3 = (unsigned short*)(ws + 218182144);
  unsigned short* bf4 = (unsigned short*)(ws + 218255872);
  unsigned short* bf5 = (unsigned short*)(ws + 218329600);     // 18432 B
  float2* twf      = (float2*)(ws + 218348032);                // 2048 B
  float*  part_r   = (float*)(ws + 218350080);                 // 12*1024*4
  float*  part_m   = (float*)(ws + 218399232);                 // 1536*4
  float*  part_p   = (float*)(ws + 218405376);                 // 128*4

  // prep
  k_twiddle<<<1, 256, 0, stream>>>(twf);
  k_transpose_w<<<5, 256, 0, stream>>>(w1, w1T, 2, 64);
  k_bfrag<<<144, 256, 0, stream>>>(w2, bf2);
  k_bfrag<<<144, 256, 0, stream>>>(w3, bf3);
  k_bfrag<<<144, 256, 0, stream>>>(w4, bf4);
  k_bfrag5<<<36, 256, 0, stream>>>(w5, bf5);
  k_csm_pack<<<24576, 256, 0, stream>>>(csm_r, csm_i, csmh, 6291456);

  // CNN: full batch, z = 8
  k_conv1<<<dim3(16, 16, 8), 256, 0, stream>>>(atb, w1T, b1, actA);
  k_conv_mfma<<<dim3(16, 16, 8), 512, 0, stream>>>(actA, bf2, b2, actB);
  k_conv_mfma<<<dim3(16, 16, 8), 512, 0, stream>>>(actB, bf3, b3, actA);
  k_conv_mfma<<<dim3(16, 16, 8), 512, 0, stream>>>(actA, bf4, b4, actB);
  k_conv5_rhs<<<dim3(16, 16, 8), 512, 0, stream>>>(actB, bf5, b5, atb, lam, rhs);

  // CG
  k_cg_init<<<1024, 256, 0, stream>>>(rhs, x, r, pbuf0, part_r);
  for (int it = 0; it < 11; ++it) {
    float2* p_cur = (it % 2 == 0) ? pbuf0 : pbuf1;
    float2* p_prv = (it == 0) ? pbuf0 : ((it % 2 == 0) ? pbuf1 : pbuf0);
    const float* pro = part_r + (it > 0 ? (it - 1) : 0) * 1024;
    const float* prn = part_r + it * 1024;
    k_coil_fft_rows<<<dim3(96, 16), 256, 0, stream>>>(
        p_prv, r, p_cur, pro, prn, it == 0 ? 1 : 0, csmh, twf, coil, part_p);
    k_fft_cols_mask<<<dim3(96, 16), 256, 0, stream>>>(coil, mask, twf, part_m);
    k_ifft_rows_acc<<<dim3(8, 16, 4), 256, 0, stream>>>(coil, csmh, twf, partbuf);
    k_update1<<<1024, 256, 0, stream>>>(x, r, p_cur, partbuf, part_m, part_p,
                                        part_r + it * 1024, part_r + (it + 1) * 1024, lam);
  }

  k_final<<<1024, 256, 0, stream>>>(x, (float*)d_out);
}

// Round 7
// 1089.784 us; speedup vs baseline: 6.5674x; 1.0189x over previous
//
#include <hip/hip_runtime.h>
#include <hip/hip_bf16.h>
#include <math.h>

static constexpr int NCOIL = 12;
static constexpr int HWSZ  = 65536;   // 256*256

typedef short v8s __attribute__((ext_vector_type(8)));
typedef float v4f __attribute__((ext_vector_type(4)));

__device__ __forceinline__ unsigned short f2bf(float v) {
  __hip_bfloat16 h = __float2bfloat16(v);
  union { __hip_bfloat16 h; unsigned short u; } cv; cv.h = h; return cv.u;
}
__device__ __forceinline__ float bf2f(unsigned short u) {
  return __uint_as_float(((unsigned)u) << 16);
}
__device__ __forceinline__ unsigned pack_bf(float2 v) {
  return ((unsigned)f2bf(v.y) << 16) | (unsigned)f2bf(v.x);
}
__device__ __forceinline__ float2 unpack_bf(unsigned u) {
  return make_float2(bf2f((unsigned short)(u & 0xffffu)),
                     bf2f((unsigned short)(u >> 16)));
}

// ---------------- complex helpers ----------------
__device__ __forceinline__ float2 cmulf(float2 a, float2 b) {
  return make_float2(a.x * b.x - a.y * b.y, a.x * b.y + a.y * b.x);
}
__device__ __forceinline__ float2 caddf(float2 a, float2 b) {
  return make_float2(a.x + b.x, a.y + b.y);
}
__device__ __forceinline__ float2 csubf(float2 a, float2 b) {
  return make_float2(a.x - b.x, a.y - b.y);
}

// ---------------- block reductions ----------------
__device__ __forceinline__ float blockRed256(float v, float* sm) {
  #pragma unroll
  for (int off = 32; off; off >>= 1) v += __shfl_down(v, off);
  int lane = threadIdx.x & 63, wv = threadIdx.x >> 6;
  if (lane == 0) sm[wv] = v;
  __syncthreads();
  return sm[0] + sm[1] + sm[2] + sm[3];
}

__device__ __forceinline__ void blockRed2(float& a, float& b, float2* sm) {
  #pragma unroll
  for (int off = 32; off; off >>= 1) {
    a += __shfl_down(a, off);
    b += __shfl_down(b, off);
  }
  int lane = threadIdx.x & 63, wv = threadIdx.x >> 6;
  if (lane == 0) sm[wv] = make_float2(a, b);
  __syncthreads();
  float2 s0 = sm[0], s1 = sm[1], s2 = sm[2], s3 = sm[3];
  a = s0.x + s1.x + s2.x + s3.x;
  b = s0.y + s1.y + s2.y + s3.y;
}

// ---------------- in-register 16-pt DFT (four-step building block) ----------------
__device__ __constant__ const float TC16[8] = {
  1.f, 0.92387953f, 0.70710678f, 0.38268343f, 0.f, -0.38268343f, -0.70710678f, -0.92387953f};
__device__ __constant__ const float TS16[8] = {
  0.f, -0.38268343f, -0.70710678f, -0.92387953f, -1.f, -0.92387953f, -0.70710678f, -0.38268343f};
__device__ __constant__ const int REV4[16] = {0,8,4,12,2,10,6,14,1,9,5,13,3,11,7,15};

// DIF: natural input -> output reg r holds X[rev4(r)]
template<int INV>
__device__ __forceinline__ void dif16(float2 v[16]) {
  #pragma unroll
  for (int ls = 0; ls < 4; ++ls) {
    const int len = 16 >> ls, half = len >> 1, step = 1 << ls;
    #pragma unroll
    for (int i = 0; i < 16; i += len) {
      #pragma unroll
      for (int j = 0; j < half; ++j) {
        float2 a = v[i + j], b = v[i + j + half];
        v[i + j] = caddf(a, b);
        float2 d = csubf(a, b);
        float cr = TC16[j * step];
        float ci = INV ? -TS16[j * step] : TS16[j * step];
        v[i + j + half] = make_float2(d.x * cr - d.y * ci, d.x * ci + d.y * cr);
      }
    }
  }
}

// DIT: input reg r holds in[rev4(r)] -> natural-order output
template<int INV>
__device__ __forceinline__ void dit16(float2 v[16]) {
  #pragma unroll
  for (int ls = 0; ls < 4; ++ls) {
    const int len = 2 << ls, half = len >> 1, step = 16 / len;
    #pragma unroll
    for (int i = 0; i < 16; i += len) {
      #pragma unroll
      for (int j = 0; j < half; ++j) {
        float cr = TC16[j * step];
        float ci = INV ? -TS16[j * step] : TS16[j * step];
        float2 b = v[i + j + half];
        float2 tt = make_float2(b.x * cr - b.y * ci, b.x * ci + b.y * cr);
        float2 a = v[i + j];
        v[i + j] = caddf(a, tt);
        v[i + j + half] = csubf(a, tt);
      }
    }
  }
}

// ---------------- prep kernels ----------------
__global__ void k_twiddle(float2* __restrict__ twf) {
  int t = threadIdx.x;
  float ang = -6.28318530717958647692f * (float)t / 256.f;
  float s, c; sincosf(ang, &s, &c);
  twf[t] = make_float2(c, s);
}

// csm fp32 r/i planes -> packed bf16x2
__global__ void k_csm_pack(const float* __restrict__ cr, const float* __restrict__ ci,
                           unsigned* __restrict__ o, int n) {
  int t = blockIdx.x * 256 + threadIdx.x;
  if (t < n) o[t] = ((unsigned)f2bf(ci[t]) << 16) | (unsigned)f2bf(cr[t]);
}

// w [OC][IC][3][3] -> wT [IC*9][OC]  (fp32, for layer 1)
__global__ void k_transpose_w(const float* __restrict__ w, float* __restrict__ wT,
                              int IC, int OC) {
  int i = blockIdx.x * 256 + threadIdx.x;
  int total = IC * 9 * OC;
  if (i >= total) return;
  int oc = i % OC;
  int rest = i / OC;
  int ic = rest / 9, k = rest - ic * 9;
  wT[i] = w[(oc * IC + ic) * 9 + k];
}

// w [64][64][3][3] fp32 -> B-fragment order bf16: [ks=18][ocg=4][lane=64][j=8]
__global__ void k_bfrag(const float* __restrict__ w, unsigned short* __restrict__ bf) {
  int i = blockIdx.x * 256 + threadIdx.x;
  if (i >= 36864) return;
  int j = i & 7, lane = (i >> 3) & 63, ocg = (i >> 9) & 3, ks = i >> 11;
  int oc = (ocg << 4) + (lane & 15);
  int ic = ((ks & 1) << 5) + (((lane >> 4) & 3) << 3) + j;
  int tap = ks >> 1;
  bf[i] = f2bf(w[(oc * 64 + ic) * 9 + tap]);
}

// w5 [2][64][3][3] -> B-fragment bf16 [ks=18][lane=64][j=8], oc padded 2->16
__global__ void k_bfrag5(const float* __restrict__ w, unsigned short* __restrict__ bf) {
  int i = blockIdx.x * 256 + threadIdx.x;
  if (i >= 9216) return;
  int j = i & 7, lane = (i >> 3) & 63, ks = i >> 9;
  int oc = lane & 15;
  int ic = ((ks & 1) << 5) + (((lane >> 4) & 3) << 3) + j;
  int tap = ks >> 1;
  bf[i] = (oc < 2) ? f2bf(w[(oc * 64 + ic) * 9 + tap]) : (unsigned short)0;
}

// ---------------- layer 1: fp32 direct conv (IC=2), out pixel-major bf16 ----------------
__global__ __launch_bounds__(256) void k_conv1(
    const float* __restrict__ atb,   // [8][2][256][256]
    const float* __restrict__ w1T,   // [18][64]
    const float* __restrict__ b1,
    unsigned short* __restrict__ out)// [8][256][256][64] bf16
{
  __shared__ float patch[2 * 324];
  const int t = threadIdx.x;
  const int img = blockIdx.z;
  const float* in = atb + (size_t)img * 131072;
  const int tx0 = blockIdx.x << 4, ty0 = blockIdx.y << 4;
  for (int i = t; i < 648; i += 256) {
    int ic = i / 324, rem = i - ic * 324;
    int py = rem / 18, px = rem - py * 18;
    int gy = ty0 + py - 1, gx = tx0 + px - 1;
    float v = 0.f;
    if ((unsigned)gy < 256u && (unsigned)gx < 256u)
      v = in[(ic << 16) + (gy << 8) + gx];
    patch[i] = v;
  }
  __syncthreads();
  const int tx = t & 15, ty = t >> 4;
  float acc[64];
  #pragma unroll
  for (int o = 0; o < 64; ++o) acc[o] = 0.f;
  #pragma unroll
  for (int ic = 0; ic < 2; ++ic) {
    const float* pb = &patch[ic * 324 + ty * 18 + tx];
    #pragma unroll
    for (int k = 0; k < 9; ++k) {
      const float v = pb[(k / 3) * 18 + (k % 3)];
      const float* wr = &w1T[(ic * 9 + k) << 6];
      #pragma unroll
      for (int o = 0; o < 64; ++o) acc[o] = fmaf(v, wr[o], acc[o]);
    }
  }
  size_t obase = ((size_t)img << 22) + ((size_t)(((ty0 + ty) << 8) + tx0 + tx) << 6);
  v8s* outv = (v8s*)(out + obase);
  #pragma unroll
  for (int g = 0; g < 8; ++g) {
    v8s ov;
    #pragma unroll
    for (int j = 0; j < 8; ++j) {
      float v = fmaxf(acc[(g << 3) + j] + b1[(g << 3) + j], 0.f);
      ov[j] = (short)f2bf(v);
    }
    outv[g] = ov;
  }
}

// ---- layers 2-4: bf16 MFMA implicit GEMM, B staged in LDS (16x8 tile, 4 waves) ----
// B table (73.7 KB) split into two ks-halves ping-ponged through one 36.8 KB LDS
// buffer; half-1 prefetched into registers during half-0 compute (issue-early).
__global__ __launch_bounds__(256, 2) void k_conv_mfma(
    const unsigned short* __restrict__ in,
    const unsigned short* __restrict__ bfrag,
    const float* __restrict__ bias,
    unsigned short* __restrict__ out)
{
  __shared__ v8s halo[1440];   // 10x18 px x 8 slots of 8ch, swizzled: 23040 B
  __shared__ v8s bsh[2304];    // 9 ks x 4 ocg x 64 lane: 36864 B
  char* hb = (char*)halo;
  const int t = threadIdx.x;
  const int img = blockIdx.z;
  const int tx0 = blockIdx.x << 4, ty0 = blockIdx.y << 3;   // tile 16x8
  const size_t ibase = ((size_t)img << 22);
  // stage halo: 10x18 px
  for (int c = t; c < 1440; c += 256) {
    int hy = c / 144, rem = c - hy * 144;
    int hx = rem >> 3, slot = rem & 7;
    int gy = ty0 + hy - 1, gx = tx0 + hx - 1;
    v8s v = {0, 0, 0, 0, 0, 0, 0, 0};
    if ((unsigned)gy < 256u && (unsigned)gx < 256u)
      v = *(const v8s*)(in + ibase + ((size_t)((gy << 8) + gx) << 6) + (slot << 3));
    int xl = hy * 18 + hx;
    *(v8s*)(hb + xl * 128 + ((slot ^ (xl & 7)) << 4)) = v;
  }
  // stage B half 0 (ks 0..8) and prefetch half 1 into registers
  const v8s* bg = (const v8s*)bfrag;
  v8s breg[9];
  #pragma unroll
  for (int i = 0; i < 9; ++i) breg[i] = bg[t + (i << 8)];
  #pragma unroll
  for (int i = 0; i < 9; ++i) bsh[t + (i << 8)] = breg[i];
  #pragma unroll
  for (int i = 0; i < 9; ++i) breg[i] = bg[2304 + t + (i << 8)];
  __syncthreads();

  const int lane = t & 63, w = t >> 6;
  const int px = lane & 15, lg = lane >> 4;
  v4f acc[2][4];
  #pragma unroll
  for (int pf = 0; pf < 2; ++pf)
    #pragma unroll
    for (int og = 0; og < 4; ++og)
      #pragma unroll
      for (int rg = 0; rg < 4; ++rg) acc[pf][og][rg] = 0.f;

  #pragma unroll
  for (int half = 0; half < 2; ++half) {
    #pragma unroll
    for (int k9 = 0; k9 < 9; ++k9) {
      const int ks = half * 9 + k9;
      const int tap = ks >> 1;
      const int dy = tap / 3, dx = tap - dy * 3;
      const int slot = ((ks & 1) << 2) | lg;
      v8s b0 = bsh[((k9 << 2) | 0) * 64 + lane];
      v8s b1 = bsh[((k9 << 2) | 1) * 64 + lane];
      v8s b2 = bsh[((k9 << 2) | 2) * 64 + lane];
      v8s b3 = bsh[((k9 << 2) | 3) * 64 + lane];
      #pragma unroll
      for (int pf = 0; pf < 2; ++pf) {
        int xl = (w * 2 + pf + dy) * 18 + px + dx;
        v8s a = *(const v8s*)(hb + xl * 128 + ((slot ^ (xl & 7)) << 4));
        acc[pf][0] = __builtin_amdgcn_mfma_f32_16x16x32_bf16(a, b0, acc[pf][0], 0, 0, 0);
        acc[pf][1] = __builtin_amdgcn_mfma_f32_16x16x32_bf16(a, b1, acc[pf][1], 0, 0, 0);
        acc[pf][2] = __builtin_amdgcn_mfma_f32_16x16x32_bf16(a, b2, acc[pf][2], 0, 0, 0);
        acc[pf][3] = __builtin_amdgcn_mfma_f32_16x16x32_bf16(a, b3, acc[pf][3], 0, 0, 0);
      }
    }
    if (half == 0) {
      __syncthreads();               // everyone done reading half 0
      #pragma unroll
      for (int i = 0; i < 9; ++i) bsh[t + (i << 8)] = breg[i];
      __syncthreads();               // half 1 visible
    }
  }
  // C layout: col(lane&15)=oc, row=(lane>>4)*4+reg = pixel-x
  const int ocl = lane & 15;
  float bv[4];
  #pragma unroll
  for (int og = 0; og < 4; ++og) bv[og] = bias[(og << 4) + ocl];
  #pragma unroll
  for (int pf = 0; pf < 2; ++pf) {
    const int gy = ty0 + w * 2 + pf;
    #pragma unroll
    for (int og = 0; og < 4; ++og) {
      const int oc = (og << 4) + ocl;
      #pragma unroll
      for (int rg = 0; rg < 4; ++rg) {
        float v = fmaxf(acc[pf][og][rg] + bv[og], 0.f);
        int gx = tx0 + (lg << 2) + rg;
        out[ibase + ((size_t)((gy << 8) + gx) << 6) + oc] = f2bf(v);
      }
    }
  }
}

// ---------------- layer 5 (64->2, MFMA) + rhs = atb + lam*(atb + conv5) ----------------
__global__ __launch_bounds__(512, 4) void k_conv5_rhs(
    const unsigned short* __restrict__ in,
    const unsigned short* __restrict__ bf5,
    const float* __restrict__ b5,
    const float* __restrict__ atb,
    const float* __restrict__ lam,
    float2* __restrict__ rhs)
{
  __shared__ v8s halo[2592];
  char* hb = (char*)halo;
  const int t = threadIdx.x;
  const int img = blockIdx.z;
  const int tx0 = blockIdx.x << 4, ty0 = blockIdx.y << 4;
  const size_t ibase = ((size_t)img << 22);
  for (int c = t; c < 2592; c += 512) {
    int hy = c / 144, rem = c - hy * 144;
    int hx = rem >> 3, slot = rem & 7;
    int gy = ty0 + hy - 1, gx = tx0 + hx - 1;
    v8s v = {0, 0, 0, 0, 0, 0, 0, 0};
    if ((unsigned)gy < 256u && (unsigned)gx < 256u)
      v = *(const v8s*)(in + ibase + ((size_t)((gy << 8) + gx) << 6) + (slot << 3));
    int xl = hy * 18 + hx;
    *(v8s*)(hb + xl * 128 + ((slot ^ (xl & 7)) << 4)) = v;
  }
  __syncthreads();
  const int lane = t & 63, w = t >> 6;
  const int px = lane & 15, lg = lane >> 4;
  v4f acc[2];
  #pragma unroll
  for (int pf = 0; pf < 2; ++pf)
    #pragma unroll
    for (int rg = 0; rg < 4; ++rg) acc[pf][rg] = 0.f;
  #pragma unroll
  for (int ks = 0; ks < 18; ++ks) {
    const int tap = ks >> 1;
    const int dy = tap / 3, dx = tap - dy * 3;
    const int slot = ((ks & 1) << 2) | lg;
    v8s b = *(const v8s*)(bf5 + (((ks * 64) + lane) << 3));
    #pragma unroll
    for (int pf = 0; pf < 2; ++pf) {
      int xl = (w * 2 + pf + dy) * 18 + px + dx;
      v8s a = *(const v8s*)(hb + xl * 128 + ((slot ^ (xl & 7)) << 4));
      acc[pf] = __builtin_amdgcn_mfma_f32_16x16x32_bf16(a, b, acc[pf], 0, 0, 0);
    }
  }
  const int ocl = lane & 15;
  const float l = *lam;
  const float bsel = b5[ocl & 1];
  #pragma unroll
  for (int pf = 0; pf < 2; ++pf) {
    const int gy = ty0 + w * 2 + pf;
    #pragma unroll
    for (int rg = 0; rg < 4; ++rg) {
      float v = acc[pf][rg] + bsel;
      float d1 = __shfl_down(v, 1);
      if (ocl == 0) {
        int gx = tx0 + (lg << 2) + rg;
        int pix = (gy << 8) + gx;
        float x0 = atb[(size_t)img * 131072 + pix];
        float x1 = atb[(size_t)img * 131072 + 65536 + pix];
        rhs[(size_t)img * 65536 + pix] =
            make_float2(fmaf(l, x0 + v, x0), fmaf(l, x1 + d1, x1));
      }
    }
  }
}

// ---- AtA pass 1: (fused p-update) coil = csm*p (bf16 out), row FFT, part_p ----
__global__ __launch_bounds__(256) void k_coil_fft_rows(
    const float2* __restrict__ p_prev, const float2* __restrict__ r,
    float2* __restrict__ p_out,
    const float* __restrict__ part_r_old, const float* __restrict__ part_r_new,
    const int first,
    const unsigned* __restrict__ csmh, const float2* __restrict__ twf,
    unsigned* __restrict__ coil, float* __restrict__ part_p)
{
  __shared__ float2 trans[4096];
  __shared__ float2 sm2[4];
  __shared__ float sm1[4];
  const int t = threadIdx.x;
  const int bc = blockIdx.x, b = bc / NCOIL, c = bc - b * NCOIL;
  const int idx = t & 15, row16 = t >> 4;
  const int row = (blockIdx.y << 4) + row16;

  float beta = 0.f; bool do_upd = false;
  if (!first) {
    float so = 0.f, sn = 0.f;
    for (int i = t; i < 1024; i += 256) { so += part_r_old[i]; sn += part_r_new[i]; }
    blockRed2(so, sn, sm2);
    do_upd = so > 1e-10f;
    beta = do_upd ? sn / so : 0.f;
  }

  const int pb = (b << 16) + (row << 8);
  const int gb = (bc << 16) + (row << 8);
  float2 v[16];
  float pe = 0.f;
  #pragma unroll
  for (int h2 = 0; h2 < 16; ++h2) {
    int n = idx + (h2 << 4);
    float2 pv = p_prev[pb + n];
    if (!first && do_upd) {
      float2 rv = r[pb + n];
      pv = make_float2(fmaf(beta, pv.x, rv.x), fmaf(beta, pv.y, rv.y));
    }
    if (c == 0) {
      if (!first) p_out[pb + n] = pv;
      pe = fmaf(pv.x, pv.x, fmaf(pv.y, pv.y, pe));
    }
    float2 cs = unpack_bf(csmh[gb + n]);
    v[h2] = make_float2(cs.x * pv.x - cs.y * pv.y, cs.x * pv.y + cs.y * pv.x);
  }
  if (c == 0) {
    float tot = blockRed256(pe, sm1);
    if (t == 0) part_p[(b << 4) + blockIdx.y] = tot;
  }
  // forward four-step along W
  dif16<0>(v);
  #pragma unroll
  for (int rr = 0; rr < 16; ++rr) {
    int k1 = REV4[rr];
    v[rr] = cmulf(v[rr], twf[idx * k1]);
    trans[(k1 << 8) + (row16 << 4) + (idx ^ k1)] = v[rr];
  }
  __syncthreads();
  #pragma unroll
  for (int h1 = 0; h1 < 16; ++h1)
    v[h1] = trans[(idx << 8) + (row16 << 4) + (h1 ^ idx)];
  dif16<0>(v);
  #pragma unroll
  for (int rr = 0; rr < 16; ++rr)
    coil[gb + idx + (REV4[rr] << 4)] = pack_bf(v[rr]);
}

// ---- AtA pass 2: col FFT + mask (+part_m) + col IFFT, bf16 coil in/out ----
__global__ __launch_bounds__(256) void k_fft_cols_mask(
    unsigned* __restrict__ coil, const float* __restrict__ mask,
    const float2* __restrict__ twf, float* __restrict__ part_m)
{
  __shared__ float2 trans[4096];
  __shared__ float smR[4];
  const int t = threadIdx.x;
  const int bc = blockIdx.x, b = bc / NCOIL;
  const int w0 = blockIdx.y << 4;
  const int col = t & 15, idx = t >> 4;
  const int base = (bc << 16) + w0 + col;
  float2 v[16];
  #pragma unroll
  for (int h2 = 0; h2 < 16; ++h2)
    v[h2] = unpack_bf(coil[base + ((idx + (h2 << 4)) << 8)]);
  // ---- forward ----
  dif16<0>(v);
  #pragma unroll
  for (int r = 0; r < 16; ++r) {
    int k1 = REV4[r];
    v[r] = cmulf(v[r], twf[idx * k1]);
    trans[(idx << 8) + (k1 << 4) + col] = v[r];
  }
  __syncthreads();
  #pragma unroll
  for (int h1 = 0; h1 < 16; ++h1)
    v[h1] = trans[(h1 << 8) + (idx << 4) + col];
  __syncthreads();
  dif16<0>(v);
  // ---- mask in registers + k-space energy partial (denominator) ----
  float pm = 0.f;
  #pragma unroll
  for (int r = 0; r < 16; ++r) {
    float mv = mask[(b << 16) + ((idx + (REV4[r] << 4)) << 8) + w0 + col];
    v[r].x *= mv; v[r].y *= mv;
    pm = fmaf(v[r].x, v[r].x, fmaf(v[r].y, v[r].y, pm));
  }
  float tot = blockRed256(pm, smR);   // internal barrier also guards trans reuse
  if (t == 0) part_m[(bc << 4) + blockIdx.y] = tot;
  // ---- inverse ----
  dit16<1>(v);
  #pragma unroll
  for (int r = 0; r < 16; ++r) {
    float2 w = twf[idx * r];
    v[r] = make_float2(v[r].x * w.x + v[r].y * w.y, v[r].y * w.x - v[r].x * w.y);
    trans[(idx << 8) + (r << 4) + col] = v[r];
  }
  __syncthreads();
  #pragma unroll
  for (int k1 = 0; k1 < 16; ++k1)
    v[k1] = trans[(k1 << 8) + (idx << 4) + col];
  dif16<1>(v);
  const float sc = 1.f / 256.f;
  #pragma unroll
  for (int r = 0; r < 16; ++r)
    coil[base + ((idx + (REV4[r] << 4)) << 8)] =
        pack_bf(make_float2(v[r].x * sc, v[r].y * sc));
}

// ---- AtA pass 3: row IFFT + conj(csm) partial sum over 3 coils -> fp32 partials ----
__global__ __launch_bounds__(256) void k_ifft_rows_acc(
    const unsigned* __restrict__ coil, const unsigned* __restrict__ csmh,
    const float2* __restrict__ twf, float2* __restrict__ partbuf)
{
  __shared__ float2 trans[4096];
  const int t = threadIdx.x;
  const int b = blockIdx.x, cs = blockIdx.z;
  const int idx = t & 15, row16 = t >> 4;
  const int row = (blockIdx.y << 4) + row16;
  float2 acc[16];
  #pragma unroll
  for (int rr = 0; rr < 16; ++rr) acc[rr] = make_float2(0.f, 0.f);
  for (int j = 0; j < 3; ++j) {
    const int c = cs * 3 + j;
    const int gb = ((b * NCOIL + c) << 16) + (row << 8);
    float2 v[16];
    #pragma unroll
    for (int rr = 0; rr < 16; ++rr)
      v[rr] = unpack_bf(coil[gb + idx + (REV4[rr] << 4)]);
    dit16<1>(v);
    if (j) __syncthreads();
    #pragma unroll
    for (int rr = 0; rr < 16; ++rr) {
      float2 w = twf[idx * rr];
      float2 z = v[rr];
      trans[(rr << 8) + (row16 << 4) + (idx ^ rr)] =
          make_float2(z.x * w.x + z.y * w.y, z.y * w.x - z.x * w.y);
    }
    __syncthreads();
    #pragma unroll
    for (int k1 = 0; k1 < 16; ++k1)
      v[k1] = trans[(idx << 8) + (row16 << 4) + (k1 ^ idx)];
    dif16<1>(v);
    #pragma unroll
    for (int rr = 0; rr < 16; ++rr) {
      int gi = gb + idx + (REV4[rr] << 4);
      float2 cw = unpack_bf(csmh[gi]);
      float2 z = v[rr];
      acc[rr].x += cw.x * z.x + cw.y * z.y;
      acc[rr].y += cw.x * z.y - cw.y * z.x;
    }
  }
  const int ob = (((cs << 3) + b) << 16) + (row << 8);
  #pragma unroll
  for (int rr = 0; rr < 16; ++rr)
    partbuf[ob + idx + (REV4[rr] << 4)] = acc[rr];
}

// ---- update1: alpha from energy-denominator, Ap inline, x,r update, part_r ----
__global__ __launch_bounds__(256) void k_update1(
    float2* __restrict__ x, float2* __restrict__ r, const float2* __restrict__ p,
    const float2* __restrict__ partbuf,
    const float* __restrict__ part_m, const float* __restrict__ part_p,
    const float* __restrict__ part_r_old, float* __restrict__ part_r_new,
    const float* __restrict__ lam)
{
  __shared__ float2 sm2[4];
  __shared__ float smA[4];
  __shared__ float smB[4];
  const int t = threadIdx.x;
  float se = 0.f, sp = 0.f, sr = 0.f;
  for (int i = t; i < 1536; i += 256) se += part_m[i];
  if (t < 128) sp = part_p[t];
  for (int i = t; i < 1024; i += 256) sr += part_r_old[i];
  blockRed2(se, sp, sm2);
  sr = blockRed256(sr, smA);
  const float l = *lam;
  const float denom = se * (1.f / 65536.f) + l * sp;
  const bool cont = sr > 1e-10f;
  const float alpha = cont ? sr / denom : 0.f;  // alpha=0 => x,r,rTr frozen exactly
  const float inv2 = 1.f / 256.f;
  float s = 0.f;
  #pragma unroll
  for (int e = 0; e < 2; ++e) {
    int pix = blockIdx.x * 512 + t + (e << 8);
    int b = pix >> 16, off = pix & 65535;
    float2 s0 = partbuf[(b << 16) + off];
    float2 s1 = partbuf[((8 + b) << 16) + off];
    float2 s2 = partbuf[((16 + b) << 16) + off];
    float2 s3 = partbuf[((24 + b) << 16) + off];
    float sx = (s0.x + s1.x) + (s2.x + s3.x);
    float sy = (s0.y + s1.y) + (s2.y + s3.y);
    float2 pv = p[pix], xv = x[pix], rv = r[pix];
    float2 apv = make_float2(fmaf(l, pv.x, sx * inv2), fmaf(l, pv.y, sy * inv2));
    xv.x = fmaf(alpha, pv.x, xv.x); xv.y = fmaf(alpha, pv.y, xv.y);
    rv.x = fmaf(-alpha, apv.x, rv.x); rv.y = fmaf(-alpha, apv.y, rv.y);
    x[pix] = xv; r[pix] = rv;
    s = fmaf(rv.x, rv.x, fmaf(rv.y, rv.y, s));
  }
  float tot = blockRed256(s, smB);
  if (t == 0) part_r_new[blockIdx.x] = tot;
}

// ---------------- CG init / final ----------------
__global__ __launch_bounds__(256) void k_cg_init(
    const float2* __restrict__ rhs, float2* __restrict__ x,
    float2* __restrict__ r, float2* __restrict__ p, float* __restrict__ part)
{
  __shared__ float sm[4];
  const int t = threadIdx.x;
  const int base = blockIdx.x * 512;
  float s = 0.f;
  #pragma unroll
  for (int e = 0; e < 2; ++e) {
    int idx = base + t + (e << 8);
    float2 v = rhs[idx];
    x[idx] = make_float2(0.f, 0.f);
    r[idx] = v; p[idx] = v;
    s = fmaf(v.x, v.x, fmaf(v.y, v.y, s));
  }
  float tot = blockRed256(s, sm);
  if (t == 0) part[blockIdx.x] = tot;
}

__global__ __launch_bounds__(256) void k_final(const float2* __restrict__ x,
                                               float* __restrict__ out) {
  const int t = threadIdx.x;
  const int base = blockIdx.x * 512;
  #pragma unroll
  for (int e = 0; e < 2; ++e) {
    int idx = base + t + (e << 8);
    int b = idx >> 16, pix = idx & 65535;
    float2 v = x[idx];
    out[(b << 17) + pix] = v.x;
    out[(b << 17) + 65536 + pix] = v.y;
  }
}

// ---------------- driver ----------------
extern "C" void kernel_launch(void* const* d_in, const int* in_sizes, int n_in,
                              void* d_out, int out_size, void* d_ws, size_t ws_size,
                              hipStream_t stream) {
  (void)in_sizes; (void)n_in; (void)out_size; (void)ws_size;
  const float* atb   = (const float*)d_in[0];
  const float* csm_r = (const float*)d_in[1];
  const float* csm_i = (const float*)d_in[2];
  const float* mask  = (const float*)d_in[3];
  const float* w1 = (const float*)d_in[4];  const float* b1 = (const float*)d_in[5];
  const float* w2 = (const float*)d_in[6];  const float* b2 = (const float*)d_in[7];
  const float* w3 = (const float*)d_in[8];  const float* b3 = (const float*)d_in[9];
  const float* w4 = (const float*)d_in[10]; const float* b4 = (const float*)d_in[11];
  const float* w5 = (const float*)d_in[12]; const float* b5 = (const float*)d_in[13];
  const float* lam = (const float*)d_in[14];

  char* ws = (char*)d_ws;   // ws_size observed = 256 MiB; we use ~218.4 MB
  unsigned short* actA = (unsigned short*)ws;                  // 64 MiB
  unsigned short* actB = (unsigned short*)(ws + 67108864);     // 64 MiB
  unsigned* coil   = (unsigned*)(ws + 134217728);              // 25165824 B (bf16x2)
  float2* partbuf  = (float2*)(ws + 159383552);                // 16777216 B
  float2* x        = (float2*)(ws + 176160768);                // 4 MiB
  float2* r        = (float2*)(ws + 180355072);
  float2* pbuf0    = (float2*)(ws + 184549376);
  float2* rhs      = (float2*)(ws + 188743680);                // doubles as pbuf1
  float2* pbuf1    = rhs;
  unsigned* csmh   = (unsigned*)(ws + 192937984);              // 25165824 B
  float*  w1T      = (float*)(ws + 218103808);                 // 4608 B
  unsigned short* bf2 = (unsigned short*)(ws + 218108416);     // 73728 B each
  unsigned short* bf3 = (unsigned short*)(ws + 218182144);
  unsigned short* bf4 = (unsigned short*)(ws + 218255872);
  unsigned short* bf5 = (unsigned short*)(ws + 218329600);     // 18432 B
  float2* twf      = (float2*)(ws + 218348032);                // 2048 B
  float*  part_r   = (float*)(ws + 218350080);                 // 12*1024*4
  float*  part_m   = (float*)(ws + 218399232);                 // 1536*4
  float*  part_p   = (float*)(ws + 218405376);                 // 128*4

  // prep
  k_twiddle<<<1, 256, 0, stream>>>(twf);
  k_transpose_w<<<5, 256, 0, stream>>>(w1, w1T, 2, 64);
  k_bfrag<<<144, 256, 0, stream>>>(w2, bf2);
  k_bfrag<<<144, 256, 0, stream>>>(w3, bf3);
  k_bfrag<<<144, 256, 0, stream>>>(w4, bf4);
  k_bfrag5<<<36, 256, 0, stream>>>(w5, bf5);
  k_csm_pack<<<24576, 256, 0, stream>>>(csm_r, csm_i, csmh, 6291456);

  // CNN: full batch, z = 8
  k_conv1<<<dim3(16, 16, 8), 256, 0, stream>>>(atb, w1T, b1, actA);
  k_conv_mfma<<<dim3(16, 32, 8), 256, 0, stream>>>(actA, bf2, b2, actB);
  k_conv_mfma<<<dim3(16, 32, 8), 256, 0, stream>>>(actB, bf3, b3, actA);
  k_conv_mfma<<<dim3(16, 32, 8), 256, 0, stream>>>(actA, bf4, b4, actB);
  k_conv5_rhs<<<dim3(16, 16, 8), 512, 0, stream>>>(actB, bf5, b5, atb, lam, rhs);

  // CG
  k_cg_init<<<1024, 256, 0, stream>>>(rhs, x, r, pbuf0, part_r);
  for (int it = 0; it < 11; ++it) {
    float2* p_cur = (it % 2 == 0) ? pbuf0 : pbuf1;
    float2* p_prv = (it == 0) ? pbuf0 : ((it % 2 == 0) ? pbuf1 : pbuf0);
    const float* pro = part_r + (it > 0 ? (it - 1) : 0) * 1024;
    const float* prn = part_r + it * 1024;
    k_coil_fft_rows<<<dim3(96, 16), 256, 0, stream>>>(
        p_prv, r, p_cur, pro, prn, it == 0 ? 1 : 0, csmh, twf, coil, part_p);
    k_fft_cols_mask<<<dim3(96, 16), 256, 0, stream>>>(coil, mask, twf, part_m);
    k_ifft_rows_acc<<<dim3(8, 16, 4), 256, 0, stream>>>(coil, csmh, twf, partbuf);
    k_update1<<<1024, 256, 0, stream>>>(x, r, p_cur, partbuf, part_m, part_p,
                                        part_r + it * 1024, part_r + (it + 1) * 1024, lam);
  }

  k_final<<<1024, 256, 0, stream>>>(x, (float*)d_out);
}

// Round 8
// 1082.315 us; speedup vs baseline: 6.6127x; 1.0069x over previous
//
#include <hip/hip_runtime.h>
#include <hip/hip_bf16.h>
#include <math.h>

static constexpr int NCOIL = 12;
static constexpr int HWSZ  = 65536;   // 256*256

typedef short v8s __attribute__((ext_vector_type(8)));
typedef float v4f __attribute__((ext_vector_type(4)));

__device__ __forceinline__ unsigned short f2bf(float v) {
  __hip_bfloat16 h = __float2bfloat16(v);
  union { __hip_bfloat16 h; unsigned short u; } cv; cv.h = h; return cv.u;
}
__device__ __forceinline__ float bf2f(unsigned short u) {
  return __uint_as_float(((unsigned)u) << 16);
}
__device__ __forceinline__ unsigned pack_bf(float2 v) {
  return ((unsigned)f2bf(v.y) << 16) | (unsigned)f2bf(v.x);
}
__device__ __forceinline__ float2 unpack_bf(unsigned u) {
  return make_float2(bf2f((unsigned short)(u & 0xffffu)),
                     bf2f((unsigned short)(u >> 16)));
}

// ---------------- complex helpers ----------------
__device__ __forceinline__ float2 cmulf(float2 a, float2 b) {
  return make_float2(a.x * b.x - a.y * b.y, a.x * b.y + a.y * b.x);
}
__device__ __forceinline__ float2 caddf(float2 a, float2 b) {
  return make_float2(a.x + b.x, a.y + b.y);
}
__device__ __forceinline__ float2 csubf(float2 a, float2 b) {
  return make_float2(a.x - b.x, a.y - b.y);
}

// ---------------- block reductions ----------------
__device__ __forceinline__ float blockRed256(float v, float* sm) {
  #pragma unroll
  for (int off = 32; off; off >>= 1) v += __shfl_down(v, off);
  int lane = threadIdx.x & 63, wv = threadIdx.x >> 6;
  if (lane == 0) sm[wv] = v;
  __syncthreads();
  return sm[0] + sm[1] + sm[2] + sm[3];
}

__device__ __forceinline__ void blockRed2(float& a, float& b, float2* sm) {
  #pragma unroll
  for (int off = 32; off; off >>= 1) {
    a += __shfl_down(a, off);
    b += __shfl_down(b, off);
  }
  int lane = threadIdx.x & 63, wv = threadIdx.x >> 6;
  if (lane == 0) sm[wv] = make_float2(a, b);
  __syncthreads();
  float2 s0 = sm[0], s1 = sm[1], s2 = sm[2], s3 = sm[3];
  a = s0.x + s1.x + s2.x + s3.x;
  b = s0.y + s1.y + s2.y + s3.y;
}

// ---------------- in-register 16-pt DFT (four-step building block) ----------------
__device__ __constant__ const float TC16[8] = {
  1.f, 0.92387953f, 0.70710678f, 0.38268343f, 0.f, -0.38268343f, -0.70710678f, -0.92387953f};
__device__ __constant__ const float TS16[8] = {
  0.f, -0.38268343f, -0.70710678f, -0.92387953f, -1.f, -0.92387953f, -0.70710678f, -0.38268343f};
__device__ __constant__ const int REV4[16] = {0,8,4,12,2,10,6,14,1,9,5,13,3,11,7,15};

// DIF: natural input -> output reg r holds X[rev4(r)]
template<int INV>
__device__ __forceinline__ void dif16(float2 v[16]) {
  #pragma unroll
  for (int ls = 0; ls < 4; ++ls) {
    const int len = 16 >> ls, half = len >> 1, step = 1 << ls;
    #pragma unroll
    for (int i = 0; i < 16; i += len) {
      #pragma unroll
      for (int j = 0; j < half; ++j) {
        float2 a = v[i + j], b = v[i + j + half];
        v[i + j] = caddf(a, b);
        float2 d = csubf(a, b);
        float cr = TC16[j * step];
        float ci = INV ? -TS16[j * step] : TS16[j * step];
        v[i + j + half] = make_float2(d.x * cr - d.y * ci, d.x * ci + d.y * cr);
      }
    }
  }
}

// DIT: input reg r holds in[rev4(r)] -> natural-order output
template<int INV>
__device__ __forceinline__ void dit16(float2 v[16]) {
  #pragma unroll
  for (int ls = 0; ls < 4; ++ls) {
    const int len = 2 << ls, half = len >> 1, step = 16 / len;
    #pragma unroll
    for (int i = 0; i < 16; i += len) {
      #pragma unroll
      for (int j = 0; j < half; ++j) {
        float cr = TC16[j * step];
        float ci = INV ? -TS16[j * step] : TS16[j * step];
        float2 b = v[i + j + half];
        float2 tt = make_float2(b.x * cr - b.y * ci, b.x * ci + b.y * cr);
        float2 a = v[i + j];
        v[i + j] = caddf(a, tt);
        v[i + j + half] = csubf(a, tt);
      }
    }
  }
}

// ---------------- merged prep kernel ----------------
// blocks [0,24576): csm pack; +432: bfrag w2/w3/w4; +36: bfrag5; +5: w1T; +1: twiddle
__global__ __launch_bounds__(256) void k_prep(
    const float* __restrict__ w1, const float* __restrict__ w2,
    const float* __restrict__ w3, const float* __restrict__ w4,
    const float* __restrict__ w5, const float* __restrict__ csm_r,
    const float* __restrict__ csm_i,
    float* __restrict__ w1T, unsigned short* __restrict__ bf2,
    unsigned short* __restrict__ bf3, unsigned short* __restrict__ bf4,
    unsigned short* __restrict__ bf5, unsigned* __restrict__ csmh,
    float2* __restrict__ twf)
{
  const int bx = blockIdx.x;
  const int t = threadIdx.x;
  if (bx < 24576) {
    int i = bx * 256 + t;
    csmh[i] = ((unsigned)f2bf(csm_i[i]) << 16) | (unsigned)f2bf(csm_r[i]);
    return;
  }
  int r = bx - 24576;
  if (r < 432) {
    const float* w = (r < 144) ? w2 : (r < 288) ? w3 : w4;
    unsigned short* bf = (r < 144) ? bf2 : (r < 288) ? bf3 : bf4;
    int i = (r % 144) * 256 + t;
    int j = i & 7, lane = (i >> 3) & 63, ocg = (i >> 9) & 3, ks = i >> 11;
    int oc = (ocg << 4) + (lane & 15);
    int ic = ((ks & 1) << 5) + (((lane >> 4) & 3) << 3) + j;
    bf[i] = f2bf(w[(oc * 64 + ic) * 9 + (ks >> 1)]);
    return;
  }
  r -= 432;
  if (r < 36) {
    int i = r * 256 + t;
    int j = i & 7, lane = (i >> 3) & 63, ks = i >> 9;
    int oc = lane & 15;
    int ic = ((ks & 1) << 5) + (((lane >> 4) & 3) << 3) + j;
    bf5[i] = (oc < 2) ? f2bf(w5[(oc * 64 + ic) * 9 + (ks >> 1)]) : (unsigned short)0;
    return;
  }
  r -= 36;
  if (r < 5) {
    int i = r * 256 + t;
    if (i < 1152) {
      int oc = i & 63;
      int rest = i >> 6;            // ic*9+k
      int ic = rest / 9, k = rest - ic * 9;
      w1T[i] = w1[(oc * 2 + ic) * 9 + k];
    }
    return;
  }
  float ang = -6.28318530717958647692f * (float)t / 256.f;
  float s, c; sincosf(ang, &s, &c);
  twf[t] = make_float2(c, s);
}

// ---------------- layer 1: fp32 direct conv (IC=2), out pixel-major bf16 ----------------
__global__ __launch_bounds__(256) void k_conv1(
    const float* __restrict__ atb,   // [8][2][256][256]
    const float* __restrict__ w1T,   // [18][64]
    const float* __restrict__ b1,
    unsigned short* __restrict__ out)// [8][256][256][64] bf16
{
  __shared__ float patch[2 * 324];
  const int t = threadIdx.x;
  const int img = blockIdx.z;
  const float* in = atb + (size_t)img * 131072;
  const int tx0 = blockIdx.x << 4, ty0 = blockIdx.y << 4;
  for (int i = t; i < 648; i += 256) {
    int ic = i / 324, rem = i - ic * 324;
    int py = rem / 18, px = rem - py * 18;
    int gy = ty0 + py - 1, gx = tx0 + px - 1;
    float v = 0.f;
    if ((unsigned)gy < 256u && (unsigned)gx < 256u)
      v = in[(ic << 16) + (gy << 8) + gx];
    patch[i] = v;
  }
  __syncthreads();
  const int tx = t & 15, ty = t >> 4;
  float acc[64];
  #pragma unroll
  for (int o = 0; o < 64; ++o) acc[o] = 0.f;
  #pragma unroll
  for (int ic = 0; ic < 2; ++ic) {
    const float* pb = &patch[ic * 324 + ty * 18 + tx];
    #pragma unroll
    for (int k = 0; k < 9; ++k) {
      const float v = pb[(k / 3) * 18 + (k % 3)];
      const float* wr = &w1T[(ic * 9 + k) << 6];
      #pragma unroll
      for (int o = 0; o < 64; ++o) acc[o] = fmaf(v, wr[o], acc[o]);
    }
  }
  size_t obase = ((size_t)img << 22) + ((size_t)(((ty0 + ty) << 8) + tx0 + tx) << 6);
  v8s* outv = (v8s*)(out + obase);
  #pragma unroll
  for (int g = 0; g < 8; ++g) {
    v8s ov;
    #pragma unroll
    for (int j = 0; j < 8; ++j) {
      float v = fmaxf(acc[(g << 3) + j] + b1[(g << 3) + j], 0.f);
      ov[j] = (short)f2bf(v);
    }
    outv[g] = ov;
  }
}

// ---- layers 2-4: bf16 MFMA implicit GEMM, 16x16 tile, 4 waves x (4 rows x 64 oc) ----
// Per ks: 4 A-reads + 4 B-reads -> 16 MFMA (ratio 2.0). B LDS ping-pong as before.
__global__ __launch_bounds__(256, 2) void k_conv_mfma(
    const unsigned short* __restrict__ in,
    const unsigned short* __restrict__ bfrag,
    const float* __restrict__ bias,
    unsigned short* __restrict__ out)
{
  __shared__ v8s halo[2592];   // 18x18 px x 8 slots, swizzled: 41472 B
  __shared__ v8s bsh[2304];    // 9 ks x 4 ocg x 64 lane: 36864 B
  char* hb = (char*)halo;
  const int t = threadIdx.x;
  const int img = blockIdx.z;
  const int tx0 = blockIdx.x << 4, ty0 = blockIdx.y << 4;   // tile 16x16
  const size_t ibase = ((size_t)img << 22);
  // stage halo: 18x18 px
  for (int c = t; c < 2592; c += 256) {
    int hy = c / 144, rem = c - hy * 144;
    int hx = rem >> 3, slot = rem & 7;
    int gy = ty0 + hy - 1, gx = tx0 + hx - 1;
    v8s v = {0, 0, 0, 0, 0, 0, 0, 0};
    if ((unsigned)gy < 256u && (unsigned)gx < 256u)
      v = *(const v8s*)(in + ibase + ((size_t)((gy << 8) + gx) << 6) + (slot << 3));
    int xl = hy * 18 + hx;
    *(v8s*)(hb + xl * 128 + ((slot ^ (xl & 7)) << 4)) = v;
  }
  // stage B half 0 (ks 0..8), prefetch half 1 into registers
  const v8s* bg = (const v8s*)bfrag;
  v8s breg[9];
  #pragma unroll
  for (int i = 0; i < 9; ++i) breg[i] = bg[t + (i << 8)];
  #pragma unroll
  for (int i = 0; i < 9; ++i) bsh[t + (i << 8)] = breg[i];
  #pragma unroll
  for (int i = 0; i < 9; ++i) breg[i] = bg[2304 + t + (i << 8)];
  __syncthreads();

  const int lane = t & 63, w = t >> 6;
  const int px = lane & 15, lg = lane >> 4;
  v4f acc[4][4];
  #pragma unroll
  for (int pf = 0; pf < 4; ++pf)
    #pragma unroll
    for (int og = 0; og < 4; ++og)
      #pragma unroll
      for (int rg = 0; rg < 4; ++rg) acc[pf][og][rg] = 0.f;

  #pragma unroll
  for (int half = 0; half < 2; ++half) {
    #pragma unroll
    for (int k9 = 0; k9 < 9; ++k9) {
      const int ks = half * 9 + k9;
      const int tap = ks >> 1;
      const int dy = tap / 3, dx = tap - dy * 3;
      const int slot = ((ks & 1) << 2) | lg;
      v8s b0 = bsh[((k9 << 2) | 0) * 64 + lane];
      v8s b1 = bsh[((k9 << 2) | 1) * 64 + lane];
      v8s b2 = bsh[((k9 << 2) | 2) * 64 + lane];
      v8s b3 = bsh[((k9 << 2) | 3) * 64 + lane];
      #pragma unroll
      for (int pf = 0; pf < 4; ++pf) {
        int xl = (w * 4 + pf + dy) * 18 + px + dx;
        v8s a = *(const v8s*)(hb + xl * 128 + ((slot ^ (xl & 7)) << 4));
        acc[pf][0] = __builtin_amdgcn_mfma_f32_16x16x32_bf16(a, b0, acc[pf][0], 0, 0, 0);
        acc[pf][1] = __builtin_amdgcn_mfma_f32_16x16x32_bf16(a, b1, acc[pf][1], 0, 0, 0);
        acc[pf][2] = __builtin_amdgcn_mfma_f32_16x16x32_bf16(a, b2, acc[pf][2], 0, 0, 0);
        acc[pf][3] = __builtin_amdgcn_mfma_f32_16x16x32_bf16(a, b3, acc[pf][3], 0, 0, 0);
      }
    }
    if (half == 0) {
      __syncthreads();               // everyone done reading half 0
      #pragma unroll
      for (int i = 0; i < 9; ++i) bsh[t + (i << 8)] = breg[i];
      __syncthreads();               // half 1 visible
    }
  }
  // C layout: col(lane&15)=oc, row=(lane>>4)*4+reg = pixel-x
  const int ocl = lane & 15;
  float bv[4];
  #pragma unroll
  for (int og = 0; og < 4; ++og) bv[og] = bias[(og << 4) + ocl];
  #pragma unroll
  for (int pf = 0; pf < 4; ++pf) {
    const int gy = ty0 + w * 4 + pf;
    #pragma unroll
    for (int og = 0; og < 4; ++og) {
      const int oc = (og << 4) + ocl;
      #pragma unroll
      for (int rg = 0; rg < 4; ++rg) {
        float v = fmaxf(acc[pf][og][rg] + bv[og], 0.f);
        int gx = tx0 + (lg << 2) + rg;
        out[ibase + ((size_t)((gy << 8) + gx) << 6) + oc] = f2bf(v);
      }
    }
  }
}

// ---------------- layer 5 (64->2, MFMA) + rhs = atb + lam*(atb + conv5) ----------------
__global__ __launch_bounds__(512, 4) void k_conv5_rhs(
    const unsigned short* __restrict__ in,
    const unsigned short* __restrict__ bf5,
    const float* __restrict__ b5,
    const float* __restrict__ atb,
    const float* __restrict__ lam,
    float2* __restrict__ rhs)
{
  __shared__ v8s halo[2592];
  char* hb = (char*)halo;
  const int t = threadIdx.x;
  const int img = blockIdx.z;
  const int tx0 = blockIdx.x << 4, ty0 = blockIdx.y << 4;
  const size_t ibase = ((size_t)img << 22);
  for (int c = t; c < 2592; c += 512) {
    int hy = c / 144, rem = c - hy * 144;
    int hx = rem >> 3, slot = rem & 7;
    int gy = ty0 + hy - 1, gx = tx0 + hx - 1;
    v8s v = {0, 0, 0, 0, 0, 0, 0, 0};
    if ((unsigned)gy < 256u && (unsigned)gx < 256u)
      v = *(const v8s*)(in + ibase + ((size_t)((gy << 8) + gx) << 6) + (slot << 3));
    int xl = hy * 18 + hx;
    *(v8s*)(hb + xl * 128 + ((slot ^ (xl & 7)) << 4)) = v;
  }
  __syncthreads();
  const int lane = t & 63, w = t >> 6;
  const int px = lane & 15, lg = lane >> 4;
  v4f acc[2];
  #pragma unroll
  for (int pf = 0; pf < 2; ++pf)
    #pragma unroll
    for (int rg = 0; rg < 4; ++rg) acc[pf][rg] = 0.f;
  #pragma unroll
  for (int ks = 0; ks < 18; ++ks) {
    const int tap = ks >> 1;
    const int dy = tap / 3, dx = tap - dy * 3;
    const int slot = ((ks & 1) << 2) | lg;
    v8s b = *(const v8s*)(bf5 + (((ks * 64) + lane) << 3));
    #pragma unroll
    for (int pf = 0; pf < 2; ++pf) {
      int xl = (w * 2 + pf + dy) * 18 + px + dx;
      v8s a = *(const v8s*)(hb + xl * 128 + ((slot ^ (xl & 7)) << 4));
      acc[pf] = __builtin_amdgcn_mfma_f32_16x16x32_bf16(a, b, acc[pf], 0, 0, 0);
    }
  }
  const int ocl = lane & 15;
  const float l = *lam;
  const float bsel = b5[ocl & 1];
  #pragma unroll
  for (int pf = 0; pf < 2; ++pf) {
    const int gy = ty0 + w * 2 + pf;
    #pragma unroll
    for (int rg = 0; rg < 4; ++rg) {
      float v = acc[pf][rg] + bsel;
      float d1 = __shfl_down(v, 1);
      if (ocl == 0) {
        int gx = tx0 + (lg << 2) + rg;
        int pix = (gy << 8) + gx;
        float x0 = atb[(size_t)img * 131072 + pix];
        float x1 = atb[(size_t)img * 131072 + 65536 + pix];
        rhs[(size_t)img * 65536 + pix] =
            make_float2(fmaf(l, x0 + v, x0), fmaf(l, x1 + d1, x1));
      }
    }
  }
}

// ---- AtA pass 1: (fused p-update) coil = csm*p (bf16 out), row FFT, part_p ----
__global__ __launch_bounds__(256) void k_coil_fft_rows(
    const float2* __restrict__ p_prev, const float2* __restrict__ r,
    float2* __restrict__ p_out,
    const float* __restrict__ part_r_old, const float* __restrict__ part_r_new,
    const int first,
    const unsigned* __restrict__ csmh, const float2* __restrict__ twf,
    unsigned* __restrict__ coil, float* __restrict__ part_p)
{
  __shared__ float2 trans[4096];
  __shared__ float2 sm2[4];
  __shared__ float sm1[4];
  const int t = threadIdx.x;
  const int bc = blockIdx.x, b = bc / NCOIL, c = bc - b * NCOIL;
  const int idx = t & 15, row16 = t >> 4;
  const int row = (blockIdx.y << 4) + row16;

  float beta = 0.f; bool do_upd = false;
  if (!first) {
    float so = 0.f, sn = 0.f;
    for (int i = t; i < 1024; i += 256) { so += part_r_old[i]; sn += part_r_new[i]; }
    blockRed2(so, sn, sm2);
    do_upd = so > 1e-10f;
    beta = do_upd ? sn / so : 0.f;
  }

  const int pb = (b << 16) + (row << 8);
  const int gb = (bc << 16) + (row << 8);
  float2 v[16];
  float pe = 0.f;
  #pragma unroll
  for (int h2 = 0; h2 < 16; ++h2) {
    int n = idx + (h2 << 4);
    float2 pv = p_prev[pb + n];
    if (!first && do_upd) {
      float2 rv = r[pb + n];
      pv = make_float2(fmaf(beta, pv.x, rv.x), fmaf(beta, pv.y, rv.y));
    }
    if (c == 0) {
      if (!first) p_out[pb + n] = pv;
      pe = fmaf(pv.x, pv.x, fmaf(pv.y, pv.y, pe));
    }
    float2 cs = unpack_bf(csmh[gb + n]);
    v[h2] = make_float2(cs.x * pv.x - cs.y * pv.y, cs.x * pv.y + cs.y * pv.x);
  }
  if (c == 0) {
    float tot = blockRed256(pe, sm1);
    if (t == 0) part_p[(b << 4) + blockIdx.y] = tot;
  }
  // forward four-step along W
  dif16<0>(v);
  #pragma unroll
  for (int rr = 0; rr < 16; ++rr) {
    int k1 = REV4[rr];
    v[rr] = cmulf(v[rr], twf[idx * k1]);
    trans[(k1 << 8) + (row16 << 4) + (idx ^ k1)] = v[rr];
  }
  __syncthreads();
  #pragma unroll
  for (int h1 = 0; h1 < 16; ++h1)
    v[h1] = trans[(idx << 8) + (row16 << 4) + (h1 ^ idx)];
  dif16<0>(v);
  #pragma unroll
  for (int rr = 0; rr < 16; ++rr)
    coil[gb + idx + (REV4[rr] << 4)] = pack_bf(v[rr]);
}

// ---- AtA pass 2: col FFT + mask (+part_m) + col IFFT, bf16 coil in/out ----
__global__ __launch_bounds__(256) void k_fft_cols_mask(
    unsigned* __restrict__ coil, const float* __restrict__ mask,
    const float2* __restrict__ twf, float* __restrict__ part_m)
{
  __shared__ float2 trans[4096];
  __shared__ float smR[4];
  const int t = threadIdx.x;
  const int bc = blockIdx.x, b = bc / NCOIL;
  const int w0 = blockIdx.y << 4;
  const int col = t & 15, idx = t >> 4;
  const int base = (bc << 16) + w0 + col;
  float2 v[16];
  #pragma unroll
  for (int h2 = 0; h2 < 16; ++h2)
    v[h2] = unpack_bf(coil[base + ((idx + (h2 << 4)) << 8)]);
  // ---- forward ----
  dif16<0>(v);
  #pragma unroll
  for (int r = 0; r < 16; ++r) {
    int k1 = REV4[r];
    v[r] = cmulf(v[r], twf[idx * k1]);
    trans[(idx << 8) + (k1 << 4) + col] = v[r];
  }
  __syncthreads();
  #pragma unroll
  for (int h1 = 0; h1 < 16; ++h1)
    v[h1] = trans[(h1 << 8) + (idx << 4) + col];
  __syncthreads();
  dif16<0>(v);
  // ---- mask in registers + k-space energy partial (denominator) ----
  float pm = 0.f;
  #pragma unroll
  for (int r = 0; r < 16; ++r) {
    float mv = mask[(b << 16) + ((idx + (REV4[r] << 4)) << 8) + w0 + col];
    v[r].x *= mv; v[r].y *= mv;
    pm = fmaf(v[r].x, v[r].x, fmaf(v[r].y, v[r].y, pm));
  }
  float tot = blockRed256(pm, smR);   // internal barrier also guards trans reuse
  if (t == 0) part_m[(bc << 4) + blockIdx.y] = tot;
  // ---- inverse ----
  dit16<1>(v);
  #pragma unroll
  for (int r = 0; r < 16; ++r) {
    float2 w = twf[idx * r];
    v[r] = make_float2(v[r].x * w.x + v[r].y * w.y, v[r].y * w.x - v[r].x * w.y);
    trans[(idx << 8) + (r << 4) + col] = v[r];
  }
  __syncthreads();
  #pragma unroll
  for (int k1 = 0; k1 < 16; ++k1)
    v[k1] = trans[(k1 << 8) + (idx << 4) + col];
  dif16<1>(v);
  const float sc = 1.f / 256.f;
  #pragma unroll
  for (int r = 0; r < 16; ++r)
    coil[base + ((idx + (REV4[r] << 4)) << 8)] =
        pack_bf(make_float2(v[r].x * sc, v[r].y * sc));
}

// ---- AtA pass 3: row IFFT + conj(csm) partial sum over 3 coils -> fp32 partials ----
__global__ __launch_bounds__(256) void k_ifft_rows_acc(
    const unsigned* __restrict__ coil, const unsigned* __restrict__ csmh,
    const float2* __restrict__ twf, float2* __restrict__ partbuf)
{
  __shared__ float2 trans[4096];
  const int t = threadIdx.x;
  const int b = blockIdx.x, cs = blockIdx.z;
  const int idx = t & 15, row16 = t >> 4;
  const int row = (blockIdx.y << 4) + row16;
  float2 acc[16];
  #pragma unroll
  for (int rr = 0; rr < 16; ++rr) acc[rr] = make_float2(0.f, 0.f);
  for (int j = 0; j < 3; ++j) {
    const int c = cs * 3 + j;
    const int gb = ((b * NCOIL + c) << 16) + (row << 8);
    float2 v[16];
    #pragma unroll
    for (int rr = 0; rr < 16; ++rr)
      v[rr] = unpack_bf(coil[gb + idx + (REV4[rr] << 4)]);
    dit16<1>(v);
    if (j) __syncthreads();
    #pragma unroll
    for (int rr = 0; rr < 16; ++rr) {
      float2 w = twf[idx * rr];
      float2 z = v[rr];
      trans[(rr << 8) + (row16 << 4) + (idx ^ rr)] =
          make_float2(z.x * w.x + z.y * w.y, z.y * w.x - z.x * w.y);
    }
    __syncthreads();
    #pragma unroll
    for (int k1 = 0; k1 < 16; ++k1)
      v[k1] = trans[(idx << 8) + (row16 << 4) + (k1 ^ idx)];
    dif16<1>(v);
    #pragma unroll
    for (int rr = 0; rr < 16; ++rr) {
      int gi = gb + idx + (REV4[rr] << 4);
      float2 cw = unpack_bf(csmh[gi]);
      float2 z = v[rr];
      acc[rr].x += cw.x * z.x + cw.y * z.y;
      acc[rr].y += cw.x * z.y - cw.y * z.x;
    }
  }
  const int ob = (((cs << 3) + b) << 16) + (row << 8);
  #pragma unroll
  for (int rr = 0; rr < 16; ++rr)
    partbuf[ob + idx + (REV4[rr] << 4)] = acc[rr];
}

// ---- update1: alpha from energy-denominator, Ap inline, x,r update, part_r ----
__global__ __launch_bounds__(256) void k_update1(
    float2* __restrict__ x, float2* __restrict__ r, const float2* __restrict__ p,
    const float2* __restrict__ partbuf,
    const float* __restrict__ part_m, const float* __restrict__ part_p,
    const float* __restrict__ part_r_old, float* __restrict__ part_r_new,
    const float* __restrict__ lam)
{
  __shared__ float2 sm2[4];
  __shared__ float smA[4];
  __shared__ float smB[4];
  const int t = threadIdx.x;
  float se = 0.f, sp = 0.f, sr = 0.f;
  for (int i = t; i < 1536; i += 256) se += part_m[i];
  if (t < 128) sp = part_p[t];
  for (int i = t; i < 1024; i += 256) sr += part_r_old[i];
  blockRed2(se, sp, sm2);
  sr = blockRed256(sr, smA);
  const float l = *lam;
  const float denom = se * (1.f / 65536.f) + l * sp;
  const bool cont = sr > 1e-10f;
  const float alpha = cont ? sr / denom : 0.f;  // alpha=0 => x,r,rTr frozen exactly
  const float inv2 = 1.f / 256.f;
  float s = 0.f;
  #pragma unroll
  for (int e = 0; e < 2; ++e) {
    int pix = blockIdx.x * 512 + t + (e << 8);
    int b = pix >> 16, off = pix & 65535;
    float2 s0 = partbuf[(b << 16) + off];
    float2 s1 = partbuf[((8 + b) << 16) + off];
    float2 s2 = partbuf[((16 + b) << 16) + off];
    float2 s3 = partbuf[((24 + b) << 16) + off];
    float sx = (s0.x + s1.x) + (s2.x + s3.x);
    float sy = (s0.y + s1.y) + (s2.y + s3.y);
    float2 pv = p[pix], xv = x[pix], rv = r[pix];
    float2 apv = make_float2(fmaf(l, pv.x, sx * inv2), fmaf(l, pv.y, sy * inv2));
    xv.x = fmaf(alpha, pv.x, xv.x); xv.y = fmaf(alpha, pv.y, xv.y);
    rv.x = fmaf(-alpha, apv.x, rv.x); rv.y = fmaf(-alpha, apv.y, rv.y);
    x[pix] = xv; r[pix] = rv;
    s = fmaf(rv.x, rv.x, fmaf(rv.y, rv.y, s));
  }
  float tot = blockRed256(s, smB);
  if (t == 0) part_r_new[blockIdx.x] = tot;
}

// ---------------- CG init / final ----------------
__global__ __launch_bounds__(256) void k_cg_init(
    const float2* __restrict__ rhs, float2* __restrict__ x,
    float2* __restrict__ r, float2* __restrict__ p, float* __restrict__ part)
{
  __shared__ float sm[4];
  const int t = threadIdx.x;
  const int base = blockIdx.x * 512;
  float s = 0.f;
  #pragma unroll
  for (int e = 0; e < 2; ++e) {
    int idx = base + t + (e << 8);
    float2 v = rhs[idx];
    x[idx] = make_float2(0.f, 0.f);
    r[idx] = v; p[idx] = v;
    s = fmaf(v.x, v.x, fmaf(v.y, v.y, s));
  }
  float tot = blockRed256(s, sm);
  if (t == 0) part[blockIdx.x] = tot;
}

__global__ __launch_bounds__(256) void k_final(const float2* __restrict__ x,
                                               float* __restrict__ out) {
  const int t = threadIdx.x;
  const int base = blockIdx.x * 512;
  #pragma unroll
  for (int e = 0; e < 2; ++e) {
    int idx = base + t + (e << 8);
    int b = idx >> 16, pix = idx & 65535;
    float2 v = x[idx];
    out[(b << 17) + pix] = v.x;
    out[(b << 17) + 65536 + pix] = v.y;
  }
}

// ---------------- driver ----------------
extern "C" void kernel_launch(void* const* d_in, const int* in_sizes, int n_in,
                              void* d_out, int out_size, void* d_ws, size_t ws_size,
                              hipStream_t stream) {
  (void)in_sizes; (void)n_in; (void)out_size; (void)ws_size;
  const float* atb   = (const float*)d_in[0];
  const float* csm_r = (const float*)d_in[1];
  const float* csm_i = (const float*)d_in[2];
  const float* mask  = (const float*)d_in[3];
  const float* w1 = (const float*)d_in[4];  const float* b1 = (const float*)d_in[5];
  const float* w2 = (const float*)d_in[6];  const float* b2 = (const float*)d_in[7];
  const float* w3 = (const float*)d_in[8];  const float* b3 = (const float*)d_in[9];
  const float* w4 = (const float*)d_in[10]; const float* b4 = (const float*)d_in[11];
  const float* w5 = (const float*)d_in[12]; const float* b5 = (const float*)d_in[13];
  const float* lam = (const float*)d_in[14];

  char* ws = (char*)d_ws;   // ws_size = 256 MiB; we use ~218.4 MB
  unsigned short* actA = (unsigned short*)ws;                  // 64 MiB
  unsigned short* actB = (unsigned short*)(ws + 67108864);     // 64 MiB
  unsigned* coil   = (unsigned*)(ws + 134217728);              // 25165824 B (bf16x2)
  float2* partbuf  = (float2*)(ws + 159383552);                // 16777216 B
  float2* x        = (float2*)(ws + 176160768);                // 4 MiB
  float2* r        = (float2*)(ws + 180355072);
  float2* pbuf0    = (float2*)(ws + 184549376);
  float2* rhs      = (float2*)(ws + 188743680);                // doubles as pbuf1
  float2* pbuf1    = rhs;
  unsigned* csmh   = (unsigned*)(ws + 192937984);              // 25165824 B
  float*  w1T      = (float*)(ws + 218103808);                 // 4608 B
  unsigned short* bf2 = (unsigned short*)(ws + 218108416);     // 73728 B each
  unsigned short* bf3 = (unsigned short*)(ws + 218182144);
  unsigned short* bf4 = (unsigned short*)(ws + 218255872);
  unsigned short* bf5 = (unsigned short*)(ws + 218329600);     // 18432 B
  float2* twf      = (float2*)(ws + 218348032);                // 2048 B
  float*  part_r   = (float*)(ws + 218350080);                 // 12*1024*4
  float*  part_m   = (float*)(ws + 218399232);                 // 1536*4
  float*  part_p   = (float*)(ws + 218405376);                 // 128*4

  // prep (single merged kernel)
  k_prep<<<25050, 256, 0, stream>>>(w1, w2, w3, w4, w5, csm_r, csm_i,
                                    w1T, bf2, bf3, bf4, bf5, csmh, twf);

  // CNN: full batch, z = 8
  k_conv1<<<dim3(16, 16, 8), 256, 0, stream>>>(atb, w1T, b1, actA);
  k_conv_mfma<<<dim3(16, 16, 8), 256, 0, stream>>>(actA, bf2, b2, actB);
  k_conv_mfma<<<dim3(16, 16, 8), 256, 0, stream>>>(actB, bf3, b3, actA);
  k_conv_mfma<<<dim3(16, 16, 8), 256, 0, stream>>>(actA, bf4, b4, actB);
  k_conv5_rhs<<<dim3(16, 16, 8), 512, 0, stream>>>(actB, bf5, b5, atb, lam, rhs);

  // CG
  k_cg_init<<<1024, 256, 0, stream>>>(rhs, x, r, pbuf0, part_r);
  for (int it = 0; it < 11; ++it) {
    float2* p_cur = (it % 2 == 0) ? pbuf0 : pbuf1;
    float2* p_prv = (it == 0) ? pbuf0 : ((it % 2 == 0) ? pbuf1 : pbuf0);
    const float* pro = part_r + (it > 0 ? (it - 1) : 0) * 1024;
    const float* prn = part_r + it * 1024;
    k_coil_fft_rows<<<dim3(96, 16), 256, 0, stream>>>(
        p_prv, r, p_cur, pro, prn, it == 0 ? 1 : 0, csmh, twf, coil, part_p);
    k_fft_cols_mask<<<dim3(96, 16), 256, 0, stream>>>(coil, mask, twf, part_m);
    k_ifft_rows_acc<<<dim3(8, 16, 4), 256, 0, stream>>>(coil, csmh, twf, partbuf);
    k_update1<<<1024, 256, 0, stream>>>(x, r, p_cur, partbuf, part_m, part_p,
                                        part_r + it * 1024, part_r + (it + 1) * 1024, lam);
  }

  k_final<<<1024, 256, 0, stream>>>(x, (float*)d_out);
}